// Round 5
// baseline (197.285 us; speedup 1.0000x reference)
//
#include <hip/hip_runtime.h>
#include <cstdint>

#define DIMC   1024
#define NHEADS 16
#define HD     64
#define BATCH  2
#define SEQ    2048
#define MROWS  (BATCH*SEQ)   // 4096
// Q pre-scale: (1/sqrt(64)) * log2(e)  -> softmax computed in base 2 (exact)
#define QSCALE2 0.18033688f

typedef __bf16 bf16x8 __attribute__((ext_vector_type(8)));
typedef float  f32x4  __attribute__((ext_vector_type(4)));
typedef float  f32x16 __attribute__((ext_vector_type(16)));

#define AST 88    // fallback LDS row stride (bf16 elems)
#define TST 136   // transpose-epilogue LDS stride

__device__ __forceinline__ unsigned short f2bf(float f) {
    union { float f; unsigned int u; } v; v.f = f;
    unsigned int u = v.u;
    u += 0x7fffu + ((u >> 16) & 1u);   // round-to-nearest-even
    return (unsigned short)(u >> 16);
}

// pack two floats to bf16x2 (round-nearest, ties away): 2 adds + 1 v_perm
__device__ __forceinline__ unsigned int pk2bf(float a, float b) {
    union { float f; unsigned int u; } ua, ub;
    ua.f = a; ub.f = b;
    return __builtin_amdgcn_perm(ub.u + 0x8000u, ua.u + 0x8000u, 0x07060302u);
}

__device__ __forceinline__ void gload_lds16(const void* g, void* l) {
    __builtin_amdgcn_global_load_lds(
        (const __attribute__((address_space(1))) unsigned int*)g,
        (__attribute__((address_space(3))) unsigned int*)l, 16, 0, 0);
}

// ---------------------------------------------------------------------------
// Pre-cast fp32 -> bf16: x (4M elems) and Wq|Wk|Wv|Wp (1M each) into xb / Wb.
// ---------------------------------------------------------------------------
__global__ __launch_bounds__(256) void cast_all(
    const float* __restrict__ x,
    const float* __restrict__ Wq, const float* __restrict__ Wk,
    const float* __restrict__ Wv, const float* __restrict__ Wp,
    unsigned short* __restrict__ xb, unsigned short* __restrict__ Wb)
{
    const size_t M1 = (size_t)DIMC * DIMC;   // 1M elems
    int y = blockIdx.y;
    const float* src;
    unsigned short* dst;
    if (y < 4)      { src = x  + (size_t)y * M1; dst = xb + (size_t)y * M1; }
    else if (y == 4){ src = Wq; dst = Wb; }
    else if (y == 5){ src = Wk; dst = Wb + M1; }
    else if (y == 6){ src = Wv; dst = Wb + 2 * M1; }
    else            { src = Wp; dst = Wb + 3 * M1; }
    size_t idx = ((size_t)blockIdx.x * 256 + threadIdx.x) * 4;
    float4 v = *(const float4*)(src + idx);
    ushort4 p; p.x = f2bf(v.x); p.y = f2bf(v.y); p.z = f2bf(v.z); p.w = f2bf(v.w);
    *(ushort4*)(dst + idx) = p;
}

// ---------------------------------------------------------------------------
// Pipelined GEMM building blocks (issue-after-barrier pattern).
// 128x128 tile, BK=64, 4 waves; LDS double-buffered (4 x 16 KB).
// ---------------------------------------------------------------------------
__device__ __forceinline__ void gemm_issue(
    const unsigned short* __restrict__ A, const unsigned short* __restrict__ B,
    unsigned short* As, unsigned short* Bs, int m0, int n0, int kt)
{
    const int t = threadIdx.x;
    const int w = t >> 6, lane = t & 63;
    const int srow = lane >> 3, scol = lane & 7;
#pragma unroll
    for (int i = 0; i < 4; ++i) {
        int r  = i * 32 + w * 8 + srow;        // 0..127
        int cg = scol ^ (r & 7);               // swizzled source chunk
        gload_lds16(A + (size_t)(m0 + r) * DIMC + kt + cg * 8, As + r * 64 + scol * 8);
        gload_lds16(B + (size_t)(n0 + r) * DIMC + kt + cg * 8, Bs + r * 64 + scol * 8);
    }
}

__device__ __forceinline__ void gemm_compute(
    const unsigned short* As, const unsigned short* Bs, f32x4 acc[4][4])
{
    const int t = threadIdx.x;
    const int w = t >> 6, lane = t & 63, quad = lane >> 4, lr = lane & 15;
    const int wr = w >> 1, wc = w & 1;
#pragma unroll
    for (int kk = 0; kk < 2; ++kk) {
        bf16x8 af[4], bfr[4];
#pragma unroll
        for (int mt = 0; mt < 4; ++mt) {
            int row = wr * 64 + mt * 16 + lr;
            int cb  = kk * 4 + quad;
            af[mt] = *(const bf16x8*)&As[row * 64 + (cb ^ (row & 7)) * 8];
        }
#pragma unroll
        for (int nt = 0; nt < 4; ++nt) {
            int row = wc * 64 + nt * 16 + lr;
            int cb  = kk * 4 + quad;
            bfr[nt] = *(const bf16x8*)&Bs[row * 64 + (cb ^ (row & 7)) * 8];
        }
#pragma unroll
        for (int mt = 0; mt < 4; ++mt)
#pragma unroll
            for (int nt = 0; nt < 4; ++nt)
                acc[mt][nt] = __builtin_amdgcn_mfma_f32_16x16x32_bf16(af[mt], bfr[nt], acc[mt][nt], 0, 0, 0);
    }
}

// Full pipelined K-loop: one __syncthreads per tile; prefetch issued after the
// barrier into the other buffer stays in flight across the compute phase.
__device__ __forceinline__ void gemm_k_loop_db(
    const unsigned short* __restrict__ A, const unsigned short* __restrict__ B,
    unsigned short* smem, int m0, int n0, f32x4 acc[4][4])
{
    unsigned short* As0 = smem;
    unsigned short* Bs0 = smem + 8192;
    unsigned short* As1 = smem + 16384;
    unsigned short* Bs1 = smem + 24576;

    gemm_issue(A, B, As0, Bs0, m0, n0, 0);
    for (int kt = 0; kt < DIMC; kt += 128) {
        __syncthreads();                       // publish As0/Bs0 (DMA had full
        gemm_issue(A, B, As1, Bs1, m0, n0, kt + 64);   //  compute phase in flight)
        gemm_compute(As0, Bs0, acc);
        __syncthreads();                       // publish As1/Bs1
        if (kt + 128 < DIMC) gemm_issue(A, B, As0, Bs0, m0, n0, kt + 128);
        gemm_compute(As1, Bs1, acc);
    }
}

// vT transpose epilogue: stage C-tile transposed in LDS, then coalesced
// 16B global stores to vT[b][h][d][n].
__device__ __forceinline__ void vt_epilogue(
    unsigned short* Ts, f32x4 acc[4][4], int m0, int n0,
    unsigned short* __restrict__ vT)
{
    const int t = threadIdx.x;
    const int w = t >> 6, lane = t & 63, quad = lane >> 4, lr = lane & 15;
    const int wr = w >> 1, wc = w & 1;

    __syncthreads();
#pragma unroll
    for (int mt = 0; mt < 4; ++mt)
#pragma unroll
        for (int nt = 0; nt < 4; ++nt) {
            int lcol  = wc * 64 + nt * 16 + lr;
            int lrow0 = wr * 64 + mt * 16 + quad * 4;
            ushort4 p;
            p.x = f2bf(acc[mt][nt][0]); p.y = f2bf(acc[mt][nt][1]);
            p.z = f2bf(acc[mt][nt][2]); p.w = f2bf(acc[mt][nt][3]);
            *(ushort4*)&Ts[lcol * TST + lrow0] = p;
        }
    __syncthreads();

    int lc = t >> 1, half = t & 1;
    int cg = n0 + lc, hh = cg >> 6, dd = cg & 63;
    int bb = m0 >> 11, nn0 = m0 & (SEQ - 1);
    size_t dst = ((size_t)((bb * NHEADS + hh) * HD + dd)) * SEQ + nn0 + half * 64;
    const unsigned short* srcp = &Ts[lc * TST + half * 64];
#pragma unroll
    for (int i = 0; i < 8; ++i)
        *(uint4*)&vT[dst + i * 8] = *(const uint4*)&srcp[i * 8];
}

// ---------------------------------------------------------------------------
// Fast QKV projection (pipelined): z=0 -> q (scaled), z=1 -> k, z=2 -> vT.
// ---------------------------------------------------------------------------
__global__ __launch_bounds__(256) void gemm_qkv_fast(
    const unsigned short* __restrict__ xb, const unsigned short* __restrict__ Wb,
    unsigned short* __restrict__ qo, unsigned short* __restrict__ ko,
    unsigned short* __restrict__ vT)
{
    __shared__ unsigned short smem[32768];   // 64 KB: 4 x 16 KB buffers

    const int t  = threadIdx.x;
    const int n0 = blockIdx.x * 128, m0 = blockIdx.y * 128, z = blockIdx.z;
    const unsigned short* B = Wb + (size_t)z * DIMC * DIMC;
    const int w = t >> 6, lane = t & 63, quad = lane >> 4, lr = lane & 15;
    const int wr = w >> 1, wc = w & 1;

    f32x4 acc[4][4];
#pragma unroll
    for (int mt = 0; mt < 4; ++mt)
#pragma unroll
        for (int nt = 0; nt < 4; ++nt)
#pragma unroll
            for (int r = 0; r < 4; ++r) acc[mt][nt][r] = 0.f;

    gemm_k_loop_db(xb, B, smem, m0, n0, acc);

    if (z == 2) {
        vt_epilogue(smem, acc, m0, n0, vT);
    } else {
        unsigned short* Out = (z == 0) ? qo : ko;
        const float sc = (z == 0) ? QSCALE2 : 1.0f;
#pragma unroll
        for (int mt = 0; mt < 4; ++mt)
#pragma unroll
            for (int nt = 0; nt < 4; ++nt)
#pragma unroll
                for (int r = 0; r < 4; ++r) {
                    int row = m0 + wr * 64 + mt * 16 + quad * 4 + r;
                    int col = n0 + wc * 64 + nt * 16 + lr;
                    Out[(size_t)row * DIMC + col] = f2bf(acc[mt][nt][r] * sc);
                }
    }
}

// ---------------------------------------------------------------------------
// Fast output projection (pipelined).
// ---------------------------------------------------------------------------
__global__ __launch_bounds__(256) void gemm_out_fast(
    const unsigned short* __restrict__ O, const unsigned short* __restrict__ Wpb,
    const float* __restrict__ bias, float* __restrict__ out)
{
    __shared__ unsigned short smem[32768];   // 64 KB: 4 x 16 KB buffers

    const int t  = threadIdx.x;
    const int n0 = blockIdx.x * 128, m0 = blockIdx.y * 128;
    const int w = t >> 6, lane = t & 63, quad = lane >> 4, lr = lane & 15;
    const int wr = w >> 1, wc = w & 1;

    f32x4 acc[4][4];
#pragma unroll
    for (int mt = 0; mt < 4; ++mt)
#pragma unroll
        for (int nt = 0; nt < 4; ++nt)
#pragma unroll
            for (int r = 0; r < 4; ++r) acc[mt][nt][r] = 0.f;

    gemm_k_loop_db(O, Wpb, smem, m0, n0, acc);

#pragma unroll
    for (int mt = 0; mt < 4; ++mt)
#pragma unroll
        for (int nt = 0; nt < 4; ++nt)
#pragma unroll
            for (int r = 0; r < 4; ++r) {
                int row = m0 + wr * 64 + mt * 16 + quad * 4 + r;
                int col = n0 + wc * 64 + nt * 16 + lr;
                out[(size_t)row * DIMC + col] = acc[mt][nt][r] + bias[col];
            }
}

// ---------------------------------------------------------------------------
// Flash attention v15: v14's 32x32x16 structure, but P routed through LDS
// with the v10-proven uint2 XOR-swizzle scheme (bisect: removes the only
// unverified mechanism, permlane32_swap; keeps the LDS-traffic halving).
//   - 32x32 C/D rows come in runs of 4 (regs 0-3 -> rows 0-3 (+4hi, +8blk)),
//     so {pk[2i],pk[2i+1]} is an 8-byte chunk of 4 consecutive kv: chunk
//     c holds kv 4c..4c+3.  Write chunk (c ^ pkey), pkey=(col&3)<<1 (even ->
//     16B reads stay contiguous).  PV A-frag pf0 = chunks {2hi,2hi+1} = kv
//     8hi..8hi+7 (exactly slots j=0..7); pf1 = chunks {4+2hi,5+2hi}.
//   - Ps wave-private 32q x 32kv (1024 shorts/wave, 8 KB total); write->read
//     same-wave (lgkm order), no extra barrier (v10-v13 pattern).
//   LDS = 32 KB K/V dbuf + 8 KB Ps = 40 KB -> 4 blocks/CU = 16 waves/CU.
//   Per block-tile LDS traffic ~64 KB (v13: 96 KB).
// ---------------------------------------------------------------------------
__global__ __launch_bounds__(256, 4) void attn_kernel(
    const unsigned short* __restrict__ qg, const unsigned short* __restrict__ kg,
    const unsigned short* __restrict__ vT, unsigned short* __restrict__ og)
{
    __shared__ unsigned short smem[20480];   // 40 KB
    unsigned short* Ka = smem;               //  8 KB each (64x64 bf16)
    unsigned short* Kb = smem + 4096;
    unsigned short* Va = smem + 8192;
    unsigned short* Vb = smem + 12288;
    unsigned short* Ps = smem + 16384;       //  8 KB: 4 x (32q x 32kv)

    const int t  = threadIdx.x;
    const int w = t >> 6, l = t & 63;
    const int col = l & 31, hi = l >> 5;      // 32x32 fragment coords
    const int qh = w >> 1, kvh = w & 1;       // q-half / kv-half of the wave
    const int srow = t >> 3, scol = t & 7;    // staging coords (srow 0..31)
    const int pkey = (col & 3) << 1;          // even -> chunk pairs stay adjacent

    unsigned short* PsW = Ps + w * 1024;      // wave-private P tile

    // XCD-aware mapping: bid&7 = XCD; each XCD owns 4 full (b,h) pairs
    // (32 q-tiles of 64 rows each) -> K/V head stays L2-local.
    const int bid  = blockIdx.x;              // 0..1023
    const int slot = bid >> 3;                // 0..127
    const int bh   = (bid & 7) * 4 + (slot >> 5);
    const int qt   = slot & 31;               // 64-row Q tile index
    const int b    = bh >> 4, h = bh & 15;

    const unsigned short* khead = kg + ((size_t)(b * SEQ)) * DIMC + h * HD;
    const unsigned short* vhead = vT + (size_t)((b * NHEADS + h) * HD) * SEQ;

    // Q B-fragments (pre-scaled by QSCALE2): col -> q row, d = ks*16+hi*8+j
    bf16x8 qf[4];
    {
        const size_t qoff = ((size_t)(b * SEQ + qt * 64 + qh * 32 + col)) * DIMC + h * HD + hi * 8;
#pragma unroll
        for (int ks = 0; ks < 4; ++ks)
            qf[ks] = *(const bf16x8*)(qg + qoff + ks * 16);
    }

    bf16x8 ones;
#pragma unroll
    for (int j = 0; j < 8; ++j) ones[j] = (__bf16)1.0f;

    f32x16 o0, o1, lac;
#pragma unroll
    for (int r = 0; r < 16; ++r) { o0[r] = 0.f; o1[r] = 0.f; lac[r] = 0.f; }

    // K rows (kv) and V rows (d) staged with the v10 XOR swizzle (unchanged).
    auto issue = [&](int kt, unsigned short* Kd, unsigned short* Vd) {
#pragma unroll
        for (int i = 0; i < 2; ++i) {
            int r  = i * 32 + srow;            // 0..63
            int cg = scol ^ (r & 7);
            gload_lds16(khead + (size_t)(kt * 64 + r) * DIMC + cg * 8, Kd + r * 64 + scol * 8);
            gload_lds16(vhead + (size_t)r * SEQ + kt * 64 + cg * 8,   Vd + r * 64 + scol * 8);
        }
    };

    auto phase = [&](const unsigned short* Kc, const unsigned short* Vc) {
        // --- S = K . Q^T over this wave's 32-kv half (rows=kv, cols=q) ---
        f32x16 s;
#pragma unroll
        for (int r = 0; r < 16; ++r) s[r] = 0.f;
#pragma unroll
        for (int ks = 0; ks < 4; ++ks) {
            int r = kvh * 32 + col;                       // kv row in tile
            int c = ks * 2 + hi;                          // source d-chunk
            bf16x8 kf = *(const bf16x8*)&Kc[r * 64 + ((c ^ (r & 7)) * 8)];
            s = __builtin_amdgcn_mfma_f32_32x32x16_bf16(kf, qf[ks], s, 0, 0, 0);
        }

        // --- V B-frags (independent of s: issue early) ---
        bf16x8 vf[2][2];
#pragma unroll
        for (int dt = 0; dt < 2; ++dt)
#pragma unroll
            for (int ks2 = 0; ks2 < 2; ++ks2) {
                int r = dt * 32 + col;                    // d row of vT tile
                int c = kvh * 4 + ks2 * 2 + hi;           // source kv-chunk
                vf[dt][ks2] = *(const bf16x8*)&Vc[r * 64 + ((c ^ (r & 7)) * 8)];
            }

        // --- p = 2^s -> bf16 pairs -> LDS (8B chunks of 4 consecutive kv) ---
        // s[reg] = S[kv-rel = (reg&3)+8*(reg>>2)+4*hi][q = col]; pairs
        // {pk[2i],pk[2i+1]} cover kv {8i+4hi .. 8i+4hi+3} = chunk cw=2i+hi.
        unsigned int pk[8];
#pragma unroll
        for (int i = 0; i < 8; ++i)
            pk[i] = pk2bf(__builtin_amdgcn_exp2f(s[2 * i]),
                          __builtin_amdgcn_exp2f(s[2 * i + 1]));
#pragma unroll
        for (int i2 = 0; i2 < 4; ++i2) {
            int cw = i2 * 2 + hi;
            uint2 pp; pp.x = pk[2 * i2]; pp.y = pk[2 * i2 + 1];
            *(uint2*)&PsW[col * 32 + ((cw ^ pkey) << 2)] = pp;
        }

        // --- PV A-frags from LDS: q row = col, slots j -> kv 8hi+j (+16) ---
        bf16x8 pf0 = *(const bf16x8*)&PsW[col * 32 + (((2 * hi) ^ pkey) << 2)];
        bf16x8 pf1 = *(const bf16x8*)&PsW[col * 32 + (((4 + 2 * hi) ^ pkey) << 2)];

        // --- l += P.1 ; O += P.V  (rows=q: matches final store) ---
        lac = __builtin_amdgcn_mfma_f32_32x32x16_bf16(pf0, ones, lac, 0, 0, 0);
        lac = __builtin_amdgcn_mfma_f32_32x32x16_bf16(pf1, ones, lac, 0, 0, 0);
        o0  = __builtin_amdgcn_mfma_f32_32x32x16_bf16(pf0, vf[0][0], o0, 0, 0, 0);
        o0  = __builtin_amdgcn_mfma_f32_32x32x16_bf16(pf1, vf[0][1], o0, 0, 0, 0);
        o1  = __builtin_amdgcn_mfma_f32_32x32x16_bf16(pf0, vf[1][0], o1, 0, 0, 0);
        o1  = __builtin_amdgcn_mfma_f32_32x32x16_bf16(pf1, vf[1][1], o1, 0, 0, 0);
    };

    issue(0, Ka, Va);
    for (int kt = 0; kt < SEQ / 64; kt += 2) {
        __syncthreads();                      // publish Ka/Va(kt)
        issue(kt + 1, Kb, Vb);
        phase(Ka, Va);
        __syncthreads();                      // publish Kb/Vb(kt+1)
        if (kt + 2 < SEQ / 64) issue(kt + 2, Ka, Va);
        phase(Kb, Vb);
    }

    // --- merge kv-halves (O and l simply add: un-normalized exp2 softmax) ---
    __syncthreads();                          // all waves done with K/V/Ps
    float* mrg = (float*)smem;                // 128 lanes x 49-f32 stride ~ 25 KB
    if (kvh == 1) {
        float* dst = mrg + (qh * 64 + l) * 49;
#pragma unroll
        for (int r = 0; r < 16; ++r) {
            dst[r] = o0[r]; dst[16 + r] = o1[r]; dst[32 + r] = lac[r];
        }
    }
    __syncthreads();
    if (kvh == 0) {
        const float* src = mrg + (qh * 64 + l) * 49;
        float inv[16];
#pragma unroll
        for (int r = 0; r < 16; ++r) {
            o0[r] += src[r]; o1[r] += src[16 + r];
            inv[r] = 1.0f / (lac[r] + src[32 + r]);
        }
#pragma unroll
        for (int r = 0; r < 16; ++r) {
            int qrow = qt * 64 + qh * 32 + (r & 3) + 8 * (r >> 2) + 4 * hi;
            size_t base = ((size_t)(b * SEQ + qrow)) * DIMC + h * HD;
            og[base + col]      = f2bf(o0[r] * inv[r]);
            og[base + 32 + col] = f2bf(o1[r] * inv[r]);
        }
    }
}

// ---------------------------------------------------------------------------
// Fallback path (ws < 40 MB): fp32-staging GEMMs.
// ---------------------------------------------------------------------------
__global__ __launch_bounds__(256) void gemm_qkv_f32(
    const float* __restrict__ x,
    const float* __restrict__ Wq, const float* __restrict__ Wk, const float* __restrict__ Wv,
    unsigned short* __restrict__ qo, unsigned short* __restrict__ ko, unsigned short* __restrict__ vT)
{
    __shared__ unsigned short smem[2 * 128 * AST];
    unsigned short* As = smem;
    unsigned short* Bs = smem + 128 * AST;

    const int t  = threadIdx.x;
    const int n0 = blockIdx.x * 128, m0 = blockIdx.y * 128, z = blockIdx.z;
    const float* W = (z == 0) ? Wq : (z == 1) ? Wk : Wv;
    const int w = t >> 6, l = t & 63, quad = l >> 4, lr = l & 15;
    const int wr = w >> 1, wc = w & 1;

    f32x4 acc[4][4];
#pragma unroll
    for (int mt = 0; mt < 4; ++mt)
#pragma unroll
        for (int nt = 0; nt < 4; ++nt)
#pragma unroll
            for (int r = 0; r < 4; ++r) acc[mt][nt][r] = 0.f;

    for (int kt = 0; kt < DIMC; kt += 64) {
        __syncthreads();
#pragma unroll
        for (int i = 0; i < 8; ++i) {
            int flat = t + i * 256;
            int row = flat >> 4, seg = flat & 15;
            float4 a = *(const float4*)(x + (size_t)(m0 + row) * DIMC + kt + seg * 4);
            ushort4 pa; pa.x = f2bf(a.x); pa.y = f2bf(a.y); pa.z = f2bf(a.z); pa.w = f2bf(a.w);
            *(ushort4*)&As[row * AST + seg * 4] = pa;
            float4 b = *(const float4*)(W + (size_t)(n0 + row) * DIMC + kt + seg * 4);
            ushort4 pb; pb.x = f2bf(b.x); pb.y = f2bf(b.y); pb.z = f2bf(b.z); pb.w = f2bf(b.w);
            *(ushort4*)&Bs[row * AST + seg * 4] = pb;
        }
        __syncthreads();
#pragma unroll
        for (int kk = 0; kk < 2; ++kk) {
            bf16x8 af[4], bfr[4];
#pragma unroll
            for (int mt = 0; mt < 4; ++mt)
                af[mt] = *(const bf16x8*)&As[(wr * 64 + mt * 16 + lr) * AST + kk * 32 + quad * 8];
#pragma unroll
            for (int nt = 0; nt < 4; ++nt)
                bfr[nt] = *(const bf16x8*)&Bs[(wc * 64 + nt * 16 + lr) * AST + kk * 32 + quad * 8];
#pragma unroll
            for (int mt = 0; mt < 4; ++mt)
#pragma unroll
                for (int nt = 0; nt < 4; ++nt)
                    acc[mt][nt] = __builtin_amdgcn_mfma_f32_16x16x32_bf16(af[mt], bfr[nt], acc[mt][nt], 0, 0, 0);
        }
    }

    if (z == 2) {
        __syncthreads();
#pragma unroll
        for (int mt = 0; mt < 4; ++mt)
#pragma unroll
            for (int nt = 0; nt < 4; ++nt) {
                int lcol  = wc * 64 + nt * 16 + lr;
                int lrow0 = wr * 64 + mt * 16 + quad * 4;
                ushort4 p;
                p.x = f2bf(acc[mt][nt][0]); p.y = f2bf(acc[mt][nt][1]);
                p.z = f2bf(acc[mt][nt][2]); p.w = f2bf(acc[mt][nt][3]);
                *(ushort4*)&smem[lcol * TST + lrow0] = p;
            }
        __syncthreads();
        int lc = t >> 1, half = t & 1;
        int cg = n0 + lc, hh = cg >> 6, dd = cg & 63;
        int bb = m0 >> 11, nn0 = m0 & (SEQ - 1);
        size_t dst = ((size_t)((bb * NHEADS + hh) * HD + dd)) * SEQ + nn0 + half * 64;
        const unsigned short* srcp = &smem[lc * TST + half * 64];
#pragma unroll
        for (int i = 0; i < 8; ++i)
            *(uint4*)&vT[dst + i * 8] = *(const uint4*)&srcp[i * 8];
    } else {
        unsigned short* Out = (z == 0) ? qo : ko;
        const float sc = (z == 0) ? QSCALE2 : 1.0f;
#pragma unroll
        for (int mt = 0; mt < 4; ++mt)
#pragma unroll
            for (int nt = 0; nt < 4; ++nt)
#pragma unroll
                for (int r = 0; r < 4; ++r) {
                    int row = m0 + wr * 64 + mt * 16 + quad * 4 + r;
                    int col = n0 + wc * 64 + nt * 16 + lr;
                    Out[(size_t)row * DIMC + col] = f2bf(acc[mt][nt][r] * sc);
                }
    }
}

__global__ __launch_bounds__(256) void gemm_out_f32(
    const unsigned short* __restrict__ A, const float* __restrict__ Wp,
    const float* __restrict__ bias, float* __restrict__ out)
{
    __shared__ unsigned short As[128 * AST];
    __shared__ unsigned short Bs[128 * AST];

    const int t  = threadIdx.x;
    const int n0 = blockIdx.x * 128, m0 = blockIdx.y * 128;
    const int w = t >> 6, l = t & 63, quad = l >> 4, lr = l & 15;
    const int wr = w >> 1, wc = w & 1;

    f32x4 acc[4][4];
#pragma unroll
    for (int mt = 0; mt < 4; ++mt)
#pragma unroll
        for (int nt = 0; nt < 4; ++nt)
#pragma unroll
            for (int r = 0; r < 4; ++r) acc[mt][nt][r] = 0.f;

    for (int kt = 0; kt < DIMC; kt += 64) {
        __syncthreads();
#pragma unroll
        for (int i = 0; i < 8; ++i) {
            int flat = t + i * 256;
            int row = flat >> 4, seg = flat & 15;
            ushort4 a = *(const ushort4*)(A + (size_t)(m0 + row) * DIMC + kt + seg * 4);
            *(ushort4*)&As[row * AST + seg * 4] = a;
            float4 b = *(const float4*)(Wp + (size_t)(n0 + row) * DIMC + kt + seg * 4);
            ushort4 pb; pb.x = f2bf(b.x); pb.y = f2bf(b.y); pb.z = f2bf(b.z); pb.w = f2bf(b.w);
            *(ushort4*)&Bs[row * AST + seg * 4] = pb;
        }
        __syncthreads();
#pragma unroll
        for (int kk = 0; kk < 2; ++kk) {
            bf16x8 af[4], bfr[4];
#pragma unroll
            for (int mt = 0; mt < 4; ++mt)
                af[mt] = *(const bf16x8*)&As[(wr * 64 + mt * 16 + lr) * AST + kk * 32 + quad * 8];
#pragma unroll
            for (int nt = 0; nt < 4; ++nt)
                bfr[nt] = *(const bf16x8*)&Bs[(wc * 64 + nt * 16 + lr) * AST + kk * 32 + quad * 8];
#pragma unroll
            for (int mt = 0; mt < 4; ++mt)
#pragma unroll
                for (int nt = 0; nt < 4; ++nt)
                    acc[mt][nt] = __builtin_amdgcn_mfma_f32_16x16x32_bf16(af[mt], bfr[nt], acc[mt][nt], 0, 0, 0);
        }
    }

#pragma unroll
    for (int mt = 0; mt < 4; ++mt)
#pragma unroll
        for (int nt = 0; nt < 4; ++nt)
#pragma unroll
            for (int r = 0; r < 4; ++r) {
                int row = m0 + wr * 64 + mt * 16 + quad * 4 + r;
                int col = n0 + wc * 64 + nt * 16 + lr;
                out[(size_t)row * DIMC + col] = acc[mt][nt][r] + bias[col];
            }
}

// ---------------------------------------------------------------------------
extern "C" void kernel_launch(void* const* d_in, const int* in_sizes, int n_in,
                              void* d_out, int out_size, void* d_ws, size_t ws_size,
                              hipStream_t stream)
{
    const float* x  = (const float*)d_in[0];
    const float* Wq = (const float*)d_in[1];
    const float* Wk = (const float*)d_in[2];
    const float* Wv = (const float*)d_in[3];
    const float* Wp = (const float*)d_in[4];
    const float* bp = (const float*)d_in[5];
    float* out = (float*)d_out;

    const size_t SZ  = (size_t)MROWS * DIMC;   // 4M elems
    const size_t WSZ = (size_t)DIMC * DIMC;    // 1M elems
    const size_t need = (4 * SZ + 4 * WSZ) * sizeof(unsigned short);  // 40 MB

    if (ws_size >= need) {
        unsigned short* q  = (unsigned short*)d_ws;
        unsigned short* k  = q + SZ;
        unsigned short* vt = k + SZ;
        unsigned short* o  = vt + SZ;
        unsigned short* Wb = o + SZ;
        unsigned short* xb = (unsigned short*)d_out;   // scratch: dead before gemm_out writes

        cast_all<<<dim3(1024, 8), 256, 0, stream>>>(x, Wq, Wk, Wv, Wp, xb, Wb);
        gemm_qkv_fast<<<dim3(DIMC / 128, MROWS / 128, 3), 256, 0, stream>>>(xb, Wb, q, k, vt);
        attn_kernel<<<dim3(1024), 256, 0, stream>>>(q, k, vt, o);
        gemm_out_fast<<<dim3(DIMC / 128, MROWS / 128), 256, 0, stream>>>(o, Wb + 3 * WSZ, bp, out);
    } else {
        unsigned short* q  = (unsigned short*)d_ws;
        unsigned short* k  = q + SZ;
        unsigned short* vt = k + SZ;
        unsigned short* o  = vt + SZ;

        gemm_qkv_f32<<<dim3(DIMC / 128, MROWS / 128, 3), 256, 0, stream>>>(x, Wq, Wk, Wv, q, k, vt);
        attn_kernel<<<dim3(1024), 256, 0, stream>>>(q, k, vt, o);
        gemm_out_f32<<<dim3(DIMC / 128, MROWS / 128), 256, 0, stream>>>(o, Wp, bp, out);
    }
}

// Round 6
// 195.272 us; speedup vs baseline: 1.0103x; 1.0103x over previous
//
#include <hip/hip_runtime.h>
#include <cstdint>

#define DIMC   1024
#define NHEADS 16
#define HD     64
#define BATCH  2
#define SEQ    2048
#define MROWS  (BATCH*SEQ)   // 4096
// Q pre-scale: (1/sqrt(64)) * log2(e)  -> softmax computed in base 2 (exact)
#define QSCALE2 0.18033688f

typedef __bf16 bf16x8 __attribute__((ext_vector_type(8)));
typedef float  f32x4  __attribute__((ext_vector_type(4)));
typedef float  f32x16 __attribute__((ext_vector_type(16)));

#define AST 88    // fallback LDS row stride (bf16 elems)
#define TST 136   // transpose-epilogue LDS stride
#define PST 40    // Ps row stride (shorts): 80 B -> col*20 mod 32 covers all
                  // multiples of 4 -> full 32-bank coverage for even chunks

__device__ __forceinline__ unsigned short f2bf(float f) {
    union { float f; unsigned int u; } v; v.f = f;
    unsigned int u = v.u;
    u += 0x7fffu + ((u >> 16) & 1u);   // round-to-nearest-even
    return (unsigned short)(u >> 16);
}

// pack two floats to bf16x2 (round-nearest, ties away): 2 adds + 1 v_perm
__device__ __forceinline__ unsigned int pk2bf(float a, float b) {
    union { float f; unsigned int u; } ua, ub;
    ua.f = a; ub.f = b;
    return __builtin_amdgcn_perm(ub.u + 0x8000u, ua.u + 0x8000u, 0x07060302u);
}

__device__ __forceinline__ void gload_lds16(const void* g, void* l) {
    __builtin_amdgcn_global_load_lds(
        (const __attribute__((address_space(1))) unsigned int*)g,
        (__attribute__((address_space(3))) unsigned int*)l, 16, 0, 0);
}

// ---------------------------------------------------------------------------
// Pre-cast fp32 -> bf16: x (4M elems) and Wq|Wk|Wv|Wp (1M each) into xb / Wb.
// ---------------------------------------------------------------------------
__global__ __launch_bounds__(256) void cast_all(
    const float* __restrict__ x,
    const float* __restrict__ Wq, const float* __restrict__ Wk,
    const float* __restrict__ Wv, const float* __restrict__ Wp,
    unsigned short* __restrict__ xb, unsigned short* __restrict__ Wb)
{
    const size_t M1 = (size_t)DIMC * DIMC;   // 1M elems
    int y = blockIdx.y;
    const float* src;
    unsigned short* dst;
    if (y < 4)      { src = x  + (size_t)y * M1; dst = xb + (size_t)y * M1; }
    else if (y == 4){ src = Wq; dst = Wb; }
    else if (y == 5){ src = Wk; dst = Wb + M1; }
    else if (y == 6){ src = Wv; dst = Wb + 2 * M1; }
    else            { src = Wp; dst = Wb + 3 * M1; }
    size_t idx = ((size_t)blockIdx.x * 256 + threadIdx.x) * 4;
    float4 v = *(const float4*)(src + idx);
    ushort4 p; p.x = f2bf(v.x); p.y = f2bf(v.y); p.z = f2bf(v.z); p.w = f2bf(v.w);
    *(ushort4*)(dst + idx) = p;
}

// ---------------------------------------------------------------------------
// Pipelined GEMM building blocks (issue-after-barrier pattern).
// 128x128 tile, BK=64, 4 waves; LDS double-buffered (4 x 16 KB).
// ---------------------------------------------------------------------------
__device__ __forceinline__ void gemm_issue(
    const unsigned short* __restrict__ A, const unsigned short* __restrict__ B,
    unsigned short* As, unsigned short* Bs, int m0, int n0, int kt)
{
    const int t = threadIdx.x;
    const int w = t >> 6, lane = t & 63;
    const int srow = lane >> 3, scol = lane & 7;
#pragma unroll
    for (int i = 0; i < 4; ++i) {
        int r  = i * 32 + w * 8 + srow;        // 0..127
        int cg = scol ^ (r & 7);               // swizzled source chunk
        gload_lds16(A + (size_t)(m0 + r) * DIMC + kt + cg * 8, As + r * 64 + scol * 8);
        gload_lds16(B + (size_t)(n0 + r) * DIMC + kt + cg * 8, Bs + r * 64 + scol * 8);
    }
}

__device__ __forceinline__ void gemm_compute(
    const unsigned short* As, const unsigned short* Bs, f32x4 acc[4][4])
{
    const int t = threadIdx.x;
    const int w = t >> 6, lane = t & 63, quad = lane >> 4, lr = lane & 15;
    const int wr = w >> 1, wc = w & 1;
#pragma unroll
    for (int kk = 0; kk < 2; ++kk) {
        bf16x8 af[4], bfr[4];
#pragma unroll
        for (int mt = 0; mt < 4; ++mt) {
            int row = wr * 64 + mt * 16 + lr;
            int cb  = kk * 4 + quad;
            af[mt] = *(const bf16x8*)&As[row * 64 + (cb ^ (row & 7)) * 8];
        }
#pragma unroll
        for (int nt = 0; nt < 4; ++nt) {
            int row = wc * 64 + nt * 16 + lr;
            int cb  = kk * 4 + quad;
            bfr[nt] = *(const bf16x8*)&Bs[row * 64 + (cb ^ (row & 7)) * 8];
        }
#pragma unroll
        for (int mt = 0; mt < 4; ++mt)
#pragma unroll
            for (int nt = 0; nt < 4; ++nt)
                acc[mt][nt] = __builtin_amdgcn_mfma_f32_16x16x32_bf16(af[mt], bfr[nt], acc[mt][nt], 0, 0, 0);
    }
}

// Full pipelined K-loop: one __syncthreads per tile; prefetch issued after the
// barrier into the other buffer stays in flight across the compute phase.
__device__ __forceinline__ void gemm_k_loop_db(
    const unsigned short* __restrict__ A, const unsigned short* __restrict__ B,
    unsigned short* smem, int m0, int n0, f32x4 acc[4][4])
{
    unsigned short* As0 = smem;
    unsigned short* Bs0 = smem + 8192;
    unsigned short* As1 = smem + 16384;
    unsigned short* Bs1 = smem + 24576;

    gemm_issue(A, B, As0, Bs0, m0, n0, 0);
    for (int kt = 0; kt < DIMC; kt += 128) {
        __syncthreads();                       // publish As0/Bs0 (DMA had full
        gemm_issue(A, B, As1, Bs1, m0, n0, kt + 64);   //  compute phase in flight)
        gemm_compute(As0, Bs0, acc);
        __syncthreads();                       // publish As1/Bs1
        if (kt + 128 < DIMC) gemm_issue(A, B, As0, Bs0, m0, n0, kt + 128);
        gemm_compute(As1, Bs1, acc);
    }
}

// vT transpose epilogue: stage C-tile transposed in LDS, then coalesced
// 16B global stores to vT[b][h][d][n].
__device__ __forceinline__ void vt_epilogue(
    unsigned short* Ts, f32x4 acc[4][4], int m0, int n0,
    unsigned short* __restrict__ vT)
{
    const int t = threadIdx.x;
    const int w = t >> 6, lane = t & 63, quad = lane >> 4, lr = lane & 15;
    const int wr = w >> 1, wc = w & 1;

    __syncthreads();
#pragma unroll
    for (int mt = 0; mt < 4; ++mt)
#pragma unroll
        for (int nt = 0; nt < 4; ++nt) {
            int lcol  = wc * 64 + nt * 16 + lr;
            int lrow0 = wr * 64 + mt * 16 + quad * 4;
            ushort4 p;
            p.x = f2bf(acc[mt][nt][0]); p.y = f2bf(acc[mt][nt][1]);
            p.z = f2bf(acc[mt][nt][2]); p.w = f2bf(acc[mt][nt][3]);
            *(ushort4*)&Ts[lcol * TST + lrow0] = p;
        }
    __syncthreads();

    int lc = t >> 1, half = t & 1;
    int cg = n0 + lc, hh = cg >> 6, dd = cg & 63;
    int bb = m0 >> 11, nn0 = m0 & (SEQ - 1);
    size_t dst = ((size_t)((bb * NHEADS + hh) * HD + dd)) * SEQ + nn0 + half * 64;
    const unsigned short* srcp = &Ts[lc * TST + half * 64];
#pragma unroll
    for (int i = 0; i < 8; ++i)
        *(uint4*)&vT[dst + i * 8] = *(const uint4*)&srcp[i * 8];
}

// ---------------------------------------------------------------------------
// Fast QKV projection (pipelined): z=0 -> q (scaled), z=1 -> k, z=2 -> vT.
// ---------------------------------------------------------------------------
__global__ __launch_bounds__(256) void gemm_qkv_fast(
    const unsigned short* __restrict__ xb, const unsigned short* __restrict__ Wb,
    unsigned short* __restrict__ qo, unsigned short* __restrict__ ko,
    unsigned short* __restrict__ vT)
{
    __shared__ unsigned short smem[32768];   // 64 KB: 4 x 16 KB buffers

    const int t  = threadIdx.x;
    const int n0 = blockIdx.x * 128, m0 = blockIdx.y * 128, z = blockIdx.z;
    const unsigned short* B = Wb + (size_t)z * DIMC * DIMC;
    const int w = t >> 6, lane = t & 63, quad = lane >> 4, lr = lane & 15;
    const int wr = w >> 1, wc = w & 1;

    f32x4 acc[4][4];
#pragma unroll
    for (int mt = 0; mt < 4; ++mt)
#pragma unroll
        for (int nt = 0; nt < 4; ++nt)
#pragma unroll
            for (int r = 0; r < 4; ++r) acc[mt][nt][r] = 0.f;

    gemm_k_loop_db(xb, B, smem, m0, n0, acc);

    if (z == 2) {
        vt_epilogue(smem, acc, m0, n0, vT);
    } else {
        unsigned short* Out = (z == 0) ? qo : ko;
        const float sc = (z == 0) ? QSCALE2 : 1.0f;
#pragma unroll
        for (int mt = 0; mt < 4; ++mt)
#pragma unroll
            for (int nt = 0; nt < 4; ++nt)
#pragma unroll
                for (int r = 0; r < 4; ++r) {
                    int row = m0 + wr * 64 + mt * 16 + quad * 4 + r;
                    int col = n0 + wc * 64 + nt * 16 + lr;
                    Out[(size_t)row * DIMC + col] = f2bf(acc[mt][nt][r] * sc);
                }
    }
}

// ---------------------------------------------------------------------------
// Fast output projection (pipelined).
// ---------------------------------------------------------------------------
__global__ __launch_bounds__(256) void gemm_out_fast(
    const unsigned short* __restrict__ O, const unsigned short* __restrict__ Wpb,
    const float* __restrict__ bias, float* __restrict__ out)
{
    __shared__ unsigned short smem[32768];   // 64 KB: 4 x 16 KB buffers

    const int t  = threadIdx.x;
    const int n0 = blockIdx.x * 128, m0 = blockIdx.y * 128;
    const int w = t >> 6, lane = t & 63, quad = lane >> 4, lr = lane & 15;
    const int wr = w >> 1, wc = w & 1;

    f32x4 acc[4][4];
#pragma unroll
    for (int mt = 0; mt < 4; ++mt)
#pragma unroll
        for (int nt = 0; nt < 4; ++nt)
#pragma unroll
            for (int r = 0; r < 4; ++r) acc[mt][nt][r] = 0.f;

    gemm_k_loop_db(O, Wpb, smem, m0, n0, acc);

#pragma unroll
    for (int mt = 0; mt < 4; ++mt)
#pragma unroll
        for (int nt = 0; nt < 4; ++nt)
#pragma unroll
            for (int r = 0; r < 4; ++r) {
                int row = m0 + wr * 64 + mt * 16 + quad * 4 + r;
                int col = n0 + wc * 64 + nt * 16 + lr;
                out[(size_t)row * DIMC + col] = acc[mt][nt][r] + bias[col];
            }
}

// ---------------------------------------------------------------------------
// Flash attention v16: v15 (passing) + Ps bank-conflict fix.
//   R5 post-mortem: conflicts 2.1M -> 13.6M because Ps row stride 64 B puts
//   col*16 mod 32 in {0,16} and the (required-even) chunk positions land all
//   pf reads on banks {0-3,8-11,16-19,24-27} only (half coverage, 2x serial).
//   Fix (arithmetic, not guesswork):
//   - PST=40 shorts (80 B, 16B-aligned): col*20 mod 32 covers every multiple
//     of 4 over col mod 8 -> reads hit all 32 banks uniformly (8 dwords/bank
//     = floor).
//   - pkey = ((col&3) ^ ((col>>3)&3)) << 1: still even (chunk pairs stay
//     adjacent -> correctness scheme byte-identical to v15), but distinct
//     within each same-bank-base lane group -> conflict-free writes too.
//   LDS = 32 KB K/V dbuf + 10 KB Ps = 42 KB -> 3 blocks/CU (12 waves/CU;
//   R2/R3 showed >8 waves/CU buys nothing while traffic-bound).
// ---------------------------------------------------------------------------
__global__ __launch_bounds__(256, 3) void attn_kernel(
    const unsigned short* __restrict__ qg, const unsigned short* __restrict__ kg,
    const unsigned short* __restrict__ vT, unsigned short* __restrict__ og)
{
    __shared__ unsigned short smem[21504];   // 42 KB
    unsigned short* Ka = smem;               //  8 KB each (64x64 bf16)
    unsigned short* Kb = smem + 4096;
    unsigned short* Va = smem + 8192;
    unsigned short* Vb = smem + 12288;
    unsigned short* Ps = smem + 16384;       // 10 KB: 4 x (32q x PST)

    const int t  = threadIdx.x;
    const int w = t >> 6, l = t & 63;
    const int col = l & 31, hi = l >> 5;      // 32x32 fragment coords
    const int qh = w >> 1, kvh = w & 1;       // q-half / kv-half of the wave
    const int srow = t >> 3, scol = t & 7;    // staging coords (srow 0..31)
    // even key (keeps chunk pairs adjacent for 16B reads); varies with both
    // col&3 and col>>3 so same-bank-base lane groups get distinct positions
    const int pkey = (((col & 3) ^ ((col >> 3) & 3)) << 1);

    unsigned short* PsW = Ps + w * (32 * PST); // wave-private P tile

    // XCD-aware mapping: bid&7 = XCD; each XCD owns 4 full (b,h) pairs
    // (32 q-tiles of 64 rows each) -> K/V head stays L2-local.
    const int bid  = blockIdx.x;              // 0..1023
    const int slot = bid >> 3;                // 0..127
    const int bh   = (bid & 7) * 4 + (slot >> 5);
    const int qt   = slot & 31;               // 64-row Q tile index
    const int b    = bh >> 4, h = bh & 15;

    const unsigned short* khead = kg + ((size_t)(b * SEQ)) * DIMC + h * HD;
    const unsigned short* vhead = vT + (size_t)((b * NHEADS + h) * HD) * SEQ;

    // Q B-fragments (pre-scaled by QSCALE2): col -> q row, d = ks*16+hi*8+j
    bf16x8 qf[4];
    {
        const size_t qoff = ((size_t)(b * SEQ + qt * 64 + qh * 32 + col)) * DIMC + h * HD + hi * 8;
#pragma unroll
        for (int ks = 0; ks < 4; ++ks)
            qf[ks] = *(const bf16x8*)(qg + qoff + ks * 16);
    }

    bf16x8 ones;
#pragma unroll
    for (int j = 0; j < 8; ++j) ones[j] = (__bf16)1.0f;

    f32x16 o0, o1, lac;
#pragma unroll
    for (int r = 0; r < 16; ++r) { o0[r] = 0.f; o1[r] = 0.f; lac[r] = 0.f; }

    // K rows (kv) and V rows (d) staged with the v10 XOR swizzle (unchanged).
    auto issue = [&](int kt, unsigned short* Kd, unsigned short* Vd) {
#pragma unroll
        for (int i = 0; i < 2; ++i) {
            int r  = i * 32 + srow;            // 0..63
            int cg = scol ^ (r & 7);
            gload_lds16(khead + (size_t)(kt * 64 + r) * DIMC + cg * 8, Kd + r * 64 + scol * 8);
            gload_lds16(vhead + (size_t)r * SEQ + kt * 64 + cg * 8,   Vd + r * 64 + scol * 8);
        }
    };

    auto phase = [&](const unsigned short* Kc, const unsigned short* Vc) {
        // --- S = K . Q^T over this wave's 32-kv half (rows=kv, cols=q) ---
        f32x16 s;
#pragma unroll
        for (int r = 0; r < 16; ++r) s[r] = 0.f;
#pragma unroll
        for (int ks = 0; ks < 4; ++ks) {
            int r = kvh * 32 + col;                       // kv row in tile
            int c = ks * 2 + hi;                          // source d-chunk
            bf16x8 kf = *(const bf16x8*)&Kc[r * 64 + ((c ^ (r & 7)) * 8)];
            s = __builtin_amdgcn_mfma_f32_32x32x16_bf16(kf, qf[ks], s, 0, 0, 0);
        }

        // --- V B-frags (independent of s: issue early) ---
        bf16x8 vf[2][2];
#pragma unroll
        for (int dt = 0; dt < 2; ++dt)
#pragma unroll
            for (int ks2 = 0; ks2 < 2; ++ks2) {
                int r = dt * 32 + col;                    // d row of vT tile
                int c = kvh * 4 + ks2 * 2 + hi;           // source kv-chunk
                vf[dt][ks2] = *(const bf16x8*)&Vc[r * 64 + ((c ^ (r & 7)) * 8)];
            }

        // --- p = 2^s -> bf16 pairs -> LDS (8B chunks of 4 consecutive kv) ---
        // s[reg] = S[kv-rel = (reg&3)+8*(reg>>2)+4*hi][q = col]; pairs
        // {pk[2i],pk[2i+1]} cover kv {8i+4hi .. 8i+4hi+3} = chunk cw=2i+hi.
        unsigned int pk[8];
#pragma unroll
        for (int i = 0; i < 8; ++i)
            pk[i] = pk2bf(__builtin_amdgcn_exp2f(s[2 * i]),
                          __builtin_amdgcn_exp2f(s[2 * i + 1]));
#pragma unroll
        for (int i2 = 0; i2 < 4; ++i2) {
            int cw = i2 * 2 + hi;
            uint2 pp; pp.x = pk[2 * i2]; pp.y = pk[2 * i2 + 1];
            *(uint2*)&PsW[col * PST + ((cw ^ pkey) << 2)] = pp;
        }

        // --- PV A-frags from LDS: q row = col, slots j -> kv 8hi+j (+16) ---
        bf16x8 pf0 = *(const bf16x8*)&PsW[col * PST + (((2 * hi) ^ pkey) << 2)];
        bf16x8 pf1 = *(const bf16x8*)&PsW[col * PST + (((4 + 2 * hi) ^ pkey) << 2)];

        // --- l += P.1 ; O += P.V  (rows=q: matches final store) ---
        lac = __builtin_amdgcn_mfma_f32_32x32x16_bf16(pf0, ones, lac, 0, 0, 0);
        lac = __builtin_amdgcn_mfma_f32_32x32x16_bf16(pf1, ones, lac, 0, 0, 0);
        o0  = __builtin_amdgcn_mfma_f32_32x32x16_bf16(pf0, vf[0][0], o0, 0, 0, 0);
        o0  = __builtin_amdgcn_mfma_f32_32x32x16_bf16(pf1, vf[0][1], o0, 0, 0, 0);
        o1  = __builtin_amdgcn_mfma_f32_32x32x16_bf16(pf0, vf[1][0], o1, 0, 0, 0);
        o1  = __builtin_amdgcn_mfma_f32_32x32x16_bf16(pf1, vf[1][1], o1, 0, 0, 0);
    };

    issue(0, Ka, Va);
    for (int kt = 0; kt < SEQ / 64; kt += 2) {
        __syncthreads();                      // publish Ka/Va(kt)
        issue(kt + 1, Kb, Vb);
        phase(Ka, Va);
        __syncthreads();                      // publish Kb/Vb(kt+1)
        if (kt + 2 < SEQ / 64) issue(kt + 2, Ka, Va);
        phase(Kb, Vb);
    }

    // --- merge kv-halves (O and l simply add: un-normalized exp2 softmax) ---
    __syncthreads();                          // all waves done with K/V/Ps
    float* mrg = (float*)smem;                // 128 lanes x 49-f32 stride ~ 25 KB
    if (kvh == 1) {
        float* dst = mrg + (qh * 64 + l) * 49;
#pragma unroll
        for (int r = 0; r < 16; ++r) {
            dst[r] = o0[r]; dst[16 + r] = o1[r]; dst[32 + r] = lac[r];
        }
    }
    __syncthreads();
    if (kvh == 0) {
        const float* src = mrg + (qh * 64 + l) * 49;
        float inv[16];
#pragma unroll
        for (int r = 0; r < 16; ++r) {
            o0[r] += src[r]; o1[r] += src[16 + r];
            inv[r] = 1.0f / (lac[r] + src[32 + r]);
        }
#pragma unroll
        for (int r = 0; r < 16; ++r) {
            int qrow = qt * 64 + qh * 32 + (r & 3) + 8 * (r >> 2) + 4 * hi;
            size_t base = ((size_t)(b * SEQ + qrow)) * DIMC + h * HD;
            og[base + col]      = f2bf(o0[r] * inv[r]);
            og[base + 32 + col] = f2bf(o1[r] * inv[r]);
        }
    }
}

// ---------------------------------------------------------------------------
// Fallback path (ws < 40 MB): fp32-staging GEMMs.
// ---------------------------------------------------------------------------
__global__ __launch_bounds__(256) void gemm_qkv_f32(
    const float* __restrict__ x,
    const float* __restrict__ Wq, const float* __restrict__ Wk, const float* __restrict__ Wv,
    unsigned short* __restrict__ qo, unsigned short* __restrict__ ko, unsigned short* __restrict__ vT)
{
    __shared__ unsigned short smem[2 * 128 * AST];
    unsigned short* As = smem;
    unsigned short* Bs = smem + 128 * AST;

    const int t  = threadIdx.x;
    const int n0 = blockIdx.x * 128, m0 = blockIdx.y * 128, z = blockIdx.z;
    const float* W = (z == 0) ? Wq : (z == 1) ? Wk : Wv;
    const int w = t >> 6, l = t & 63, quad = l >> 4, lr = l & 15;
    const int wr = w >> 1, wc = w & 1;

    f32x4 acc[4][4];
#pragma unroll
    for (int mt = 0; mt < 4; ++mt)
#pragma unroll
        for (int nt = 0; nt < 4; ++nt)
#pragma unroll
            for (int r = 0; r < 4; ++r) acc[mt][nt][r] = 0.f;

    for (int kt = 0; kt < DIMC; kt += 64) {
        __syncthreads();
#pragma unroll
        for (int i = 0; i < 8; ++i) {
            int flat = t + i * 256;
            int row = flat >> 4, seg = flat & 15;
            float4 a = *(const float4*)(x + (size_t)(m0 + row) * DIMC + kt + seg * 4);
            ushort4 pa; pa.x = f2bf(a.x); pa.y = f2bf(a.y); pa.z = f2bf(a.z); pa.w = f2bf(a.w);
            *(ushort4*)&As[row * AST + seg * 4] = pa;
            float4 b = *(const float4*)(W + (size_t)(n0 + row) * DIMC + kt + seg * 4);
            ushort4 pb; pb.x = f2bf(b.x); pb.y = f2bf(b.y); pb.z = f2bf(b.z); pb.w = f2bf(b.w);
            *(ushort4*)&Bs[row * AST + seg * 4] = pb;
        }
        __syncthreads();
#pragma unroll
        for (int kk = 0; kk < 2; ++kk) {
            bf16x8 af[4], bfr[4];
#pragma unroll
            for (int mt = 0; mt < 4; ++mt)
                af[mt] = *(const bf16x8*)&As[(wr * 64 + mt * 16 + lr) * AST + kk * 32 + quad * 8];
#pragma unroll
            for (int nt = 0; nt < 4; ++nt)
                bfr[nt] = *(const bf16x8*)&Bs[(wc * 64 + nt * 16 + lr) * AST + kk * 32 + quad * 8];
#pragma unroll
            for (int mt = 0; mt < 4; ++mt)
#pragma unroll
                for (int nt = 0; nt < 4; ++nt)
                    acc[mt][nt] = __builtin_amdgcn_mfma_f32_16x16x32_bf16(af[mt], bfr[nt], acc[mt][nt], 0, 0, 0);
        }
    }

    if (z == 2) {
        __syncthreads();
#pragma unroll
        for (int mt = 0; mt < 4; ++mt)
#pragma unroll
            for (int nt = 0; nt < 4; ++nt) {
                int lcol  = wc * 64 + nt * 16 + lr;
                int lrow0 = wr * 64 + mt * 16 + quad * 4;
                ushort4 p;
                p.x = f2bf(acc[mt][nt][0]); p.y = f2bf(acc[mt][nt][1]);
                p.z = f2bf(acc[mt][nt][2]); p.w = f2bf(acc[mt][nt][3]);
                *(ushort4*)&smem[lcol * TST + lrow0] = p;
            }
        __syncthreads();
        int lc = t >> 1, half = t & 1;
        int cg = n0 + lc, hh = cg >> 6, dd = cg & 63;
        int bb = m0 >> 11, nn0 = m0 & (SEQ - 1);
        size_t dst = ((size_t)((bb * NHEADS + hh) * HD + dd)) * SEQ + nn0 + half * 64;
        const unsigned short* srcp = &smem[lc * TST + half * 64];
#pragma unroll
        for (int i = 0; i < 8; ++i)
            *(uint4*)&vT[dst + i * 8] = *(const uint4*)&srcp[i * 8];
    } else {
        unsigned short* Out = (z == 0) ? qo : ko;
        const float sc = (z == 0) ? QSCALE2 : 1.0f;
#pragma unroll
        for (int mt = 0; mt < 4; ++mt)
#pragma unroll
            for (int nt = 0; nt < 4; ++nt)
#pragma unroll
                for (int r = 0; r < 4; ++r) {
                    int row = m0 + wr * 64 + mt * 16 + quad * 4 + r;
                    int col = n0 + wc * 64 + nt * 16 + lr;
                    Out[(size_t)row * DIMC + col] = f2bf(acc[mt][nt][r] * sc);
                }
    }
}

__global__ __launch_bounds__(256) void gemm_out_f32(
    const unsigned short* __restrict__ A, const float* __restrict__ Wp,
    const float* __restrict__ bias, float* __restrict__ out)
{
    __shared__ unsigned short As[128 * AST];
    __shared__ unsigned short Bs[128 * AST];

    const int t  = threadIdx.x;
    const int n0 = blockIdx.x * 128, m0 = blockIdx.y * 128;
    const int w = t >> 6, l = t & 63, quad = l >> 4, lr = l & 15;
    const int wr = w >> 1, wc = w & 1;

    f32x4 acc[4][4];
#pragma unroll
    for (int mt = 0; mt < 4; ++mt)
#pragma unroll
        for (int nt = 0; nt < 4; ++nt)
#pragma unroll
            for (int r = 0; r < 4; ++r) acc[mt][nt][r] = 0.f;

    for (int kt = 0; kt < DIMC; kt += 64) {
        __syncthreads();
#pragma unroll
        for (int i = 0; i < 8; ++i) {
            int flat = t + i * 256;
            int row = flat >> 4, seg = flat & 15;
            ushort4 a = *(const ushort4*)(A + (size_t)(m0 + row) * DIMC + kt + seg * 4);
            *(ushort4*)&As[row * AST + seg * 4] = a;
            float4 b = *(const float4*)(Wp + (size_t)(n0 + row) * DIMC + kt + seg * 4);
            ushort4 pb; pb.x = f2bf(b.x); pb.y = f2bf(b.y); pb.z = f2bf(b.z); pb.w = f2bf(b.w);
            *(ushort4*)&Bs[row * AST + seg * 4] = pb;
        }
        __syncthreads();
#pragma unroll
        for (int kk = 0; kk < 2; ++kk) {
            bf16x8 af[4], bfr[4];
#pragma unroll
            for (int mt = 0; mt < 4; ++mt)
                af[mt] = *(const bf16x8*)&As[(wr * 64 + mt * 16 + lr) * AST + kk * 32 + quad * 8];
#pragma unroll
            for (int nt = 0; nt < 4; ++nt)
                bfr[nt] = *(const bf16x8*)&Bs[(wc * 64 + nt * 16 + lr) * AST + kk * 32 + quad * 8];
#pragma unroll
            for (int mt = 0; mt < 4; ++mt)
#pragma unroll
                for (int nt = 0; nt < 4; ++nt)
                    acc[mt][nt] = __builtin_amdgcn_mfma_f32_16x16x32_bf16(af[mt], bfr[nt], acc[mt][nt], 0, 0, 0);
        }
    }

#pragma unroll
    for (int mt = 0; mt < 4; ++mt)
#pragma unroll
        for (int nt = 0; nt < 4; ++nt)
#pragma unroll
            for (int r = 0; r < 4; ++r) {
                int row = m0 + wr * 64 + mt * 16 + quad * 4 + r;
                int col = n0 + wc * 64 + nt * 16 + lr;
                out[(size_t)row * DIMC + col] = acc[mt][nt][r] + bias[col];
            }
}

// ---------------------------------------------------------------------------
extern "C" void kernel_launch(void* const* d_in, const int* in_sizes, int n_in,
                              void* d_out, int out_size, void* d_ws, size_t ws_size,
                              hipStream_t stream)
{
    const float* x  = (const float*)d_in[0];
    const float* Wq = (const float*)d_in[1];
    const float* Wk = (const float*)d_in[2];
    const float* Wv = (const float*)d_in[3];
    const float* Wp = (const float*)d_in[4];
    const float* bp = (const float*)d_in[5];
    float* out = (float*)d_out;

    const size_t SZ  = (size_t)MROWS * DIMC;   // 4M elems
    const size_t WSZ = (size_t)DIMC * DIMC;    // 1M elems
    const size_t need = (4 * SZ + 4 * WSZ) * sizeof(unsigned short);  // 40 MB

    if (ws_size >= need) {
        unsigned short* q  = (unsigned short*)d_ws;
        unsigned short* k  = q + SZ;
        unsigned short* vt = k + SZ;
        unsigned short* o  = vt + SZ;
        unsigned short* Wb = o + SZ;
        unsigned short* xb = (unsigned short*)d_out;   // scratch: dead before gemm_out writes

        cast_all<<<dim3(1024, 8), 256, 0, stream>>>(x, Wq, Wk, Wv, Wp, xb, Wb);
        gemm_qkv_fast<<<dim3(DIMC / 128, MROWS / 128, 3), 256, 0, stream>>>(xb, Wb, q, k, vt);
        attn_kernel<<<dim3(1024), 256, 0, stream>>>(q, k, vt, o);
        gemm_out_fast<<<dim3(DIMC / 128, MROWS / 128), 256, 0, stream>>>(o, Wb + 3 * WSZ, bp, out);
    } else {
        unsigned short* q  = (unsigned short*)d_ws;
        unsigned short* k  = q + SZ;
        unsigned short* vt = k + SZ;
        unsigned short* o  = vt + SZ;

        gemm_qkv_f32<<<dim3(DIMC / 128, MROWS / 128, 3), 256, 0, stream>>>(x, Wq, Wk, Wv, q, k, vt);
        attn_kernel<<<dim3(1024), 256, 0, stream>>>(q, k, vt, o);
        gemm_out_f32<<<dim3(DIMC / 128, MROWS / 128), 256, 0, stream>>>(o, Wp, bp, out);
    }
}

// Round 7
// 189.392 us; speedup vs baseline: 1.0417x; 1.0310x over previous
//
#include <hip/hip_runtime.h>
#include <cstdint>

#define DIMC   1024
#define NHEADS 16
#define HD     64
#define BATCH  2
#define SEQ    2048
#define MROWS  (BATCH*SEQ)   // 4096
// Q pre-scale: (1/sqrt(64)) * log2(e)  -> softmax computed in base 2 (exact)
#define QSCALE2 0.18033688f

typedef __bf16 bf16x8 __attribute__((ext_vector_type(8)));
typedef float  f32x4  __attribute__((ext_vector_type(4)));
typedef float  f32x16 __attribute__((ext_vector_type(16)));

#define AST 88    // fallback LDS row stride (bf16 elems)
#define TST 136   // transpose-epilogue LDS stride

__device__ __forceinline__ unsigned short f2bf(float f) {
    union { float f; unsigned int u; } v; v.f = f;
    unsigned int u = v.u;
    u += 0x7fffu + ((u >> 16) & 1u);   // round-to-nearest-even
    return (unsigned short)(u >> 16);
}

// pack two floats to bf16x2 (round-nearest, ties away): 2 adds + 1 v_perm
__device__ __forceinline__ unsigned int pk2bf(float a, float b) {
    union { float f; unsigned int u; } ua, ub;
    ua.f = a; ub.f = b;
    return __builtin_amdgcn_perm(ub.u + 0x8000u, ua.u + 0x8000u, 0x07060302u);
}

__device__ __forceinline__ void gload_lds16(const void* g, void* l) {
    __builtin_amdgcn_global_load_lds(
        (const __attribute__((address_space(1))) unsigned int*)g,
        (__attribute__((address_space(3))) unsigned int*)l, 16, 0, 0);
}

// ---------------------------------------------------------------------------
// Pre-cast fp32 -> bf16: x (4M elems) and Wq|Wk|Wv|Wp (1M each) into xb / Wb.
// ---------------------------------------------------------------------------
__global__ __launch_bounds__(256) void cast_all(
    const float* __restrict__ x,
    const float* __restrict__ Wq, const float* __restrict__ Wk,
    const float* __restrict__ Wv, const float* __restrict__ Wp,
    unsigned short* __restrict__ xb, unsigned short* __restrict__ Wb)
{
    const size_t M1 = (size_t)DIMC * DIMC;   // 1M elems
    int y = blockIdx.y;
    const float* src;
    unsigned short* dst;
    if (y < 4)      { src = x  + (size_t)y * M1; dst = xb + (size_t)y * M1; }
    else if (y == 4){ src = Wq; dst = Wb; }
    else if (y == 5){ src = Wk; dst = Wb + M1; }
    else if (y == 6){ src = Wv; dst = Wb + 2 * M1; }
    else            { src = Wp; dst = Wb + 3 * M1; }
    size_t idx = ((size_t)blockIdx.x * 256 + threadIdx.x) * 4;
    float4 v = *(const float4*)(src + idx);
    ushort4 p; p.x = f2bf(v.x); p.y = f2bf(v.y); p.z = f2bf(v.z); p.w = f2bf(v.w);
    *(ushort4*)(dst + idx) = p;
}

// ---------------------------------------------------------------------------
// Pipelined GEMM building blocks (issue-after-barrier pattern).
// 128x128 tile, BK=64, 4 waves; LDS double-buffered (4 x 16 KB).
// ---------------------------------------------------------------------------
__device__ __forceinline__ void gemm_issue(
    const unsigned short* __restrict__ A, const unsigned short* __restrict__ B,
    unsigned short* As, unsigned short* Bs, int m0, int n0, int kt)
{
    const int t = threadIdx.x;
    const int w = t >> 6, lane = t & 63;
    const int srow = lane >> 3, scol = lane & 7;
#pragma unroll
    for (int i = 0; i < 4; ++i) {
        int r  = i * 32 + w * 8 + srow;        // 0..127
        int cg = scol ^ (r & 7);               // swizzled source chunk
        gload_lds16(A + (size_t)(m0 + r) * DIMC + kt + cg * 8, As + r * 64 + scol * 8);
        gload_lds16(B + (size_t)(n0 + r) * DIMC + kt + cg * 8, Bs + r * 64 + scol * 8);
    }
}

__device__ __forceinline__ void gemm_compute(
    const unsigned short* As, const unsigned short* Bs, f32x4 acc[4][4])
{
    const int t = threadIdx.x;
    const int w = t >> 6, lane = t & 63, quad = lane >> 4, lr = lane & 15;
    const int wr = w >> 1, wc = w & 1;
#pragma unroll
    for (int kk = 0; kk < 2; ++kk) {
        bf16x8 af[4], bfr[4];
#pragma unroll
        for (int mt = 0; mt < 4; ++mt) {
            int row = wr * 64 + mt * 16 + lr;
            int cb  = kk * 4 + quad;
            af[mt] = *(const bf16x8*)&As[row * 64 + (cb ^ (row & 7)) * 8];
        }
#pragma unroll
        for (int nt = 0; nt < 4; ++nt) {
            int row = wc * 64 + nt * 16 + lr;
            int cb  = kk * 4 + quad;
            bfr[nt] = *(const bf16x8*)&Bs[row * 64 + (cb ^ (row & 7)) * 8];
        }
#pragma unroll
        for (int mt = 0; mt < 4; ++mt)
#pragma unroll
            for (int nt = 0; nt < 4; ++nt)
                acc[mt][nt] = __builtin_amdgcn_mfma_f32_16x16x32_bf16(af[mt], bfr[nt], acc[mt][nt], 0, 0, 0);
    }
}

// Full pipelined K-loop: one __syncthreads per tile; prefetch issued after the
// barrier into the other buffer stays in flight across the compute phase.
__device__ __forceinline__ void gemm_k_loop_db(
    const unsigned short* __restrict__ A, const unsigned short* __restrict__ B,
    unsigned short* smem, int m0, int n0, f32x4 acc[4][4])
{
    unsigned short* As0 = smem;
    unsigned short* Bs0 = smem + 8192;
    unsigned short* As1 = smem + 16384;
    unsigned short* Bs1 = smem + 24576;

    gemm_issue(A, B, As0, Bs0, m0, n0, 0);
    for (int kt = 0; kt < DIMC; kt += 128) {
        __syncthreads();                       // publish As0/Bs0 (DMA had full
        gemm_issue(A, B, As1, Bs1, m0, n0, kt + 64);   //  compute phase in flight)
        gemm_compute(As0, Bs0, acc);
        __syncthreads();                       // publish As1/Bs1
        if (kt + 128 < DIMC) gemm_issue(A, B, As0, Bs0, m0, n0, kt + 128);
        gemm_compute(As1, Bs1, acc);
    }
}

// vT transpose epilogue: stage C-tile transposed in LDS, then coalesced
// 16B global stores to vT[b][h][d][n].
__device__ __forceinline__ void vt_epilogue(
    unsigned short* Ts, f32x4 acc[4][4], int m0, int n0,
    unsigned short* __restrict__ vT)
{
    const int t = threadIdx.x;
    const int w = t >> 6, lane = t & 63, quad = lane >> 4, lr = lane & 15;
    const int wr = w >> 1, wc = w & 1;

    __syncthreads();
#pragma unroll
    for (int mt = 0; mt < 4; ++mt)
#pragma unroll
        for (int nt = 0; nt < 4; ++nt) {
            int lcol  = wc * 64 + nt * 16 + lr;
            int lrow0 = wr * 64 + mt * 16 + quad * 4;
            ushort4 p;
            p.x = f2bf(acc[mt][nt][0]); p.y = f2bf(acc[mt][nt][1]);
            p.z = f2bf(acc[mt][nt][2]); p.w = f2bf(acc[mt][nt][3]);
            *(ushort4*)&Ts[lcol * TST + lrow0] = p;
        }
    __syncthreads();

    int lc = t >> 1, half = t & 1;
    int cg = n0 + lc, hh = cg >> 6, dd = cg & 63;
    int bb = m0 >> 11, nn0 = m0 & (SEQ - 1);
    size_t dst = ((size_t)((bb * NHEADS + hh) * HD + dd)) * SEQ + nn0 + half * 64;
    const unsigned short* srcp = &Ts[lc * TST + half * 64];
#pragma unroll
    for (int i = 0; i < 8; ++i)
        *(uint4*)&vT[dst + i * 8] = *(const uint4*)&srcp[i * 8];
}

// ---------------------------------------------------------------------------
// Fast QKV projection (pipelined): z=0 -> q (scaled), z=1 -> k, z=2 -> vT.
// ---------------------------------------------------------------------------
__global__ __launch_bounds__(256) void gemm_qkv_fast(
    const unsigned short* __restrict__ xb, const unsigned short* __restrict__ Wb,
    unsigned short* __restrict__ qo, unsigned short* __restrict__ ko,
    unsigned short* __restrict__ vT)
{
    __shared__ unsigned short smem[32768];   // 64 KB: 4 x 16 KB buffers

    const int t  = threadIdx.x;
    const int n0 = blockIdx.x * 128, m0 = blockIdx.y * 128, z = blockIdx.z;
    const unsigned short* B = Wb + (size_t)z * DIMC * DIMC;
    const int w = t >> 6, lane = t & 63, quad = lane >> 4, lr = lane & 15;
    const int wr = w >> 1, wc = w & 1;

    f32x4 acc[4][4];
#pragma unroll
    for (int mt = 0; mt < 4; ++mt)
#pragma unroll
        for (int nt = 0; nt < 4; ++nt)
#pragma unroll
            for (int r = 0; r < 4; ++r) acc[mt][nt][r] = 0.f;

    gemm_k_loop_db(xb, B, smem, m0, n0, acc);

    if (z == 2) {
        vt_epilogue(smem, acc, m0, n0, vT);
    } else {
        unsigned short* Out = (z == 0) ? qo : ko;
        const float sc = (z == 0) ? QSCALE2 : 1.0f;
#pragma unroll
        for (int mt = 0; mt < 4; ++mt)
#pragma unroll
            for (int nt = 0; nt < 4; ++nt)
#pragma unroll
                for (int r = 0; r < 4; ++r) {
                    int row = m0 + wr * 64 + mt * 16 + quad * 4 + r;
                    int col = n0 + wc * 64 + nt * 16 + lr;
                    Out[(size_t)row * DIMC + col] = f2bf(acc[mt][nt][r] * sc);
                }
    }
}

// ---------------------------------------------------------------------------
// Fast output projection (pipelined).
// ---------------------------------------------------------------------------
__global__ __launch_bounds__(256) void gemm_out_fast(
    const unsigned short* __restrict__ O, const unsigned short* __restrict__ Wpb,
    const float* __restrict__ bias, float* __restrict__ out)
{
    __shared__ unsigned short smem[32768];   // 64 KB: 4 x 16 KB buffers

    const int t  = threadIdx.x;
    const int n0 = blockIdx.x * 128, m0 = blockIdx.y * 128;
    const int w = t >> 6, lane = t & 63, quad = lane >> 4, lr = lane & 15;
    const int wr = w >> 1, wc = w & 1;

    f32x4 acc[4][4];
#pragma unroll
    for (int mt = 0; mt < 4; ++mt)
#pragma unroll
        for (int nt = 0; nt < 4; ++nt)
#pragma unroll
            for (int r = 0; r < 4; ++r) acc[mt][nt][r] = 0.f;

    gemm_k_loop_db(O, Wpb, smem, m0, n0, acc);

#pragma unroll
    for (int mt = 0; mt < 4; ++mt)
#pragma unroll
        for (int nt = 0; nt < 4; ++nt)
#pragma unroll
            for (int r = 0; r < 4; ++r) {
                int row = m0 + wr * 64 + mt * 16 + quad * 4 + r;
                int col = n0 + wc * 64 + nt * 16 + lr;
                out[(size_t)row * DIMC + col] = acc[mt][nt][r] + bias[col];
            }
}

// ---------------------------------------------------------------------------
// Flash attention v17: v16 with Ps rebuilt on v10's PROVEN bank geometry.
//   R6 post-mortem: PST=40 "fix" was wrong (bank = f(col,slot) is not a
//   permutation: col4/col2, col6/col0, ... collide) -> conflicts only
//   13.6M -> 11.5M.  v17: row stride 128 B (64 shorts) -> bank base 0 for
//   EVERY row, banks determined by 8B-slot index alone; XOR permutation over
//   the full 16-slot range.  The qh-paired waves (kvh=0/1) share one region:
//   rows = 32 q, slots = kvh*8 + cw (cw = 2*i2+hi local chunk).
//     phys_slot = (kvh*8 + cw) ^ pkey, pkey = (col&7)<<1  (even: 16B reads
//     stay pair-adjacent; content per slot unchanged vs v16).
//   Enumerated: writes 16 slots x 4 lanes = 4 dwords/bank (floor); reads
//   8 pair-regions x 8 lanes = 8 dwords/bank (floor).  K/V reads already at
//   floor.  Ps = 2 x (32 x 64) shorts = 16 KB; LDS = 48 KB -> 3 blocks/CU
//   (unchanged occupancy).
// ---------------------------------------------------------------------------
__global__ __launch_bounds__(256, 3) void attn_kernel(
    const unsigned short* __restrict__ qg, const unsigned short* __restrict__ kg,
    const unsigned short* __restrict__ vT, unsigned short* __restrict__ og)
{
    __shared__ unsigned short smem[24576];   // 48 KB
    unsigned short* Ka = smem;               //  8 KB each (64x64 bf16)
    unsigned short* Kb = smem + 4096;
    unsigned short* Va = smem + 8192;
    unsigned short* Vb = smem + 12288;
    unsigned short* Ps = smem + 16384;       // 16 KB: 2 x (32q x 64 shorts)

    const int t  = threadIdx.x;
    const int w = t >> 6, l = t & 63;
    const int col = l & 31, hi = l >> 5;      // 32x32 fragment coords
    const int qh = w >> 1, kvh = w & 1;       // q-half / kv-half of the wave
    const int srow = t >> 3, scol = t & 7;    // staging coords (srow 0..31)
    const int pkey = (col & 7) << 1;          // even slot key, full 8-value range

    unsigned short* PsQ = Ps + qh * 2048;     // qh-pair shared P tile (32x64)

    // XCD-aware mapping: bid&7 = XCD; each XCD owns 4 full (b,h) pairs
    // (32 q-tiles of 64 rows each) -> K/V head stays L2-local.
    const int bid  = blockIdx.x;              // 0..1023
    const int slot = bid >> 3;                // 0..127
    const int bh   = (bid & 7) * 4 + (slot >> 5);
    const int qt   = slot & 31;               // 64-row Q tile index
    const int b    = bh >> 4, h = bh & 15;

    const unsigned short* khead = kg + ((size_t)(b * SEQ)) * DIMC + h * HD;
    const unsigned short* vhead = vT + (size_t)((b * NHEADS + h) * HD) * SEQ;

    // Q B-fragments (pre-scaled by QSCALE2): col -> q row, d = ks*16+hi*8+j
    bf16x8 qf[4];
    {
        const size_t qoff = ((size_t)(b * SEQ + qt * 64 + qh * 32 + col)) * DIMC + h * HD + hi * 8;
#pragma unroll
        for (int ks = 0; ks < 4; ++ks)
            qf[ks] = *(const bf16x8*)(qg + qoff + ks * 16);
    }

    bf16x8 ones;
#pragma unroll
    for (int j = 0; j < 8; ++j) ones[j] = (__bf16)1.0f;

    f32x16 o0, o1, lac;
#pragma unroll
    for (int r = 0; r < 16; ++r) { o0[r] = 0.f; o1[r] = 0.f; lac[r] = 0.f; }

    // K rows (kv) and V rows (d) staged with the v10 XOR swizzle (unchanged).
    auto issue = [&](int kt, unsigned short* Kd, unsigned short* Vd) {
#pragma unroll
        for (int i = 0; i < 2; ++i) {
            int r  = i * 32 + srow;            // 0..63
            int cg = scol ^ (r & 7);
            gload_lds16(khead + (size_t)(kt * 64 + r) * DIMC + cg * 8, Kd + r * 64 + scol * 8);
            gload_lds16(vhead + (size_t)r * SEQ + kt * 64 + cg * 8,   Vd + r * 64 + scol * 8);
        }
    };

    auto phase = [&](const unsigned short* Kc, const unsigned short* Vc) {
        // --- S = K . Q^T over this wave's 32-kv half (rows=kv, cols=q) ---
        f32x16 s;
#pragma unroll
        for (int r = 0; r < 16; ++r) s[r] = 0.f;
#pragma unroll
        for (int ks = 0; ks < 4; ++ks) {
            int r = kvh * 32 + col;                       // kv row in tile
            int c = ks * 2 + hi;                          // source d-chunk
            bf16x8 kf = *(const bf16x8*)&Kc[r * 64 + ((c ^ (r & 7)) * 8)];
            s = __builtin_amdgcn_mfma_f32_32x32x16_bf16(kf, qf[ks], s, 0, 0, 0);
        }

        // --- V B-frags (independent of s: issue early) ---
        bf16x8 vf[2][2];
#pragma unroll
        for (int dt = 0; dt < 2; ++dt)
#pragma unroll
            for (int ks2 = 0; ks2 < 2; ++ks2) {
                int r = dt * 32 + col;                    // d row of vT tile
                int c = kvh * 4 + ks2 * 2 + hi;           // source kv-chunk
                vf[dt][ks2] = *(const bf16x8*)&Vc[r * 64 + ((c ^ (r & 7)) * 8)];
            }

        // --- p = 2^s -> bf16 pairs -> LDS (8B slots of 4 consecutive kv) ---
        // s[reg] = S[kv_loc = (reg&3)+8*(reg>>2)+4*hi][q = col]; pair
        // {pk[2i2],pk[2i2+1]} = kv_loc {8i2+4hi..+3} -> local slot 2i2+hi,
        // global slot g = kvh*8 + 2i2 + hi; physical = g ^ pkey.
        unsigned int pk[8];
#pragma unroll
        for (int i = 0; i < 8; ++i)
            pk[i] = pk2bf(__builtin_amdgcn_exp2f(s[2 * i]),
                          __builtin_amdgcn_exp2f(s[2 * i + 1]));
#pragma unroll
        for (int i2 = 0; i2 < 4; ++i2) {
            int g = (kvh << 3) + i2 * 2 + hi;
            uint2 pp; pp.x = pk[2 * i2]; pp.y = pk[2 * i2 + 1];
            *(uint2*)&PsQ[col * 64 + ((g ^ pkey) << 2)] = pp;
        }

        // --- PV A-frags: q row = col; kv slots {kvh*8+2hi, +1} and {+4} ---
        bf16x8 pf0 = *(const bf16x8*)&PsQ[col * 64 + ((((kvh << 3) + 2 * hi) ^ pkey) << 2)];
        bf16x8 pf1 = *(const bf16x8*)&PsQ[col * 64 + ((((kvh << 3) + 4 + 2 * hi) ^ pkey) << 2)];

        // --- l += P.1 ; O += P.V  (rows=q: matches final store) ---
        lac = __builtin_amdgcn_mfma_f32_32x32x16_bf16(pf0, ones, lac, 0, 0, 0);
        lac = __builtin_amdgcn_mfma_f32_32x32x16_bf16(pf1, ones, lac, 0, 0, 0);
        o0  = __builtin_amdgcn_mfma_f32_32x32x16_bf16(pf0, vf[0][0], o0, 0, 0, 0);
        o0  = __builtin_amdgcn_mfma_f32_32x32x16_bf16(pf1, vf[0][1], o0, 0, 0, 0);
        o1  = __builtin_amdgcn_mfma_f32_32x32x16_bf16(pf0, vf[1][0], o1, 0, 0, 0);
        o1  = __builtin_amdgcn_mfma_f32_32x32x16_bf16(pf1, vf[1][1], o1, 0, 0, 0);
    };

    issue(0, Ka, Va);
    for (int kt = 0; kt < SEQ / 64; kt += 2) {
        __syncthreads();                      // publish Ka/Va(kt)
        issue(kt + 1, Kb, Vb);
        phase(Ka, Va);
        __syncthreads();                      // publish Kb/Vb(kt+1)
        if (kt + 2 < SEQ / 64) issue(kt + 2, Ka, Va);
        phase(Kb, Vb);
    }

    // --- merge kv-halves (O and l simply add: un-normalized exp2 softmax) ---
    __syncthreads();                          // all waves done with K/V/Ps
    float* mrg = (float*)smem;                // 128 lanes x 49-f32 stride ~ 25 KB
    if (kvh == 1) {
        float* dst = mrg + (qh * 64 + l) * 49;
#pragma unroll
        for (int r = 0; r < 16; ++r) {
            dst[r] = o0[r]; dst[16 + r] = o1[r]; dst[32 + r] = lac[r];
        }
    }
    __syncthreads();
    if (kvh == 0) {
        const float* src = mrg + (qh * 64 + l) * 49;
        float inv[16];
#pragma unroll
        for (int r = 0; r < 16; ++r) {
            o0[r] += src[r]; o1[r] += src[16 + r];
            inv[r] = 1.0f / (lac[r] + src[32 + r]);
        }
#pragma unroll
        for (int r = 0; r < 16; ++r) {
            int qrow = qt * 64 + qh * 32 + (r & 3) + 8 * (r >> 2) + 4 * hi;
            size_t base = ((size_t)(b * SEQ + qrow)) * DIMC + h * HD;
            og[base + col]      = f2bf(o0[r] * inv[r]);
            og[base + 32 + col] = f2bf(o1[r] * inv[r]);
        }
    }
}

// ---------------------------------------------------------------------------
// Fallback path (ws < 40 MB): fp32-staging GEMMs.
// ---------------------------------------------------------------------------
__global__ __launch_bounds__(256) void gemm_qkv_f32(
    const float* __restrict__ x,
    const float* __restrict__ Wq, const float* __restrict__ Wk, const float* __restrict__ Wv,
    unsigned short* __restrict__ qo, unsigned short* __restrict__ ko, unsigned short* __restrict__ vT)
{
    __shared__ unsigned short smem[2 * 128 * AST];
    unsigned short* As = smem;
    unsigned short* Bs = smem + 128 * AST;

    const int t  = threadIdx.x;
    const int n0 = blockIdx.x * 128, m0 = blockIdx.y * 128, z = blockIdx.z;
    const float* W = (z == 0) ? Wq : (z == 1) ? Wk : Wv;
    const int w = t >> 6, l = t & 63, quad = l >> 4, lr = l & 15;
    const int wr = w >> 1, wc = w & 1;

    f32x4 acc[4][4];
#pragma unroll
    for (int mt = 0; mt < 4; ++mt)
#pragma unroll
        for (int nt = 0; nt < 4; ++nt)
#pragma unroll
            for (int r = 0; r < 4; ++r) acc[mt][nt][r] = 0.f;

    for (int kt = 0; kt < DIMC; kt += 64) {
        __syncthreads();
#pragma unroll
        for (int i = 0; i < 8; ++i) {
            int flat = t + i * 256;
            int row = flat >> 4, seg = flat & 15;
            float4 a = *(const float4*)(x + (size_t)(m0 + row) * DIMC + kt + seg * 4);
            ushort4 pa; pa.x = f2bf(a.x); pa.y = f2bf(a.y); pa.z = f2bf(a.z); pa.w = f2bf(a.w);
            *(ushort4*)&As[row * AST + seg * 4] = pa;
            float4 b = *(const float4*)(W + (size_t)(n0 + row) * DIMC + kt + seg * 4);
            ushort4 pb; pb.x = f2bf(b.x); pb.y = f2bf(b.y); pb.z = f2bf(b.z); pb.w = f2bf(b.w);
            *(ushort4*)&Bs[row * AST + seg * 4] = pb;
        }
        __syncthreads();
#pragma unroll
        for (int kk = 0; kk < 2; ++kk) {
            bf16x8 af[4], bfr[4];
#pragma unroll
            for (int mt = 0; mt < 4; ++mt)
                af[mt] = *(const bf16x8*)&As[(wr * 64 + mt * 16 + lr) * AST + kk * 32 + quad * 8];
#pragma unroll
            for (int nt = 0; nt < 4; ++nt)
                bfr[nt] = *(const bf16x8*)&Bs[(wc * 64 + nt * 16 + lr) * AST + kk * 32 + quad * 8];
#pragma unroll
            for (int mt = 0; mt < 4; ++mt)
#pragma unroll
                for (int nt = 0; nt < 4; ++nt)
                    acc[mt][nt] = __builtin_amdgcn_mfma_f32_16x16x32_bf16(af[mt], bfr[nt], acc[mt][nt], 0, 0, 0);
        }
    }

    if (z == 2) {
        __syncthreads();
#pragma unroll
        for (int mt = 0; mt < 4; ++mt)
#pragma unroll
            for (int nt = 0; nt < 4; ++nt) {
                int lcol  = wc * 64 + nt * 16 + lr;
                int lrow0 = wr * 64 + mt * 16 + quad * 4;
                ushort4 p;
                p.x = f2bf(acc[mt][nt][0]); p.y = f2bf(acc[mt][nt][1]);
                p.z = f2bf(acc[mt][nt][2]); p.w = f2bf(acc[mt][nt][3]);
                *(ushort4*)&smem[lcol * TST + lrow0] = p;
            }
        __syncthreads();
        int lc = t >> 1, half = t & 1;
        int cg = n0 + lc, hh = cg >> 6, dd = cg & 63;
        int bb = m0 >> 11, nn0 = m0 & (SEQ - 1);
        size_t dst = ((size_t)((bb * NHEADS + hh) * HD + dd)) * SEQ + nn0 + half * 64;
        const unsigned short* srcp = &smem[lc * TST + half * 64];
#pragma unroll
        for (int i = 0; i < 8; ++i)
            *(uint4*)&vT[dst + i * 8] = *(const uint4*)&srcp[i * 8];
    } else {
        unsigned short* Out = (z == 0) ? qo : ko;
        const float sc = (z == 0) ? QSCALE2 : 1.0f;
#pragma unroll
        for (int mt = 0; mt < 4; ++mt)
#pragma unroll
            for (int nt = 0; nt < 4; ++nt)
#pragma unroll
                for (int r = 0; r < 4; ++r) {
                    int row = m0 + wr * 64 + mt * 16 + quad * 4 + r;
                    int col = n0 + wc * 64 + nt * 16 + lr;
                    Out[(size_t)row * DIMC + col] = f2bf(acc[mt][nt][r] * sc);
                }
    }
}

__global__ __launch_bounds__(256) void gemm_out_f32(
    const unsigned short* __restrict__ A, const float* __restrict__ Wp,
    const float* __restrict__ bias, float* __restrict__ out)
{
    __shared__ unsigned short As[128 * AST];
    __shared__ unsigned short Bs[128 * AST];

    const int t  = threadIdx.x;
    const int n0 = blockIdx.x * 128, m0 = blockIdx.y * 128;
    const int w = t >> 6, l = t & 63, quad = l >> 4, lr = l & 15;
    const int wr = w >> 1, wc = w & 1;

    f32x4 acc[4][4];
#pragma unroll
    for (int mt = 0; mt < 4; ++mt)
#pragma unroll
        for (int nt = 0; nt < 4; ++nt)
#pragma unroll
            for (int r = 0; r < 4; ++r) acc[mt][nt][r] = 0.f;

    for (int kt = 0; kt < DIMC; kt += 64) {
        __syncthreads();
#pragma unroll
        for (int i = 0; i < 8; ++i) {
            int flat = t + i * 256;
            int row = flat >> 4, seg = flat & 15;
            ushort4 a = *(const ushort4*)(A + (size_t)(m0 + row) * DIMC + kt + seg * 4);
            *(ushort4*)&As[row * AST + seg * 4] = a;
            float4 b = *(const float4*)(Wp + (size_t)(n0 + row) * DIMC + kt + seg * 4);
            ushort4 pb; pb.x = f2bf(b.x); pb.y = f2bf(b.y); pb.z = f2bf(b.z); pb.w = f2bf(b.w);
            *(ushort4*)&Bs[row * AST + seg * 4] = pb;
        }
        __syncthreads();
#pragma unroll
        for (int kk = 0; kk < 2; ++kk) {
            bf16x8 af[4], bfr[4];
#pragma unroll
            for (int mt = 0; mt < 4; ++mt)
                af[mt] = *(const bf16x8*)&As[(wr * 64 + mt * 16 + lr) * AST + kk * 32 + quad * 8];
#pragma unroll
            for (int nt = 0; nt < 4; ++nt)
                bfr[nt] = *(const bf16x8*)&Bs[(wc * 64 + nt * 16 + lr) * AST + kk * 32 + quad * 8];
#pragma unroll
            for (int mt = 0; mt < 4; ++mt)
#pragma unroll
                for (int nt = 0; nt < 4; ++nt)
                    acc[mt][nt] = __builtin_amdgcn_mfma_f32_16x16x32_bf16(af[mt], bfr[nt], acc[mt][nt], 0, 0, 0);
        }
    }

#pragma unroll
    for (int mt = 0; mt < 4; ++mt)
#pragma unroll
        for (int nt = 0; nt < 4; ++nt)
#pragma unroll
            for (int r = 0; r < 4; ++r) {
                int row = m0 + wr * 64 + mt * 16 + quad * 4 + r;
                int col = n0 + wc * 64 + nt * 16 + lr;
                out[(size_t)row * DIMC + col] = acc[mt][nt][r] + bias[col];
            }
}

// ---------------------------------------------------------------------------
extern "C" void kernel_launch(void* const* d_in, const int* in_sizes, int n_in,
                              void* d_out, int out_size, void* d_ws, size_t ws_size,
                              hipStream_t stream)
{
    const float* x  = (const float*)d_in[0];
    const float* Wq = (const float*)d_in[1];
    const float* Wk = (const float*)d_in[2];
    const float* Wv = (const float*)d_in[3];
    const float* Wp = (const float*)d_in[4];
    const float* bp = (const float*)d_in[5];
    float* out = (float*)d_out;

    const size_t SZ  = (size_t)MROWS * DIMC;   // 4M elems
    const size_t WSZ = (size_t)DIMC * DIMC;    // 1M elems
    const size_t need = (4 * SZ + 4 * WSZ) * sizeof(unsigned short);  // 40 MB

    if (ws_size >= need) {
        unsigned short* q  = (unsigned short*)d_ws;
        unsigned short* k  = q + SZ;
        unsigned short* vt = k + SZ;
        unsigned short* o  = vt + SZ;
        unsigned short* Wb = o + SZ;
        unsigned short* xb = (unsigned short*)d_out;   // scratch: dead before gemm_out writes

        cast_all<<<dim3(1024, 8), 256, 0, stream>>>(x, Wq, Wk, Wv, Wp, xb, Wb);
        gemm_qkv_fast<<<dim3(DIMC / 128, MROWS / 128, 3), 256, 0, stream>>>(xb, Wb, q, k, vt);
        attn_kernel<<<dim3(1024), 256, 0, stream>>>(q, k, vt, o);
        gemm_out_fast<<<dim3(DIMC / 128, MROWS / 128), 256, 0, stream>>>(o, Wb + 3 * WSZ, bp, out);
    } else {
        unsigned short* q  = (unsigned short*)d_ws;
        unsigned short* k  = q + SZ;
        unsigned short* vt = k + SZ;
        unsigned short* o  = vt + SZ;

        gemm_qkv_f32<<<dim3(DIMC / 128, MROWS / 128, 3), 256, 0, stream>>>(x, Wq, Wk, Wv, q, k, vt);
        attn_kernel<<<dim3(1024), 256, 0, stream>>>(q, k, vt, o);
        gemm_out_f32<<<dim3(DIMC / 128, MROWS / 128), 256, 0, stream>>>(o, Wp, bp, out);
    }
}

// Round 8
// 175.695 us; speedup vs baseline: 1.1229x; 1.0780x over previous
//
#include <hip/hip_runtime.h>
#include <cstdint>

#define DIMC   1024
#define NHEADS 16
#define HD     64
#define BATCH  2
#define SEQ    2048
#define MROWS  (BATCH*SEQ)   // 4096
// Q pre-scale: (1/sqrt(64)) * log2(e)  -> softmax computed in base 2 (exact)
#define QSCALE2 0.18033688f

typedef __bf16 bf16x8 __attribute__((ext_vector_type(8)));
typedef float  f32x4  __attribute__((ext_vector_type(4)));

#define AST 88    // fallback LDS row stride (bf16 elems)
#define TST 136   // transpose-epilogue LDS stride

__device__ __forceinline__ unsigned short f2bf(float f) {
    union { float f; unsigned int u; } v; v.f = f;
    unsigned int u = v.u;
    u += 0x7fffu + ((u >> 16) & 1u);   // round-to-nearest-even
    return (unsigned short)(u >> 16);
}

// pack two floats to bf16x2 (round-nearest, ties away): 2 adds + 1 v_perm
__device__ __forceinline__ unsigned int pk2bf(float a, float b) {
    union { float f; unsigned int u; } ua, ub;
    ua.f = a; ub.f = b;
    return __builtin_amdgcn_perm(ub.u + 0x8000u, ua.u + 0x8000u, 0x07060302u);
}

__device__ __forceinline__ void gload_lds16(const void* g, void* l) {
    __builtin_amdgcn_global_load_lds(
        (const __attribute__((address_space(1))) unsigned int*)g,
        (__attribute__((address_space(3))) unsigned int*)l, 16, 0, 0);
}

// ---------------------------------------------------------------------------
// Pre-cast fp32 -> bf16: x (4M elems) and Wq|Wk|Wv|Wp (1M each) into xb / Wb.
// ---------------------------------------------------------------------------
__global__ __launch_bounds__(256) void cast_all(
    const float* __restrict__ x,
    const float* __restrict__ Wq, const float* __restrict__ Wk,
    const float* __restrict__ Wv, const float* __restrict__ Wp,
    unsigned short* __restrict__ xb, unsigned short* __restrict__ Wb)
{
    const size_t M1 = (size_t)DIMC * DIMC;   // 1M elems
    int y = blockIdx.y;
    const float* src;
    unsigned short* dst;
    if (y < 4)      { src = x  + (size_t)y * M1; dst = xb + (size_t)y * M1; }
    else if (y == 4){ src = Wq; dst = Wb; }
    else if (y == 5){ src = Wk; dst = Wb + M1; }
    else if (y == 6){ src = Wv; dst = Wb + 2 * M1; }
    else            { src = Wp; dst = Wb + 3 * M1; }
    size_t idx = ((size_t)blockIdx.x * 256 + threadIdx.x) * 4;
    float4 v = *(const float4*)(src + idx);
    ushort4 p; p.x = f2bf(v.x); p.y = f2bf(v.y); p.z = f2bf(v.z); p.w = f2bf(v.w);
    *(ushort4*)(dst + idx) = p;
}

// ---------------------------------------------------------------------------
// Pipelined GEMM building blocks (issue-after-barrier pattern).
// 128x128 tile, BK=64, 4 waves; LDS double-buffered (4 x 16 KB).
// ---------------------------------------------------------------------------
__device__ __forceinline__ void gemm_issue(
    const unsigned short* __restrict__ A, const unsigned short* __restrict__ B,
    unsigned short* As, unsigned short* Bs, int m0, int n0, int kt)
{
    const int t = threadIdx.x;
    const int w = t >> 6, lane = t & 63;
    const int srow = lane >> 3, scol = lane & 7;
#pragma unroll
    for (int i = 0; i < 4; ++i) {
        int r  = i * 32 + w * 8 + srow;        // 0..127
        int cg = scol ^ (r & 7);               // swizzled source chunk
        gload_lds16(A + (size_t)(m0 + r) * DIMC + kt + cg * 8, As + r * 64 + scol * 8);
        gload_lds16(B + (size_t)(n0 + r) * DIMC + kt + cg * 8, Bs + r * 64 + scol * 8);
    }
}

__device__ __forceinline__ void gemm_compute(
    const unsigned short* As, const unsigned short* Bs, f32x4 acc[4][4])
{
    const int t = threadIdx.x;
    const int w = t >> 6, lane = t & 63, quad = lane >> 4, lr = lane & 15;
    const int wr = w >> 1, wc = w & 1;
#pragma unroll
    for (int kk = 0; kk < 2; ++kk) {
        bf16x8 af[4], bfr[4];
#pragma unroll
        for (int mt = 0; mt < 4; ++mt) {
            int row = wr * 64 + mt * 16 + lr;
            int cb  = kk * 4 + quad;
            af[mt] = *(const bf16x8*)&As[row * 64 + (cb ^ (row & 7)) * 8];
        }
#pragma unroll
        for (int nt = 0; nt < 4; ++nt) {
            int row = wc * 64 + nt * 16 + lr;
            int cb  = kk * 4 + quad;
            bfr[nt] = *(const bf16x8*)&Bs[row * 64 + (cb ^ (row & 7)) * 8];
        }
#pragma unroll
        for (int mt = 0; mt < 4; ++mt)
#pragma unroll
            for (int nt = 0; nt < 4; ++nt)
                acc[mt][nt] = __builtin_amdgcn_mfma_f32_16x16x32_bf16(af[mt], bfr[nt], acc[mt][nt], 0, 0, 0);
    }
}

// Full pipelined K-loop: one __syncthreads per tile; prefetch issued after the
// barrier into the other buffer stays in flight across the compute phase.
__device__ __forceinline__ void gemm_k_loop_db(
    const unsigned short* __restrict__ A, const unsigned short* __restrict__ B,
    unsigned short* smem, int m0, int n0, f32x4 acc[4][4])
{
    unsigned short* As0 = smem;
    unsigned short* Bs0 = smem + 8192;
    unsigned short* As1 = smem + 16384;
    unsigned short* Bs1 = smem + 24576;

    gemm_issue(A, B, As0, Bs0, m0, n0, 0);
    for (int kt = 0; kt < DIMC; kt += 128) {
        __syncthreads();                       // publish As0/Bs0 (DMA had full
        gemm_issue(A, B, As1, Bs1, m0, n0, kt + 64);   //  compute phase in flight)
        gemm_compute(As0, Bs0, acc);
        __syncthreads();                       // publish As1/Bs1
        if (kt + 128 < DIMC) gemm_issue(A, B, As0, Bs0, m0, n0, kt + 128);
        gemm_compute(As1, Bs1, acc);
    }
}

// vT transpose epilogue: stage C-tile transposed in LDS, then coalesced
// 16B global stores to vT[b][h][d][n].
__device__ __forceinline__ void vt_epilogue(
    unsigned short* Ts, f32x4 acc[4][4], int m0, int n0,
    unsigned short* __restrict__ vT)
{
    const int t = threadIdx.x;
    const int w = t >> 6, lane = t & 63, quad = lane >> 4, lr = lane & 15;
    const int wr = w >> 1, wc = w & 1;

    __syncthreads();
#pragma unroll
    for (int mt = 0; mt < 4; ++mt)
#pragma unroll
        for (int nt = 0; nt < 4; ++nt) {
            int lcol  = wc * 64 + nt * 16 + lr;
            int lrow0 = wr * 64 + mt * 16 + quad * 4;
            ushort4 p;
            p.x = f2bf(acc[mt][nt][0]); p.y = f2bf(acc[mt][nt][1]);
            p.z = f2bf(acc[mt][nt][2]); p.w = f2bf(acc[mt][nt][3]);
            *(ushort4*)&Ts[lcol * TST + lrow0] = p;
        }
    __syncthreads();

    int lc = t >> 1, half = t & 1;
    int cg = n0 + lc, hh = cg >> 6, dd = cg & 63;
    int bb = m0 >> 11, nn0 = m0 & (SEQ - 1);
    size_t dst = ((size_t)((bb * NHEADS + hh) * HD + dd)) * SEQ + nn0 + half * 64;
    const unsigned short* srcp = &Ts[lc * TST + half * 64];
#pragma unroll
    for (int i = 0; i < 8; ++i)
        *(uint4*)&vT[dst + i * 8] = *(const uint4*)&srcp[i * 8];
}

// ---------------------------------------------------------------------------
// Fast QKV projection (pipelined): z=0 -> q (scaled), z=1 -> k, z=2 -> vT.
// T1: bijective XCD swizzle — 256 xy-blocks remapped so each XCD owns a 4x8
// (m x n) rectangle: A-slice 1 MB + B 2 MB = 3 MB < 4 MB per-XCD L2.
// ---------------------------------------------------------------------------
__global__ __launch_bounds__(256) void gemm_qkv_fast(
    const unsigned short* __restrict__ xb, const unsigned short* __restrict__ Wb,
    unsigned short* __restrict__ qo, unsigned short* __restrict__ ko,
    unsigned short* __restrict__ vT)
{
    __shared__ unsigned short smem[32768];   // 64 KB: 4 x 16 KB buffers

    const int t  = threadIdx.x;
    const int lin = blockIdx.y * 8 + blockIdx.x;      // hw dispatch order
    const int T   = (lin & 7) * 32 + (lin >> 3);      // bijective XCD chunking
    const int n0 = (T & 7) * 128, m0 = (T >> 3) * 128, z = blockIdx.z;
    const unsigned short* B = Wb + (size_t)z * DIMC * DIMC;
    const int w = t >> 6, lane = t & 63, quad = lane >> 4, lr = lane & 15;
    const int wr = w >> 1, wc = w & 1;

    f32x4 acc[4][4];
#pragma unroll
    for (int mt = 0; mt < 4; ++mt)
#pragma unroll
        for (int nt = 0; nt < 4; ++nt)
#pragma unroll
            for (int r = 0; r < 4; ++r) acc[mt][nt][r] = 0.f;

    gemm_k_loop_db(xb, B, smem, m0, n0, acc);

    if (z == 2) {
        vt_epilogue(smem, acc, m0, n0, vT);
    } else {
        unsigned short* Out = (z == 0) ? qo : ko;
        const float sc = (z == 0) ? QSCALE2 : 1.0f;
#pragma unroll
        for (int mt = 0; mt < 4; ++mt)
#pragma unroll
            for (int nt = 0; nt < 4; ++nt)
#pragma unroll
                for (int r = 0; r < 4; ++r) {
                    int row = m0 + wr * 64 + mt * 16 + quad * 4 + r;
                    int col = n0 + wc * 64 + nt * 16 + lr;
                    Out[(size_t)row * DIMC + col] = f2bf(acc[mt][nt][r] * sc);
                }
    }
}

// ---------------------------------------------------------------------------
// Fast output projection (pipelined), same T1 swizzle.
// ---------------------------------------------------------------------------
__global__ __launch_bounds__(256) void gemm_out_fast(
    const unsigned short* __restrict__ O, const unsigned short* __restrict__ Wpb,
    const float* __restrict__ bias, float* __restrict__ out)
{
    __shared__ unsigned short smem[32768];   // 64 KB: 4 x 16 KB buffers

    const int t  = threadIdx.x;
    const int lin = blockIdx.y * 8 + blockIdx.x;
    const int T   = (lin & 7) * 32 + (lin >> 3);
    const int n0 = (T & 7) * 128, m0 = (T >> 3) * 128;
    const int w = t >> 6, lane = t & 63, quad = lane >> 4, lr = lane & 15;
    const int wr = w >> 1, wc = w & 1;

    f32x4 acc[4][4];
#pragma unroll
    for (int mt = 0; mt < 4; ++mt)
#pragma unroll
        for (int nt = 0; nt < 4; ++nt)
#pragma unroll
            for (int r = 0; r < 4; ++r) acc[mt][nt][r] = 0.f;

    gemm_k_loop_db(O, Wpb, smem, m0, n0, acc);

#pragma unroll
    for (int mt = 0; mt < 4; ++mt)
#pragma unroll
        for (int nt = 0; nt < 4; ++nt)
#pragma unroll
            for (int r = 0; r < 4; ++r) {
                int row = m0 + wr * 64 + mt * 16 + quad * 4 + r;
                int col = n0 + wc * 64 + nt * 16 + lr;
                out[(size_t)row * DIMC + col] = acc[mt][nt][r] + bias[col];
            }
}

// ---------------------------------------------------------------------------
// Flash attention v18 = v11 (proven best, 52.3 us) + T5 s_setprio around the
// MFMA clusters.  R7 post-mortem: the 32x32 track (v14-v17) never beat v11
// (65 vs 52 us; un-modellable residual bank conflicts) -> reverted.
// v11 structure: 128-row Q tile, 4 waves x 32 q-rows, S(t)/PV(t-1) software
// pipeline with Ps double-buffer + V-in-registers; 2 blocks/CU, 8 waves/CU.
// T5 mechanism applies: independent blocks put waves at different phases, so
// boosting MFMA-cluster priority preempts other waves' staging (attn +4-7%,
// guide m191).
// ---------------------------------------------------------------------------
__global__ __launch_bounds__(256, 2) void attn_kernel(
    const unsigned short* __restrict__ qg, const unsigned short* __restrict__ kg,
    const unsigned short* __restrict__ vT, unsigned short* __restrict__ og)
{
    __shared__ unsigned short Ka[64 * 64];
    __shared__ unsigned short Kb[64 * 64];
    __shared__ unsigned short Va[64 * 64];
    __shared__ unsigned short Vb[64 * 64];
    __shared__ unsigned short PsA[128 * 64];  // wave w owns rows w*32..w*32+31
    __shared__ unsigned short PsB[128 * 64];

    const int t  = threadIdx.x;
    const int w = t >> 6, l = t & 63, quad = l >> 4, lr = l & 15;
    const int srow = t >> 3, scol = t & 7;    // staging coords (256 threads: srow 0..31)
    const int pkey = (lr & 7) << 1;           // Ps swizzle key (even -> keeps pairs)

    // XCD-aware mapping: bid&7 = XCD; each XCD owns 4 full (b,h) pairs.
    const int bid  = blockIdx.x;              // 0..511
    const int slot = bid >> 3;                // 0..63
    const int bh   = (bid & 7) * 4 + (slot >> 4);
    const int qt   = slot & 15;               // 128-row Q tile index
    const int b    = bh >> 4, h = bh & 15;

    const unsigned short* khead = kg + ((size_t)(b * SEQ)) * DIMC + h * HD;
    const unsigned short* vhead = vT + (size_t)((b * NHEADS + h) * HD) * SEQ;

    // Q A-fragments (pre-scaled by QSCALE2): 2 m-tiles x 2 k-steps per wave
    bf16x8 qf[2][2];
#pragma unroll
    for (int mt = 0; mt < 2; ++mt) {
        const size_t qoff = ((size_t)(b * SEQ + qt * 128 + w * 32 + mt * 16 + lr)) * DIMC + h * HD;
        qf[mt][0] = *(const bf16x8*)(qg + qoff + 0  + quad * 8);
        qf[mt][1] = *(const bf16x8*)(qg + qoff + 32 + quad * 8);
    }

    bf16x8 ones;
#pragma unroll
    for (int j = 0; j < 8; ++j) ones[j] = (__bf16)1.0f;
    const f32x4 fzero = { 0.f, 0.f, 0.f, 0.f };

    f32x4 o_acc[2][4], lacc[2];
#pragma unroll
    for (int mt = 0; mt < 2; ++mt) {
        lacc[mt] = fzero;
#pragma unroll
        for (int ct = 0; ct < 4; ++ct) o_acc[mt][ct] = fzero;
    }

    auto issue = [&](int kt, unsigned short* Kd, unsigned short* Vd) {
#pragma unroll
        for (int i = 0; i < 2; ++i) {
            int r  = i * 32 + srow;            // 0..63
            int cg = scol ^ (r & 7);
            gload_lds16(khead + (size_t)(kt * 64 + r) * DIMC + cg * 8, Kd + r * 64 + scol * 8);
            gload_lds16(vhead + (size_t)r * SEQ + kt * 64 + cg * 8,   Vd + r * 64 + scol * 8);
        }
    };

    // S^T = K·Q^T : row = kv, col = m; chain seeded with fzero
    auto s_phase = [&](const unsigned short* Kc, f32x4 (&s)[2][4]) {
        __builtin_amdgcn_s_setprio(1);        // T5: keep matrix pipe fed
#pragma unroll
        for (int nt = 0; nt < 4; ++nt) {
            int row = nt * 16 + lr;
            bf16x8 kf = *(const bf16x8*)&Kc[row * 64 + ((quad ^ (row & 7)) * 8)];
#pragma unroll
            for (int mt = 0; mt < 2; ++mt)
                s[mt][nt] = __builtin_amdgcn_mfma_f32_16x16x32_bf16(kf, qf[mt][0], fzero, 0, 0, 0);
        }
#pragma unroll
        for (int nt = 0; nt < 4; ++nt) {
            int row = nt * 16 + lr;
            bf16x8 kf = *(const bf16x8*)&Kc[row * 64 + (((4 + quad) ^ (row & 7)) * 8)];
#pragma unroll
            for (int mt = 0; mt < 2; ++mt)
                s[mt][nt] = __builtin_amdgcn_mfma_f32_16x16x32_bf16(kf, qf[mt][1], s[mt][nt], 0, 0, 0);
        }
        __builtin_amdgcn_s_setprio(0);
    };

    // p = 2^s (raw v_exp), packed pair-wise, 8B swizzled stores: Ps[m][kv]
    auto exp_store = [&](const f32x4 (&s)[2][4], unsigned short* PsW) {
#pragma unroll
        for (int mt = 0; mt < 2; ++mt)
#pragma unroll
            for (int nt = 0; nt < 4; ++nt) {
                uint2 pp;
                pp.x = pk2bf(__builtin_amdgcn_exp2f(s[mt][nt][0]),
                             __builtin_amdgcn_exp2f(s[mt][nt][1]));
                pp.y = pk2bf(__builtin_amdgcn_exp2f(s[mt][nt][2]),
                             __builtin_amdgcn_exp2f(s[mt][nt][3]));
                *(uint2*)&PsW[(w * 32 + mt * 16 + lr) * 64 + (((nt * 4 + quad) ^ pkey) * 4)] = pp;
            }
    };

    // stage V(t) fragments to registers (used by PV in the NEXT phase,
    // after this LDS buffer has been handed back to the DMA engine)
    auto vload = [&](const unsigned short* Vc, bf16x8 (&vr)[8]) {
#pragma unroll
        for (int kk = 0; kk < 2; ++kk)
#pragma unroll
            for (int ct = 0; ct < 4; ++ct) {
                int row = ct * 16 + lr;
                vr[kk * 4 + ct] = *(const bf16x8*)&Vc[row * 64 + (((kk * 4 + quad) ^ (row & 7)) * 8)];
            }
    };

    // O += P*V ; l += P*1   (P from wave-private Ps buffer, V from registers)
    auto pv = [&](const unsigned short* PsR, const bf16x8 (&vr)[8]) {
        __builtin_amdgcn_s_setprio(1);        // T5
#pragma unroll
        for (int kk = 0; kk < 2; ++kk)
#pragma unroll
            for (int mt = 0; mt < 2; ++mt) {
                bf16x8 pf = *(const bf16x8*)&PsR[(w * 32 + mt * 16 + lr) * 64 + (((kk * 8 + quad * 2) ^ pkey) * 4)];
                lacc[mt] = __builtin_amdgcn_mfma_f32_16x16x32_bf16(pf, ones, lacc[mt], 0, 0, 0);
#pragma unroll
                for (int ct = 0; ct < 4; ++ct)
                    o_acc[mt][ct] = __builtin_amdgcn_mfma_f32_16x16x32_bf16(pf, vr[kk * 4 + ct], o_acc[mt][ct], 0, 0, 0);
            }
        __builtin_amdgcn_s_setprio(0);
    };

    bf16x8 vrA[8], vrB[8];

    issue(0, Ka, Va);
    for (int kt = 0; kt < SEQ / 64; kt += 2) {
        __syncthreads();                      // publish Ka/Va(kt)
        issue(kt + 1, Kb, Vb);
        {
            f32x4 s[2][4];
            s_phase(Ka, s);                   // S(kt)
            if (kt) pv(PsB, vrB);             // PV(kt-1): regs + PsB (independent)
            exp_store(s, PsA);                // P(kt) -> PsA
            vload(Va, vrA);                   // V(kt) -> regs (before Va is re-DMA'd)
        }
        __syncthreads();                      // publish Kb/Vb(kt+1)
        if (kt + 2 < SEQ / 64) issue(kt + 2, Ka, Va);
        {
            f32x4 s[2][4];
            s_phase(Kb, s);                   // S(kt+1)
            pv(PsA, vrA);                     // PV(kt)
            exp_store(s, PsB);                // P(kt+1) -> PsB
            vload(Vb, vrB);                   // V(kt+1) -> regs
        }
    }
    pv(PsB, vrB);                             // drain: PV(last tile)

#pragma unroll
    for (int mt = 0; mt < 2; ++mt) {
        float inv[4];
#pragma unroll
        for (int r = 0; r < 4; ++r) inv[r] = 1.0f / lacc[mt][r];
#pragma unroll
        for (int ct = 0; ct < 4; ++ct)
#pragma unroll
            for (int r = 0; r < 4; ++r) {
                int qrow = qt * 128 + w * 32 + mt * 16 + quad * 4 + r;
                og[((size_t)(b * SEQ + qrow)) * DIMC + h * HD + ct * 16 + lr] =
                    f2bf(o_acc[mt][ct][r] * inv[r]);
            }
    }
}

// ---------------------------------------------------------------------------
// Fallback path (ws < 40 MB): fp32-staging GEMMs.
// ---------------------------------------------------------------------------
__global__ __launch_bounds__(256) void gemm_qkv_f32(
    const float* __restrict__ x,
    const float* __restrict__ Wq, const float* __restrict__ Wk, const float* __restrict__ Wv,
    unsigned short* __restrict__ qo, unsigned short* __restrict__ ko, unsigned short* __restrict__ vT)
{
    __shared__ unsigned short smem[2 * 128 * AST];
    unsigned short* As = smem;
    unsigned short* Bs = smem + 128 * AST;

    const int t  = threadIdx.x;
    const int n0 = blockIdx.x * 128, m0 = blockIdx.y * 128, z = blockIdx.z;
    const float* W = (z == 0) ? Wq : (z == 1) ? Wk : Wv;
    const int w = t >> 6, l = t & 63, quad = l >> 4, lr = l & 15;
    const int wr = w >> 1, wc = w & 1;

    f32x4 acc[4][4];
#pragma unroll
    for (int mt = 0; mt < 4; ++mt)
#pragma unroll
        for (int nt = 0; nt < 4; ++nt)
#pragma unroll
            for (int r = 0; r < 4; ++r) acc[mt][nt][r] = 0.f;

    for (int kt = 0; kt < DIMC; kt += 64) {
        __syncthreads();
#pragma unroll
        for (int i = 0; i < 8; ++i) {
            int flat = t + i * 256;
            int row = flat >> 4, seg = flat & 15;
            float4 a = *(const float4*)(x + (size_t)(m0 + row) * DIMC + kt + seg * 4);
            ushort4 pa; pa.x = f2bf(a.x); pa.y = f2bf(a.y); pa.z = f2bf(a.z); pa.w = f2bf(a.w);
            *(ushort4*)&As[row * AST + seg * 4] = pa;
            float4 b = *(const float4*)(W + (size_t)(n0 + row) * DIMC + kt + seg * 4);
            ushort4 pb; pb.x = f2bf(b.x); pb.y = f2bf(b.y); pb.z = f2bf(b.z); pb.w = f2bf(b.w);
            *(ushort4*)&Bs[row * AST + seg * 4] = pb;
        }
        __syncthreads();
#pragma unroll
        for (int kk = 0; kk < 2; ++kk) {
            bf16x8 af[4], bfr[4];
#pragma unroll
            for (int mt = 0; mt < 4; ++mt)
                af[mt] = *(const bf16x8*)&As[(wr * 64 + mt * 16 + lr) * AST + kk * 32 + quad * 8];
#pragma unroll
            for (int nt = 0; nt < 4; ++nt)
                bfr[nt] = *(const bf16x8*)&Bs[(wc * 64 + nt * 16 + lr) * AST + kk * 32 + quad * 8];
#pragma unroll
            for (int mt = 0; mt < 4; ++mt)
#pragma unroll
                for (int nt = 0; nt < 4; ++nt)
                    acc[mt][nt] = __builtin_amdgcn_mfma_f32_16x16x32_bf16(af[mt], bfr[nt], acc[mt][nt], 0, 0, 0);
        }
    }

    if (z == 2) {
        __syncthreads();
#pragma unroll
        for (int mt = 0; mt < 4; ++mt)
#pragma unroll
            for (int nt = 0; nt < 4; ++nt) {
                int lcol  = wc * 64 + nt * 16 + lr;
                int lrow0 = wr * 64 + mt * 16 + quad * 4;
                ushort4 p;
                p.x = f2bf(acc[mt][nt][0]); p.y = f2bf(acc[mt][nt][1]);
                p.z = f2bf(acc[mt][nt][2]); p.w = f2bf(acc[mt][nt][3]);
                *(ushort4*)&smem[lcol * TST + lrow0] = p;
            }
        __syncthreads();
        int lc = t >> 1, half = t & 1;
        int cg = n0 + lc, hh = cg >> 6, dd = cg & 63;
        int bb = m0 >> 11, nn0 = m0 & (SEQ - 1);
        size_t dst = ((size_t)((bb * NHEADS + hh) * HD + dd)) * SEQ + nn0 + half * 64;
        const unsigned short* srcp = &smem[lc * TST + half * 64];
#pragma unroll
        for (int i = 0; i < 8; ++i)
            *(uint4*)&vT[dst + i * 8] = *(const uint4*)&srcp[i * 8];
    } else {
        unsigned short* Out = (z == 0) ? qo : ko;
        const float sc = (z == 0) ? QSCALE2 : 1.0f;
#pragma unroll
        for (int mt = 0; mt < 4; ++mt)
#pragma unroll
            for (int nt = 0; nt < 4; ++nt)
#pragma unroll
                for (int r = 0; r < 4; ++r) {
                    int row = m0 + wr * 64 + mt * 16 + quad * 4 + r;
                    int col = n0 + wc * 64 + nt * 16 + lr;
                    Out[(size_t)row * DIMC + col] = f2bf(acc[mt][nt][r] * sc);
                }
    }
}

__global__ __launch_bounds__(256) void gemm_out_f32(
    const unsigned short* __restrict__ A, const float* __restrict__ Wp,
    const float* __restrict__ bias, float* __restrict__ out)
{
    __shared__ unsigned short As[128 * AST];
    __shared__ unsigned short Bs[128 * AST];

    const int t  = threadIdx.x;
    const int n0 = blockIdx.x * 128, m0 = blockIdx.y * 128;
    const int w = t >> 6, l = t & 63, quad = l >> 4, lr = l & 15;
    const int wr = w >> 1, wc = w & 1;

    f32x4 acc[4][4];
#pragma unroll
    for (int mt = 0; mt < 4; ++mt)
#pragma unroll
        for (int nt = 0; nt < 4; ++nt)
#pragma unroll
            for (int r = 0; r < 4; ++r) acc[mt][nt][r] = 0.f;

    for (int kt = 0; kt < DIMC; kt += 64) {
        __syncthreads();
#pragma unroll
        for (int i = 0; i < 8; ++i) {
            int flat = t + i * 256;
            int row = flat >> 4, seg = flat & 15;
            ushort4 a = *(const ushort4*)(A + (size_t)(m0 + row) * DIMC + kt + seg * 4);
            *(ushort4*)&As[row * AST + seg * 4] = a;
            float4 b = *(const float4*)(Wp + (size_t)(n0 + row) * DIMC + kt + seg * 4);
            ushort4 pb; pb.x = f2bf(b.x); pb.y = f2bf(b.y); pb.z = f2bf(b.z); pb.w = f2bf(b.w);
            *(ushort4*)&Bs[row * AST + seg * 4] = pb;
        }
        __syncthreads();
#pragma unroll
        for (int kk = 0; kk < 2; ++kk) {
            bf16x8 af[4], bfr[4];
#pragma unroll
            for (int mt = 0; mt < 4; ++mt)
                af[mt] = *(const bf16x8*)&As[(wr * 64 + mt * 16 + lr) * AST + kk * 32 + quad * 8];
#pragma unroll
            for (int nt = 0; nt < 4; ++nt)
                bfr[nt] = *(const bf16x8*)&Bs[(wc * 64 + nt * 16 + lr) * AST + kk * 32 + quad * 8];
#pragma unroll
            for (int mt = 0; mt < 4; ++mt)
#pragma unroll
                for (int nt = 0; nt < 4; ++nt)
                    acc[mt][nt] = __builtin_amdgcn_mfma_f32_16x16x32_bf16(af[mt], bfr[nt], acc[mt][nt], 0, 0, 0);
        }
    }

#pragma unroll
    for (int mt = 0; mt < 4; ++mt)
#pragma unroll
        for (int nt = 0; nt < 4; ++nt)
#pragma unroll
            for (int r = 0; r < 4; ++r) {
                int row = m0 + wr * 64 + mt * 16 + quad * 4 + r;
                int col = n0 + wc * 64 + nt * 16 + lr;
                out[(size_t)row * DIMC + col] = acc[mt][nt][r] + bias[col];
            }
}

// ---------------------------------------------------------------------------
extern "C" void kernel_launch(void* const* d_in, const int* in_sizes, int n_in,
                              void* d_out, int out_size, void* d_ws, size_t ws_size,
                              hipStream_t stream)
{
    const float* x  = (const float*)d_in[0];
    const float* Wq = (const float*)d_in[1];
    const float* Wk = (const float*)d_in[2];
    const float* Wv = (const float*)d_in[3];
    const float* Wp = (const float*)d_in[4];
    const float* bp = (const float*)d_in[5];
    float* out = (float*)d_out;

    const size_t SZ  = (size_t)MROWS * DIMC;   // 4M elems
    const size_t WSZ = (size_t)DIMC * DIMC;    // 1M elems
    const size_t need = (4 * SZ + 4 * WSZ) * sizeof(unsigned short);  // 40 MB

    if (ws_size >= need) {
        unsigned short* q  = (unsigned short*)d_ws;
        unsigned short* k  = q + SZ;
        unsigned short* vt = k + SZ;
        unsigned short* o  = vt + SZ;
        unsigned short* Wb = o + SZ;
        unsigned short* xb = (unsigned short*)d_out;   // scratch: dead before gemm_out writes

        cast_all<<<dim3(1024, 8), 256, 0, stream>>>(x, Wq, Wk, Wv, Wp, xb, Wb);
        gemm_qkv_fast<<<dim3(DIMC / 128, MROWS / 128, 3), 256, 0, stream>>>(xb, Wb, q, k, vt);
        attn_kernel<<<dim3(512), 256, 0, stream>>>(q, k, vt, o);
        gemm_out_fast<<<dim3(DIMC / 128, MROWS / 128), 256, 0, stream>>>(o, Wb + 3 * WSZ, bp, out);
    } else {
        unsigned short* q  = (unsigned short*)d_ws;
        unsigned short* k  = q + SZ;
        unsigned short* vt = k + SZ;
        unsigned short* o  = vt + SZ;

        gemm_qkv_f32<<<dim3(DIMC / 128, MROWS / 128, 3), 256, 0, stream>>>(x, Wq, Wk, Wv, q, k, vt);
        attn_kernel<<<dim3(512), 256, 0, stream>>>(q, k, vt, o);
        gemm_out_f32<<<dim3(DIMC / 128, MROWS / 128), 256, 0, stream>>>(o, Wp, bp, out);
    }
}

// Round 9
// 172.522 us; speedup vs baseline: 1.1435x; 1.0184x over previous
//
#include <hip/hip_runtime.h>
#include <cstdint>

#define DIMC   1024
#define NHEADS 16
#define HD     64
#define BATCH  2
#define SEQ    2048
#define MROWS  (BATCH*SEQ)   // 4096
// Q pre-scale: (1/sqrt(64)) * log2(e)  -> softmax computed in base 2 (exact)
#define QSCALE2 0.18033688f

typedef __bf16 bf16x8 __attribute__((ext_vector_type(8)));
typedef float  f32x4  __attribute__((ext_vector_type(4)));

#define AST 88    // fallback LDS row stride (bf16 elems)
#define TST 136   // transpose-epilogue LDS stride

__device__ __forceinline__ unsigned short f2bf(float f) {
    union { float f; unsigned int u; } v; v.f = f;
    unsigned int u = v.u;
    u += 0x7fffu + ((u >> 16) & 1u);   // round-to-nearest-even
    return (unsigned short)(u >> 16);
}

// pack two floats to bf16x2 (round-nearest, ties away): 2 adds + 1 v_perm
__device__ __forceinline__ unsigned int pk2bf(float a, float b) {
    union { float f; unsigned int u; } ua, ub;
    ua.f = a; ub.f = b;
    return __builtin_amdgcn_perm(ub.u + 0x8000u, ua.u + 0x8000u, 0x07060302u);
}

__device__ __forceinline__ void gload_lds16(const void* g, void* l) {
    __builtin_amdgcn_global_load_lds(
        (const __attribute__((address_space(1))) unsigned int*)g,
        (__attribute__((address_space(3))) unsigned int*)l, 16, 0, 0);
}

// ---------------------------------------------------------------------------
// Pre-cast fp32 -> bf16: x (4M elems) and Wq|Wk|Wv|Wp (1M each) into xb / Wb.
// ---------------------------------------------------------------------------
__global__ __launch_bounds__(256) void cast_all(
    const float* __restrict__ x,
    const float* __restrict__ Wq, const float* __restrict__ Wk,
    const float* __restrict__ Wv, const float* __restrict__ Wp,
    unsigned short* __restrict__ xb, unsigned short* __restrict__ Wb)
{
    const size_t M1 = (size_t)DIMC * DIMC;   // 1M elems
    int y = blockIdx.y;
    const float* src;
    unsigned short* dst;
    if (y < 4)      { src = x  + (size_t)y * M1; dst = xb + (size_t)y * M1; }
    else if (y == 4){ src = Wq; dst = Wb; }
    else if (y == 5){ src = Wk; dst = Wb + M1; }
    else if (y == 6){ src = Wv; dst = Wb + 2 * M1; }
    else            { src = Wp; dst = Wb + 3 * M1; }
    size_t idx = ((size_t)blockIdx.x * 256 + threadIdx.x) * 4;
    float4 v = *(const float4*)(src + idx);
    ushort4 p; p.x = f2bf(v.x); p.y = f2bf(v.y); p.z = f2bf(v.z); p.w = f2bf(v.w);
    *(ushort4*)(dst + idx) = p;
}

// ---------------------------------------------------------------------------
// Pipelined GEMM building blocks (issue-after-barrier pattern).
// v19 geometry: 128(M) x 64(N) tile, BK=64, 4 waves (2m x 2n).
// LDS = As dbuf 32 KB + Bs dbuf 16 KB = 48 KB -> 3 blocks/CU (12 waves/CU).
// R8 post-mortem: 64 KB tiles gave 2 blocks/CU -> qkv grid 768 ran 1.5
// scheduling rounds (half-empty round 2) and out grid 256 ran at 1 block/CU.
// New grids: qkv 1536 = 2 exact rounds of 768 slots; out 512 co-resident.
// Same XOR swizzles / fragment formulas, rescaled wc*64->wc*32, nt<4->nt<2.
// ---------------------------------------------------------------------------
__device__ __forceinline__ void gemm_issue(
    const unsigned short* __restrict__ A, const unsigned short* __restrict__ B,
    unsigned short* As, unsigned short* Bs, int m0, int n0, int kt)
{
    const int t = threadIdx.x;
    const int w = t >> 6, lane = t & 63;
    const int srow = lane >> 3, scol = lane & 7;
#pragma unroll
    for (int i = 0; i < 4; ++i) {
        int r  = i * 32 + w * 8 + srow;        // 0..127 (A rows)
        int cg = scol ^ (r & 7);               // swizzled source chunk
        gload_lds16(A + (size_t)(m0 + r) * DIMC + kt + cg * 8, As + r * 64 + scol * 8);
    }
#pragma unroll
    for (int i = 0; i < 2; ++i) {
        int r  = i * 32 + w * 8 + srow;        // 0..63 (B rows)
        int cg = scol ^ (r & 7);
        gload_lds16(B + (size_t)(n0 + r) * DIMC + kt + cg * 8, Bs + r * 64 + scol * 8);
    }
}

__device__ __forceinline__ void gemm_compute(
    const unsigned short* As, const unsigned short* Bs, f32x4 acc[4][2])
{
    const int t = threadIdx.x;
    const int w = t >> 6, lane = t & 63, quad = lane >> 4, lr = lane & 15;
    const int wr = w >> 1, wc = w & 1;
#pragma unroll
    for (int kk = 0; kk < 2; ++kk) {
        bf16x8 af[4], bfr[2];
#pragma unroll
        for (int mt = 0; mt < 4; ++mt) {
            int row = wr * 64 + mt * 16 + lr;
            int cb  = kk * 4 + quad;
            af[mt] = *(const bf16x8*)&As[row * 64 + (cb ^ (row & 7)) * 8];
        }
#pragma unroll
        for (int nt = 0; nt < 2; ++nt) {
            int row = wc * 32 + nt * 16 + lr;
            int cb  = kk * 4 + quad;
            bfr[nt] = *(const bf16x8*)&Bs[row * 64 + (cb ^ (row & 7)) * 8];
        }
#pragma unroll
        for (int mt = 0; mt < 4; ++mt)
#pragma unroll
            for (int nt = 0; nt < 2; ++nt)
                acc[mt][nt] = __builtin_amdgcn_mfma_f32_16x16x32_bf16(af[mt], bfr[nt], acc[mt][nt], 0, 0, 0);
    }
}

// Full pipelined K-loop: one __syncthreads per tile; prefetch issued after the
// barrier into the other buffer stays in flight across the compute phase.
__device__ __forceinline__ void gemm_k_loop_db(
    const unsigned short* __restrict__ A, const unsigned short* __restrict__ B,
    unsigned short* smem, int m0, int n0, f32x4 acc[4][2])
{
    unsigned short* As0 = smem;              // 16 KB (128 x 64)
    unsigned short* Bs0 = smem + 8192;       //  8 KB ( 64 x 64)
    unsigned short* As1 = smem + 12288;
    unsigned short* Bs1 = smem + 20480;

    gemm_issue(A, B, As0, Bs0, m0, n0, 0);
    for (int kt = 0; kt < DIMC; kt += 128) {
        __syncthreads();                       // publish As0/Bs0 (DMA had full
        gemm_issue(A, B, As1, Bs1, m0, n0, kt + 64);   //  compute phase in flight)
        gemm_compute(As0, Bs0, acc);
        __syncthreads();                       // publish As1/Bs1
        if (kt + 128 < DIMC) gemm_issue(A, B, As0, Bs0, m0, n0, kt + 128);
        gemm_compute(As1, Bs1, acc);
    }
}

// vT transpose epilogue (64-col tile): stage C-tile transposed in LDS, then
// coalesced 16B global stores to vT[b][h][d][n].
__device__ __forceinline__ void vt_epilogue(
    unsigned short* Ts, f32x4 acc[4][2], int m0, int n0,
    unsigned short* __restrict__ vT)
{
    const int t = threadIdx.x;
    const int w = t >> 6, lane = t & 63, quad = lane >> 4, lr = lane & 15;
    const int wr = w >> 1, wc = w & 1;

    __syncthreads();
#pragma unroll
    for (int mt = 0; mt < 4; ++mt)
#pragma unroll
        for (int nt = 0; nt < 2; ++nt) {
            int lcol  = wc * 32 + nt * 16 + lr;        // 0..63
            int lrow0 = wr * 64 + mt * 16 + quad * 4;  // 0..127
            ushort4 p;
            p.x = f2bf(acc[mt][nt][0]); p.y = f2bf(acc[mt][nt][1]);
            p.z = f2bf(acc[mt][nt][2]); p.w = f2bf(acc[mt][nt][3]);
            *(ushort4*)&Ts[lcol * TST + lrow0] = p;
        }
    __syncthreads();

    int lc = t >> 2, part = t & 3;            // 64 cols x 4 row-quarters
    int cg = n0 + lc, hh = cg >> 6, dd = cg & 63;
    int bb = m0 >> 11, nn0 = m0 & (SEQ - 1);
    size_t dst = ((size_t)((bb * NHEADS + hh) * HD + dd)) * SEQ + nn0 + part * 32;
    const unsigned short* srcp = &Ts[lc * TST + part * 32];
#pragma unroll
    for (int i = 0; i < 4; ++i)
        *(uint4*)&vT[dst + i * 8] = *(const uint4*)&srcp[i * 8];
}

// ---------------------------------------------------------------------------
// Fast QKV projection (pipelined): z=0 -> q (scaled), z=1 -> k, z=2 -> vT.
// grid (16,32,3) = 1536 blocks; bijective XCD chunking over the 512 xy-tiles.
// ---------------------------------------------------------------------------
__global__ __launch_bounds__(256, 3) void gemm_qkv_fast(
    const unsigned short* __restrict__ xb, const unsigned short* __restrict__ Wb,
    unsigned short* __restrict__ qo, unsigned short* __restrict__ ko,
    unsigned short* __restrict__ vT)
{
    __shared__ unsigned short smem[24576];   // 48 KB: 2 x (16+8) KB buffers

    const int t  = threadIdx.x;
    const int lin = blockIdx.y * 16 + blockIdx.x;     // 0..511
    const int T   = (lin & 7) * 64 + (lin >> 3);      // bijective XCD chunking
    const int n0 = (T & 15) * 64, m0 = (T >> 4) * 128, z = blockIdx.z;
    const unsigned short* B = Wb + (size_t)z * DIMC * DIMC;
    const int w = t >> 6, lane = t & 63, quad = lane >> 4, lr = lane & 15;
    const int wr = w >> 1, wc = w & 1;

    f32x4 acc[4][2];
#pragma unroll
    for (int mt = 0; mt < 4; ++mt)
#pragma unroll
        for (int nt = 0; nt < 2; ++nt)
#pragma unroll
            for (int r = 0; r < 4; ++r) acc[mt][nt][r] = 0.f;

    gemm_k_loop_db(xb, B, smem, m0, n0, acc);

    if (z == 2) {
        vt_epilogue(smem, acc, m0, n0, vT);
    } else {
        unsigned short* Out = (z == 0) ? qo : ko;
        const float sc = (z == 0) ? QSCALE2 : 1.0f;
#pragma unroll
        for (int mt = 0; mt < 4; ++mt)
#pragma unroll
            for (int nt = 0; nt < 2; ++nt)
#pragma unroll
                for (int r = 0; r < 4; ++r) {
                    int row = m0 + wr * 64 + mt * 16 + quad * 4 + r;
                    int col = n0 + wc * 32 + nt * 16 + lr;
                    Out[(size_t)row * DIMC + col] = f2bf(acc[mt][nt][r] * sc);
                }
    }
}

// ---------------------------------------------------------------------------
// Fast output projection (pipelined), grid (16,32) = 512 blocks co-resident.
// ---------------------------------------------------------------------------
__global__ __launch_bounds__(256, 3) void gemm_out_fast(
    const unsigned short* __restrict__ O, const unsigned short* __restrict__ Wpb,
    const float* __restrict__ bias, float* __restrict__ out)
{
    __shared__ unsigned short smem[24576];   // 48 KB

    const int t  = threadIdx.x;
    const int lin = blockIdx.y * 16 + blockIdx.x;
    const int T   = (lin & 7) * 64 + (lin >> 3);
    const int n0 = (T & 15) * 64, m0 = (T >> 4) * 128;
    const int w = t >> 6, lane = t & 63, quad = lane >> 4, lr = lane & 15;
    const int wr = w >> 1, wc = w & 1;

    f32x4 acc[4][2];
#pragma unroll
    for (int mt = 0; mt < 4; ++mt)
#pragma unroll
        for (int nt = 0; nt < 2; ++nt)
#pragma unroll
            for (int r = 0; r < 4; ++r) acc[mt][nt][r] = 0.f;

    gemm_k_loop_db(O, Wpb, smem, m0, n0, acc);

#pragma unroll
    for (int mt = 0; mt < 4; ++mt)
#pragma unroll
        for (int nt = 0; nt < 2; ++nt)
#pragma unroll
            for (int r = 0; r < 4; ++r) {
                int row = m0 + wr * 64 + mt * 16 + quad * 4 + r;
                int col = n0 + wc * 32 + nt * 16 + lr;
                out[(size_t)row * DIMC + col] = acc[mt][nt][r] + bias[col];
            }
}

// ---------------------------------------------------------------------------
// Flash attention v18 (UNCHANGED from R8, the 49.7 us proven config):
// v11 structure + T5 s_setprio.  128-row Q tile, 4 waves x 32 q-rows,
// S(t)/PV(t-1) software pipeline, Ps dbuf, V-in-registers; 2 blocks/CU.
// ---------------------------------------------------------------------------
__global__ __launch_bounds__(256, 2) void attn_kernel(
    const unsigned short* __restrict__ qg, const unsigned short* __restrict__ kg,
    const unsigned short* __restrict__ vT, unsigned short* __restrict__ og)
{
    __shared__ unsigned short Ka[64 * 64];
    __shared__ unsigned short Kb[64 * 64];
    __shared__ unsigned short Va[64 * 64];
    __shared__ unsigned short Vb[64 * 64];
    __shared__ unsigned short PsA[128 * 64];  // wave w owns rows w*32..w*32+31
    __shared__ unsigned short PsB[128 * 64];

    const int t  = threadIdx.x;
    const int w = t >> 6, l = t & 63, quad = l >> 4, lr = l & 15;
    const int srow = t >> 3, scol = t & 7;    // staging coords (256 threads: srow 0..31)
    const int pkey = (lr & 7) << 1;           // Ps swizzle key (even -> keeps pairs)

    // XCD-aware mapping: bid&7 = XCD; each XCD owns 4 full (b,h) pairs.
    const int bid  = blockIdx.x;              // 0..511
    const int slot = bid >> 3;                // 0..63
    const int bh   = (bid & 7) * 4 + (slot >> 4);
    const int qt   = slot & 15;               // 128-row Q tile index
    const int b    = bh >> 4, h = bh & 15;

    const unsigned short* khead = kg + ((size_t)(b * SEQ)) * DIMC + h * HD;
    const unsigned short* vhead = vT + (size_t)((b * NHEADS + h) * HD) * SEQ;

    // Q A-fragments (pre-scaled by QSCALE2): 2 m-tiles x 2 k-steps per wave
    bf16x8 qf[2][2];
#pragma unroll
    for (int mt = 0; mt < 2; ++mt) {
        const size_t qoff = ((size_t)(b * SEQ + qt * 128 + w * 32 + mt * 16 + lr)) * DIMC + h * HD;
        qf[mt][0] = *(const bf16x8*)(qg + qoff + 0  + quad * 8);
        qf[mt][1] = *(const bf16x8*)(qg + qoff + 32 + quad * 8);
    }

    bf16x8 ones;
#pragma unroll
    for (int j = 0; j < 8; ++j) ones[j] = (__bf16)1.0f;
    const f32x4 fzero = { 0.f, 0.f, 0.f, 0.f };

    f32x4 o_acc[2][4], lacc[2];
#pragma unroll
    for (int mt = 0; mt < 2; ++mt) {
        lacc[mt] = fzero;
#pragma unroll
        for (int ct = 0; ct < 4; ++ct) o_acc[mt][ct] = fzero;
    }

    auto issue = [&](int kt, unsigned short* Kd, unsigned short* Vd) {
#pragma unroll
        for (int i = 0; i < 2; ++i) {
            int r  = i * 32 + srow;            // 0..63
            int cg = scol ^ (r & 7);
            gload_lds16(khead + (size_t)(kt * 64 + r) * DIMC + cg * 8, Kd + r * 64 + scol * 8);
            gload_lds16(vhead + (size_t)r * SEQ + kt * 64 + cg * 8,   Vd + r * 64 + scol * 8);
        }
    };

    // S^T = K·Q^T : row = kv, col = m; chain seeded with fzero
    auto s_phase = [&](const unsigned short* Kc, f32x4 (&s)[2][4]) {
        __builtin_amdgcn_s_setprio(1);        // T5: keep matrix pipe fed
#pragma unroll
        for (int nt = 0; nt < 4; ++nt) {
            int row = nt * 16 + lr;
            bf16x8 kf = *(const bf16x8*)&Kc[row * 64 + ((quad ^ (row & 7)) * 8)];
#pragma unroll
            for (int mt = 0; mt < 2; ++mt)
                s[mt][nt] = __builtin_amdgcn_mfma_f32_16x16x32_bf16(kf, qf[mt][0], fzero, 0, 0, 0);
        }
#pragma unroll
        for (int nt = 0; nt < 4; ++nt) {
            int row = nt * 16 + lr;
            bf16x8 kf = *(const bf16x8*)&Kc[row * 64 + (((4 + quad) ^ (row & 7)) * 8)];
#pragma unroll
            for (int mt = 0; mt < 2; ++mt)
                s[mt][nt] = __builtin_amdgcn_mfma_f32_16x16x32_bf16(kf, qf[mt][1], s[mt][nt], 0, 0, 0);
        }
        __builtin_amdgcn_s_setprio(0);
    };

    // p = 2^s (raw v_exp), packed pair-wise, 8B swizzled stores: Ps[m][kv]
    auto exp_store = [&](const f32x4 (&s)[2][4], unsigned short* PsW) {
#pragma unroll
        for (int mt = 0; mt < 2; ++mt)
#pragma unroll
            for (int nt = 0; nt < 4; ++nt) {
                uint2 pp;
                pp.x = pk2bf(__builtin_amdgcn_exp2f(s[mt][nt][0]),
                             __builtin_amdgcn_exp2f(s[mt][nt][1]));
                pp.y = pk2bf(__builtin_amdgcn_exp2f(s[mt][nt][2]),
                             __builtin_amdgcn_exp2f(s[mt][nt][3]));
                *(uint2*)&PsW[(w * 32 + mt * 16 + lr) * 64 + (((nt * 4 + quad) ^ pkey) * 4)] = pp;
            }
    };

    // stage V(t) fragments to registers (used by PV in the NEXT phase,
    // after this LDS buffer has been handed back to the DMA engine)
    auto vload = [&](const unsigned short* Vc, bf16x8 (&vr)[8]) {
#pragma unroll
        for (int kk = 0; kk < 2; ++kk)
#pragma unroll
            for (int ct = 0; ct < 4; ++ct) {
                int row = ct * 16 + lr;
                vr[kk * 4 + ct] = *(const bf16x8*)&Vc[row * 64 + (((kk * 4 + quad) ^ (row & 7)) * 8)];
            }
    };

    // O += P*V ; l += P*1   (P from wave-private Ps buffer, V from registers)
    auto pv = [&](const unsigned short* PsR, const bf16x8 (&vr)[8]) {
        __builtin_amdgcn_s_setprio(1);        // T5
#pragma unroll
        for (int kk = 0; kk < 2; ++kk)
#pragma unroll
            for (int mt = 0; mt < 2; ++mt) {
                bf16x8 pf = *(const bf16x8*)&PsR[(w * 32 + mt * 16 + lr) * 64 + (((kk * 8 + quad * 2) ^ pkey) * 4)];
                lacc[mt] = __builtin_amdgcn_mfma_f32_16x16x32_bf16(pf, ones, lacc[mt], 0, 0, 0);
#pragma unroll
                for (int ct = 0; ct < 4; ++ct)
                    o_acc[mt][ct] = __builtin_amdgcn_mfma_f32_16x16x32_bf16(pf, vr[kk * 4 + ct], o_acc[mt][ct], 0, 0, 0);
            }
        __builtin_amdgcn_s_setprio(0);
    };

    bf16x8 vrA[8], vrB[8];

    issue(0, Ka, Va);
    for (int kt = 0; kt < SEQ / 64; kt += 2) {
        __syncthreads();                      // publish Ka/Va(kt)
        issue(kt + 1, Kb, Vb);
        {
            f32x4 s[2][4];
            s_phase(Ka, s);                   // S(kt)
            if (kt) pv(PsB, vrB);             // PV(kt-1): regs + PsB (independent)
            exp_store(s, PsA);                // P(kt) -> PsA
            vload(Va, vrA);                   // V(kt) -> regs (before Va is re-DMA'd)
        }
        __syncthreads();                      // publish Kb/Vb(kt+1)
        if (kt + 2 < SEQ / 64) issue(kt + 2, Ka, Va);
        {
            f32x4 s[2][4];
            s_phase(Kb, s);                   // S(kt+1)
            pv(PsA, vrA);                     // PV(kt)
            exp_store(s, PsB);                // P(kt+1) -> PsB
            vload(Vb, vrB);                   // V(kt+1) -> regs
        }
    }
    pv(PsB, vrB);                             // drain: PV(last tile)

#pragma unroll
    for (int mt = 0; mt < 2; ++mt) {
        float inv[4];
#pragma unroll
        for (int r = 0; r < 4; ++r) inv[r] = 1.0f / lacc[mt][r];
#pragma unroll
        for (int ct = 0; ct < 4; ++ct)
#pragma unroll
            for (int r = 0; r < 4; ++r) {
                int qrow = qt * 128 + w * 32 + mt * 16 + quad * 4 + r;
                og[((size_t)(b * SEQ + qrow)) * DIMC + h * HD + ct * 16 + lr] =
                    f2bf(o_acc[mt][ct][r] * inv[r]);
            }
    }
}

// ---------------------------------------------------------------------------
// Fallback path (ws < 40 MB): fp32-staging GEMMs.
// ---------------------------------------------------------------------------
__global__ __launch_bounds__(256) void gemm_qkv_f32(
    const float* __restrict__ x,
    const float* __restrict__ Wq, const float* __restrict__ Wk, const float* __restrict__ Wv,
    unsigned short* __restrict__ qo, unsigned short* __restrict__ ko, unsigned short* __restrict__ vT)
{
    __shared__ unsigned short smem[2 * 128 * AST];
    unsigned short* As = smem;
    unsigned short* Bs = smem + 128 * AST;

    const int t  = threadIdx.x;
    const int n0 = blockIdx.x * 128, m0 = blockIdx.y * 128, z = blockIdx.z;
    const float* W = (z == 0) ? Wq : (z == 1) ? Wk : Wv;
    const int w = t >> 6, l = t & 63, quad = l >> 4, lr = l & 15;
    const int wr = w >> 1, wc = w & 1;

    f32x4 acc[4][4];
#pragma unroll
    for (int mt = 0; mt < 4; ++mt)
#pragma unroll
        for (int nt = 0; nt < 4; ++nt)
#pragma unroll
            for (int r = 0; r < 4; ++r) acc[mt][nt][r] = 0.f;

    for (int kt = 0; kt < DIMC; kt += 64) {
        __syncthreads();
#pragma unroll
        for (int i = 0; i < 8; ++i) {
            int flat = t + i * 256;
            int row = flat >> 4, seg = flat & 15;
            float4 a = *(const float4*)(x + (size_t)(m0 + row) * DIMC + kt + seg * 4);
            ushort4 pa; pa.x = f2bf(a.x); pa.y = f2bf(a.y); pa.z = f2bf(a.z); pa.w = f2bf(a.w);
            *(ushort4*)&As[row * AST + seg * 4] = pa;
            float4 b = *(const float4*)(W + (size_t)(n0 + row) * DIMC + kt + seg * 4);
            ushort4 pb; pb.x = f2bf(b.x); pb.y = f2bf(b.y); pb.z = f2bf(b.z); pb.w = f2bf(b.w);
            *(ushort4*)&Bs[row * AST + seg * 4] = pb;
        }
        __syncthreads();
#pragma unroll
        for (int kk = 0; kk < 2; ++kk) {
            bf16x8 af[4], bfr[4];
#pragma unroll
            for (int mt = 0; mt < 4; ++mt)
                af[mt] = *(const bf16x8*)&As[(wr * 64 + mt * 16 + lr) * AST + kk * 32 + quad * 8];
#pragma unroll
            for (int nt = 0; nt < 4; ++nt)
                bfr[nt] = *(const bf16x8*)&Bs[(wc * 64 + nt * 16 + lr) * AST + kk * 32 + quad * 8];
#pragma unroll
            for (int mt = 0; mt < 4; ++mt)
#pragma unroll
                for (int nt = 0; nt < 4; ++nt)
                    acc[mt][nt] = __builtin_amdgcn_mfma_f32_16x16x32_bf16(af[mt], bfr[nt], acc[mt][nt], 0, 0, 0);
        }
    }

    if (z == 2) {
        __syncthreads();
#pragma unroll
        for (int mt = 0; mt < 4; ++mt)
#pragma unroll
            for (int nt = 0; nt < 4; ++nt) {
                int lcol  = wc * 64 + nt * 16 + lr;
                int lrow0 = wr * 64 + mt * 16 + quad * 4;
                ushort4 p;
                p.x = f2bf(acc[mt][nt][0]); p.y = f2bf(acc[mt][nt][1]);
                p.z = f2bf(acc[mt][nt][2]); p.w = f2bf(acc[mt][nt][3]);
                *(ushort4*)&smem[lcol * TST + lrow0] = p;
            }
        __syncthreads();
        int lc = t >> 1, half = t & 1;
        int cg = n0 + lc, hh = cg >> 6, dd = cg & 63;
        int bb = m0 >> 11, nn0 = m0 & (SEQ - 1);
        size_t dst = ((size_t)((bb * NHEADS + hh) * HD + dd)) * SEQ + nn0 + half * 64;
        const unsigned short* srcp = &smem[lc * TST + half * 64];
#pragma unroll
        for (int i = 0; i < 8; ++i)
            *(uint4*)&vT[dst + i * 8] = *(const uint4*)&srcp[i * 8];
    } else {
        unsigned short* Out = (z == 0) ? qo : ko;
        const float sc = (z == 0) ? QSCALE2 : 1.0f;
#pragma unroll
        for (int mt = 0; mt < 4; ++mt)
#pragma unroll
            for (int nt = 0; nt < 4; ++nt)
#pragma unroll
                for (int r = 0; r < 4; ++r) {
                    int row = m0 + wr * 64 + mt * 16 + quad * 4 + r;
                    int col = n0 + wc * 64 + nt * 16 + lr;
                    Out[(size_t)row * DIMC + col] = f2bf(acc[mt][nt][r] * sc);
                }
    }
}

__global__ __launch_bounds__(256) void gemm_out_f32(
    const unsigned short* __restrict__ A, const float* __restrict__ Wp,
    const float* __restrict__ bias, float* __restrict__ out)
{
    __shared__ unsigned short As[128 * AST];
    __shared__ unsigned short Bs[128 * AST];

    const int t  = threadIdx.x;
    const int n0 = blockIdx.x * 128, m0 = blockIdx.y * 128;
    const int w = t >> 6, l = t & 63, quad = l >> 4, lr = l & 15;
    const int wr = w >> 1, wc = w & 1;

    f32x4 acc[4][4];
#pragma unroll
    for (int mt = 0; mt < 4; ++mt)
#pragma unroll
        for (int nt = 0; nt < 4; ++nt)
#pragma unroll
            for (int r = 0; r < 4; ++r) acc[mt][nt][r] = 0.f;

    for (int kt = 0; kt < DIMC; kt += 64) {
        __syncthreads();
#pragma unroll
        for (int i = 0; i < 8; ++i) {
            int flat = t + i * 256;
            int row = flat >> 4, seg = flat & 15;
            ushort4 a = *(const ushort4*)(A + (size_t)(m0 + row) * DIMC + kt + seg * 4);
            *(ushort4*)&As[row * AST + seg * 4] = a;
            float4 b = *(const float4*)(Wp + (size_t)(n0 + row) * DIMC + kt + seg * 4);
            ushort4 pb; pb.x = f2bf(b.x); pb.y = f2bf(b.y); pb.z = f2bf(b.z); pb.w = f2bf(b.w);
            *(ushort4*)&Bs[row * AST + seg * 4] = pb;
        }
        __syncthreads();
#pragma unroll
        for (int kk = 0; kk < 2; ++kk) {
            bf16x8 af[4], bfr[4];
#pragma unroll
            for (int mt = 0; mt < 4; ++mt)
                af[mt] = *(const bf16x8*)&As[(wr * 64 + mt * 16 + lr) * AST + kk * 32 + quad * 8];
#pragma unroll
            for (int nt = 0; nt < 4; ++nt)
                bfr[nt] = *(const bf16x8*)&Bs[(wc * 64 + nt * 16 + lr) * AST + kk * 32 + quad * 8];
#pragma unroll
            for (int mt = 0; mt < 4; ++mt)
#pragma unroll
                for (int nt = 0; nt < 4; ++nt)
                    acc[mt][nt] = __builtin_amdgcn_mfma_f32_16x16x32_bf16(af[mt], bfr[nt], acc[mt][nt], 0, 0, 0);
        }
    }

#pragma unroll
    for (int mt = 0; mt < 4; ++mt)
#pragma unroll
        for (int nt = 0; nt < 4; ++nt)
#pragma unroll
            for (int r = 0; r < 4; ++r) {
                int row = m0 + wr * 64 + mt * 16 + quad * 4 + r;
                int col = n0 + wc * 64 + nt * 16 + lr;
                out[(size_t)row * DIMC + col] = acc[mt][nt][r] + bias[col];
            }
}

// ---------------------------------------------------------------------------
extern "C" void kernel_launch(void* const* d_in, const int* in_sizes, int n_in,
                              void* d_out, int out_size, void* d_ws, size_t ws_size,
                              hipStream_t stream)
{
    const float* x  = (const float*)d_in[0];
    const float* Wq = (const float*)d_in[1];
    const float* Wk = (const float*)d_in[2];
    const float* Wv = (const float*)d_in[3];
    const float* Wp = (const float*)d_in[4];
    const float* bp = (const float*)d_in[5];
    float* out = (float*)d_out;

    const size_t SZ  = (size_t)MROWS * DIMC;   // 4M elems
    const size_t WSZ = (size_t)DIMC * DIMC;    // 1M elems
    const size_t need = (4 * SZ + 4 * WSZ) * sizeof(unsigned short);  // 40 MB

    if (ws_size >= need) {
        unsigned short* q  = (unsigned short*)d_ws;
        unsigned short* k  = q + SZ;
        unsigned short* vt = k + SZ;
        unsigned short* o  = vt + SZ;
        unsigned short* Wb = o + SZ;
        unsigned short* xb = (unsigned short*)d_out;   // scratch: dead before gemm_out writes

        cast_all<<<dim3(1024, 8), 256, 0, stream>>>(x, Wq, Wk, Wv, Wp, xb, Wb);
        gemm_qkv_fast<<<dim3(16, 32, 3), 256, 0, stream>>>(xb, Wb, q, k, vt);
        attn_kernel<<<dim3(512), 256, 0, stream>>>(q, k, vt, o);
        gemm_out_fast<<<dim3(16, 32), 256, 0, stream>>>(o, Wb + 3 * WSZ, bp, out);
    } else {
        unsigned short* q  = (unsigned short*)d_ws;
        unsigned short* k  = q + SZ;
        unsigned short* vt = k + SZ;
        unsigned short* o  = vt + SZ;

        gemm_qkv_f32<<<dim3(DIMC / 128, MROWS / 128, 3), 256, 0, stream>>>(x, Wq, Wk, Wv, q, k, vt);
        attn_kernel<<<dim3(512), 256, 0, stream>>>(q, k, vt, o);
        gemm_out_f32<<<dim3(DIMC / 128, MROWS / 128), 256, 0, stream>>>(o, Wp, bp, out);
    }
}

// Round 10
// 172.006 us; speedup vs baseline: 1.1470x; 1.0030x over previous
//
#include <hip/hip_runtime.h>
#include <cstdint>

#define DIMC   1024
#define NHEADS 16
#define HD     64
#define BATCH  2
#define SEQ    2048
#define MROWS  (BATCH*SEQ)   // 4096
// Q pre-scale: (1/sqrt(64)) * log2(e)  -> softmax computed in base 2 (exact)
#define QSCALE2 0.18033688f

typedef __bf16 bf16x8 __attribute__((ext_vector_type(8)));
typedef float  f32x4  __attribute__((ext_vector_type(4)));

#define AST 88    // fallback LDS row stride (bf16 elems)
#define TST 136   // transpose-epilogue LDS stride

__device__ __forceinline__ unsigned short f2bf(float f) {
    union { float f; unsigned int u; } v; v.f = f;
    unsigned int u = v.u;
    u += 0x7fffu + ((u >> 16) & 1u);   // round-to-nearest-even
    return (unsigned short)(u >> 16);
}

// pack two floats to bf16x2 (round-nearest, ties away): 2 adds + 1 v_perm
__device__ __forceinline__ unsigned int pk2bf(float a, float b) {
    union { float f; unsigned int u; } ua, ub;
    ua.f = a; ub.f = b;
    return __builtin_amdgcn_perm(ub.u + 0x8000u, ua.u + 0x8000u, 0x07060302u);
}

__device__ __forceinline__ void gload_lds16(const void* g, void* l) {
    __builtin_amdgcn_global_load_lds(
        (const __attribute__((address_space(1))) unsigned int*)g,
        (__attribute__((address_space(3))) unsigned int*)l, 16, 0, 0);
}

// ---------------------------------------------------------------------------
// Pre-cast fp32 -> bf16: x (4M elems) and Wq|Wk|Wv|Wp (1M each) into xb / Wb.
// ---------------------------------------------------------------------------
__global__ __launch_bounds__(256) void cast_all(
    const float* __restrict__ x,
    const float* __restrict__ Wq, const float* __restrict__ Wk,
    const float* __restrict__ Wv, const float* __restrict__ Wp,
    unsigned short* __restrict__ xb, unsigned short* __restrict__ Wb)
{
    const size_t M1 = (size_t)DIMC * DIMC;   // 1M elems
    int y = blockIdx.y;
    const float* src;
    unsigned short* dst;
    if (y < 4)      { src = x  + (size_t)y * M1; dst = xb + (size_t)y * M1; }
    else if (y == 4){ src = Wq; dst = Wb; }
    else if (y == 5){ src = Wk; dst = Wb + M1; }
    else if (y == 6){ src = Wv; dst = Wb + 2 * M1; }
    else            { src = Wp; dst = Wb + 3 * M1; }
    size_t idx = ((size_t)blockIdx.x * 256 + threadIdx.x) * 4;
    float4 v = *(const float4*)(src + idx);
    ushort4 p; p.x = f2bf(v.x); p.y = f2bf(v.y); p.z = f2bf(v.z); p.w = f2bf(v.w);
    *(ushort4*)(dst + idx) = p;
}

// ---------------------------------------------------------------------------
// v20 qkv GEMM: 128x128 tile, BK=32, dbuf = 4 x 8 KB = 32 KB.
// R9 post-mortem: 128x64 tile has 0.75 KB LDS-read/MFMA vs 128x128's 0.5 —
// occupancy won 3 us but ratio lost; BK=32 gets both (12+ waves/CU AND 0.5).
// LDS layout at BK=32 (row = 64 B = 16 banks): PAIR-ROW INTERLEAVE —
// logical row r lives at (r>>1)*64 + (r&1)*32 shorts, so each 128-B LDS line
// holds 2 rows (bank base 0 per line, like the proven BK=64 layout).
// Chunk key = (r>>1)&3.  Enumerated: DMA dest = wave-uniform base + lane*16
// (m104 constraint holds); read collisions only lr<->lr+8 = 2-way (free,
// m136); writes linear.  Epilogues identical to R8's verified 128-wide code.
// ---------------------------------------------------------------------------
__device__ __forceinline__ void gemm_issue32(
    const unsigned short* __restrict__ A, const unsigned short* __restrict__ B,
    unsigned short* As, unsigned short* Bs, int m0, int n0, int kt)
{
    const int t = threadIdx.x;
    const int rr = t >> 2, cg = t & 3;     // rr 0..63, physical chunk 0..3
#pragma unroll
    for (int i = 0; i < 2; ++i) {
        int r  = i * 64 + rr;              // logical row 0..127
        int sc = cg ^ ((r >> 1) & 3);      // source k-chunk (swizzled)
        int dst = (r >> 1) * 64 + (r & 1) * 32 + cg * 8;
        gload_lds16(A + (size_t)(m0 + r) * DIMC + kt + sc * 8, As + dst);
        gload_lds16(B + (size_t)(n0 + r) * DIMC + kt + sc * 8, Bs + dst);
    }
}

__device__ __forceinline__ void gemm_compute32(
    const unsigned short* As, const unsigned short* Bs, f32x4 acc[4][4])
{
    const int t = threadIdx.x;
    const int w = t >> 6, lane = t & 63, quad = lane >> 4, lr = lane & 15;
    const int wr = w >> 1, wc = w & 1;
    bf16x8 af[4], bfr[4];
#pragma unroll
    for (int mt = 0; mt < 4; ++mt) {
        int row = wr * 64 + mt * 16 + lr;
        af[mt] = *(const bf16x8*)&As[(row >> 1) * 64 + (row & 1) * 32
                                     + ((quad ^ ((row >> 1) & 3)) * 8)];
    }
#pragma unroll
    for (int nt = 0; nt < 4; ++nt) {
        int row = wc * 64 + nt * 16 + lr;
        bfr[nt] = *(const bf16x8*)&Bs[(row >> 1) * 64 + (row & 1) * 32
                                      + ((quad ^ ((row >> 1) & 3)) * 8)];
    }
#pragma unroll
    for (int mt = 0; mt < 4; ++mt)
#pragma unroll
        for (int nt = 0; nt < 4; ++nt)
            acc[mt][nt] = __builtin_amdgcn_mfma_f32_16x16x32_bf16(af[mt], bfr[nt], acc[mt][nt], 0, 0, 0);
}

__device__ __forceinline__ void gemm_k_loop_db32(
    const unsigned short* __restrict__ A, const unsigned short* __restrict__ B,
    unsigned short* smem, int m0, int n0, f32x4 acc[4][4])
{
    unsigned short* As0 = smem;            // 8 KB each (64 lines x 128 B)
    unsigned short* Bs0 = smem + 4096;
    unsigned short* As1 = smem + 8192;
    unsigned short* Bs1 = smem + 12288;

    gemm_issue32(A, B, As0, Bs0, m0, n0, 0);
    for (int kt = 0; kt < DIMC; kt += 64) {
        __syncthreads();                   // publish buf0(kt)
        gemm_issue32(A, B, As1, Bs1, m0, n0, kt + 32);
        gemm_compute32(As0, Bs0, acc);
        __syncthreads();                   // publish buf1(kt+32)
        if (kt + 64 < DIMC) gemm_issue32(A, B, As0, Bs0, m0, n0, kt + 64);
        gemm_compute32(As1, Bs1, acc);
    }
}

// vT transpose epilogue (128-col tile, R8-verified): stage C-tile transposed
// in LDS, then coalesced 16B global stores to vT[b][h][d][n].
__device__ __forceinline__ void vt_epilogue(
    unsigned short* Ts, f32x4 acc[4][4], int m0, int n0,
    unsigned short* __restrict__ vT)
{
    const int t = threadIdx.x;
    const int w = t >> 6, lane = t & 63, quad = lane >> 4, lr = lane & 15;
    const int wr = w >> 1, wc = w & 1;

    __syncthreads();
#pragma unroll
    for (int mt = 0; mt < 4; ++mt)
#pragma unroll
        for (int nt = 0; nt < 4; ++nt) {
            int lcol  = wc * 64 + nt * 16 + lr;
            int lrow0 = wr * 64 + mt * 16 + quad * 4;
            ushort4 p;
            p.x = f2bf(acc[mt][nt][0]); p.y = f2bf(acc[mt][nt][1]);
            p.z = f2bf(acc[mt][nt][2]); p.w = f2bf(acc[mt][nt][3]);
            *(ushort4*)&Ts[lcol * TST + lrow0] = p;
        }
    __syncthreads();

    int lc = t >> 1, half = t & 1;
    int cg = n0 + lc, hh = cg >> 6, dd = cg & 63;
    int bb = m0 >> 11, nn0 = m0 & (SEQ - 1);
    size_t dst = ((size_t)((bb * NHEADS + hh) * HD + dd)) * SEQ + nn0 + half * 64;
    const unsigned short* srcp = &Ts[lc * TST + half * 64];
#pragma unroll
    for (int i = 0; i < 8; ++i)
        *(uint4*)&vT[dst + i * 8] = *(const uint4*)&srcp[i * 8];
}

// ---------------------------------------------------------------------------
// Fast QKV projection (v20): grid (8,32,3) = 768 blocks, fully co-resident
// at 3 blocks/CU.  Bijective XCD chunking over the 256 xy-tiles (R8's map).
// ---------------------------------------------------------------------------
__global__ __launch_bounds__(256, 3) void gemm_qkv_fast(
    const unsigned short* __restrict__ xb, const unsigned short* __restrict__ Wb,
    unsigned short* __restrict__ qo, unsigned short* __restrict__ ko,
    unsigned short* __restrict__ vT)
{
    __shared__ unsigned short smem[17408];   // 34 KB: 32 KB dbuf / 34 KB Ts

    const int t  = threadIdx.x;
    const int lin = blockIdx.y * 8 + blockIdx.x;      // 0..255
    const int T   = (lin & 7) * 32 + (lin >> 3);      // bijective XCD chunking
    const int n0 = (T & 7) * 128, m0 = (T >> 3) * 128, z = blockIdx.z;
    const unsigned short* B = Wb + (size_t)z * DIMC * DIMC;
    const int w = t >> 6, lane = t & 63, quad = lane >> 4, lr = lane & 15;
    const int wr = w >> 1, wc = w & 1;

    f32x4 acc[4][4];
#pragma unroll
    for (int mt = 0; mt < 4; ++mt)
#pragma unroll
        for (int nt = 0; nt < 4; ++nt)
#pragma unroll
            for (int r = 0; r < 4; ++r) acc[mt][nt][r] = 0.f;

    gemm_k_loop_db32(xb, B, smem, m0, n0, acc);

    if (z == 2) {
        vt_epilogue(smem, acc, m0, n0, vT);
    } else {
        unsigned short* Out = (z == 0) ? qo : ko;
        const float sc = (z == 0) ? QSCALE2 : 1.0f;
#pragma unroll
        for (int mt = 0; mt < 4; ++mt)
#pragma unroll
            for (int nt = 0; nt < 4; ++nt)
#pragma unroll
                for (int r = 0; r < 4; ++r) {
                    int row = m0 + wr * 64 + mt * 16 + quad * 4 + r;
                    int col = n0 + wc * 64 + nt * 16 + lr;
                    Out[(size_t)row * DIMC + col] = f2bf(acc[mt][nt][r] * sc);
                }
    }
}

// ---------------------------------------------------------------------------
// Fast output projection: R9's verified 128x64 geometry (512 blocks, 3/CU
// co-resident).  Unchanged.
// ---------------------------------------------------------------------------
__device__ __forceinline__ void gemm_issue_out(
    const unsigned short* __restrict__ A, const unsigned short* __restrict__ B,
    unsigned short* As, unsigned short* Bs, int m0, int n0, int kt)
{
    const int t = threadIdx.x;
    const int w = t >> 6, lane = t & 63;
    const int srow = lane >> 3, scol = lane & 7;
#pragma unroll
    for (int i = 0; i < 4; ++i) {
        int r  = i * 32 + w * 8 + srow;        // 0..127 (A rows)
        int cg = scol ^ (r & 7);
        gload_lds16(A + (size_t)(m0 + r) * DIMC + kt + cg * 8, As + r * 64 + scol * 8);
    }
#pragma unroll
    for (int i = 0; i < 2; ++i) {
        int r  = i * 32 + w * 8 + srow;        // 0..63 (B rows)
        int cg = scol ^ (r & 7);
        gload_lds16(B + (size_t)(n0 + r) * DIMC + kt + cg * 8, Bs + r * 64 + scol * 8);
    }
}

__device__ __forceinline__ void gemm_compute_out(
    const unsigned short* As, const unsigned short* Bs, f32x4 acc[4][2])
{
    const int t = threadIdx.x;
    const int w = t >> 6, lane = t & 63, quad = lane >> 4, lr = lane & 15;
    const int wr = w >> 1, wc = w & 1;
#pragma unroll
    for (int kk = 0; kk < 2; ++kk) {
        bf16x8 af[4], bfr[2];
#pragma unroll
        for (int mt = 0; mt < 4; ++mt) {
            int row = wr * 64 + mt * 16 + lr;
            int cb  = kk * 4 + quad;
            af[mt] = *(const bf16x8*)&As[row * 64 + (cb ^ (row & 7)) * 8];
        }
#pragma unroll
        for (int nt = 0; nt < 2; ++nt) {
            int row = wc * 32 + nt * 16 + lr;
            int cb  = kk * 4 + quad;
            bfr[nt] = *(const bf16x8*)&Bs[row * 64 + (cb ^ (row & 7)) * 8];
        }
#pragma unroll
        for (int mt = 0; mt < 4; ++mt)
#pragma unroll
            for (int nt = 0; nt < 2; ++nt)
                acc[mt][nt] = __builtin_amdgcn_mfma_f32_16x16x32_bf16(af[mt], bfr[nt], acc[mt][nt], 0, 0, 0);
    }
}

__global__ __launch_bounds__(256, 3) void gemm_out_fast(
    const unsigned short* __restrict__ O, const unsigned short* __restrict__ Wpb,
    const float* __restrict__ bias, float* __restrict__ out)
{
    __shared__ unsigned short smem[24576];   // 48 KB

    const int t  = threadIdx.x;
    const int lin = blockIdx.y * 16 + blockIdx.x;
    const int T   = (lin & 7) * 64 + (lin >> 3);
    const int n0 = (T & 15) * 64, m0 = (T >> 4) * 128;
    const int w = t >> 6, lane = t & 63, quad = lane >> 4, lr = lane & 15;
    const int wr = w >> 1, wc = w & 1;

    f32x4 acc[4][2];
#pragma unroll
    for (int mt = 0; mt < 4; ++mt)
#pragma unroll
        for (int nt = 0; nt < 2; ++nt)
#pragma unroll
            for (int r = 0; r < 4; ++r) acc[mt][nt][r] = 0.f;

    unsigned short* As0 = smem;              // 16 KB (128 x 64)
    unsigned short* Bs0 = smem + 8192;       //  8 KB ( 64 x 64)
    unsigned short* As1 = smem + 12288;
    unsigned short* Bs1 = smem + 20480;

    gemm_issue_out(O, Wpb, As0, Bs0, m0, n0, 0);
    for (int kt = 0; kt < DIMC; kt += 128) {
        __syncthreads();
        gemm_issue_out(O, Wpb, As1, Bs1, m0, n0, kt + 64);
        gemm_compute_out(As0, Bs0, acc);
        __syncthreads();
        if (kt + 128 < DIMC) gemm_issue_out(O, Wpb, As0, Bs0, m0, n0, kt + 128);
        gemm_compute_out(As1, Bs1, acc);
    }

#pragma unroll
    for (int mt = 0; mt < 4; ++mt)
#pragma unroll
        for (int nt = 0; nt < 2; ++nt)
#pragma unroll
            for (int r = 0; r < 4; ++r) {
                int row = m0 + wr * 64 + mt * 16 + quad * 4 + r;
                int col = n0 + wc * 32 + nt * 16 + lr;
                out[(size_t)row * DIMC + col] = acc[mt][nt][r] + bias[col];
            }
}

// ---------------------------------------------------------------------------
// Flash attention v18 (UNCHANGED from R8/R9, the 49.7-50.0 us proven config):
// v11 structure + T5 s_setprio.  128-row Q tile, 4 waves x 32 q-rows,
// S(t)/PV(t-1) software pipeline, Ps dbuf, V-in-registers; 2 blocks/CU.
// ---------------------------------------------------------------------------
__global__ __launch_bounds__(256, 2) void attn_kernel(
    const unsigned short* __restrict__ qg, const unsigned short* __restrict__ kg,
    const unsigned short* __restrict__ vT, unsigned short* __restrict__ og)
{
    __shared__ unsigned short Ka[64 * 64];
    __shared__ unsigned short Kb[64 * 64];
    __shared__ unsigned short Va[64 * 64];
    __shared__ unsigned short Vb[64 * 64];
    __shared__ unsigned short PsA[128 * 64];  // wave w owns rows w*32..w*32+31
    __shared__ unsigned short PsB[128 * 64];

    const int t  = threadIdx.x;
    const int w = t >> 6, l = t & 63, quad = l >> 4, lr = l & 15;
    const int srow = t >> 3, scol = t & 7;    // staging coords (256 threads: srow 0..31)
    const int pkey = (lr & 7) << 1;           // Ps swizzle key (even -> keeps pairs)

    // XCD-aware mapping: bid&7 = XCD; each XCD owns 4 full (b,h) pairs.
    const int bid  = blockIdx.x;              // 0..511
    const int slot = bid >> 3;                // 0..63
    const int bh   = (bid & 7) * 4 + (slot >> 4);
    const int qt   = slot & 15;               // 128-row Q tile index
    const int b    = bh >> 4, h = bh & 15;

    const unsigned short* khead = kg + ((size_t)(b * SEQ)) * DIMC + h * HD;
    const unsigned short* vhead = vT + (size_t)((b * NHEADS + h) * HD) * SEQ;

    // Q A-fragments (pre-scaled by QSCALE2): 2 m-tiles x 2 k-steps per wave
    bf16x8 qf[2][2];
#pragma unroll
    for (int mt = 0; mt < 2; ++mt) {
        const size_t qoff = ((size_t)(b * SEQ + qt * 128 + w * 32 + mt * 16 + lr)) * DIMC + h * HD;
        qf[mt][0] = *(const bf16x8*)(qg + qoff + 0  + quad * 8);
        qf[mt][1] = *(const bf16x8*)(qg + qoff + 32 + quad * 8);
    }

    bf16x8 ones;
#pragma unroll
    for (int j = 0; j < 8; ++j) ones[j] = (__bf16)1.0f;
    const f32x4 fzero = { 0.f, 0.f, 0.f, 0.f };

    f32x4 o_acc[2][4], lacc[2];
#pragma unroll
    for (int mt = 0; mt < 2; ++mt) {
        lacc[mt] = fzero;
#pragma unroll
        for (int ct = 0; ct < 4; ++ct) o_acc[mt][ct] = fzero;
    }

    auto issue = [&](int kt, unsigned short* Kd, unsigned short* Vd) {
#pragma unroll
        for (int i = 0; i < 2; ++i) {
            int r  = i * 32 + srow;            // 0..63
            int cg = scol ^ (r & 7);
            gload_lds16(khead + (size_t)(kt * 64 + r) * DIMC + cg * 8, Kd + r * 64 + scol * 8);
            gload_lds16(vhead + (size_t)r * SEQ + kt * 64 + cg * 8,   Vd + r * 64 + scol * 8);
        }
    };

    // S^T = K·Q^T : row = kv, col = m; chain seeded with fzero
    auto s_phase = [&](const unsigned short* Kc, f32x4 (&s)[2][4]) {
        __builtin_amdgcn_s_setprio(1);        // T5: keep matrix pipe fed
#pragma unroll
        for (int nt = 0; nt < 4; ++nt) {
            int row = nt * 16 + lr;
            bf16x8 kf = *(const bf16x8*)&Kc[row * 64 + ((quad ^ (row & 7)) * 8)];
#pragma unroll
            for (int mt = 0; mt < 2; ++mt)
                s[mt][nt] = __builtin_amdgcn_mfma_f32_16x16x32_bf16(kf, qf[mt][0], fzero, 0, 0, 0);
        }
#pragma unroll
        for (int nt = 0; nt < 4; ++nt) {
            int row = nt * 16 + lr;
            bf16x8 kf = *(const bf16x8*)&Kc[row * 64 + (((4 + quad) ^ (row & 7)) * 8)];
#pragma unroll
            for (int mt = 0; mt < 2; ++mt)
                s[mt][nt] = __builtin_amdgcn_mfma_f32_16x16x32_bf16(kf, qf[mt][1], s[mt][nt], 0, 0, 0);
        }
        __builtin_amdgcn_s_setprio(0);
    };

    // p = 2^s (raw v_exp), packed pair-wise, 8B swizzled stores: Ps[m][kv]
    auto exp_store = [&](const f32x4 (&s)[2][4], unsigned short* PsW) {
#pragma unroll
        for (int mt = 0; mt < 2; ++mt)
#pragma unroll
            for (int nt = 0; nt < 4; ++nt) {
                uint2 pp;
                pp.x = pk2bf(__builtin_amdgcn_exp2f(s[mt][nt][0]),
                             __builtin_amdgcn_exp2f(s[mt][nt][1]));
                pp.y = pk2bf(__builtin_amdgcn_exp2f(s[mt][nt][2]),
                             __builtin_amdgcn_exp2f(s[mt][nt][3]));
                *(uint2*)&PsW[(w * 32 + mt * 16 + lr) * 64 + (((nt * 4 + quad) ^ pkey) * 4)] = pp;
            }
    };

    // stage V(t) fragments to registers (used by PV in the NEXT phase,
    // after this LDS buffer has been handed back to the DMA engine)
    auto vload = [&](const unsigned short* Vc, bf16x8 (&vr)[8]) {
#pragma unroll
        for (int kk = 0; kk < 2; ++kk)
#pragma unroll
            for (int ct = 0; ct < 4; ++ct) {
                int row = ct * 16 + lr;
                vr[kk * 4 + ct] = *(const bf16x8*)&Vc[row * 64 + (((kk * 4 + quad) ^ (row & 7)) * 8)];
            }
    };

    // O += P*V ; l += P*1   (P from wave-private Ps buffer, V from registers)
    auto pv = [&](const unsigned short* PsR, const bf16x8 (&vr)[8]) {
        __builtin_amdgcn_s_setprio(1);        // T5
#pragma unroll
        for (int kk = 0; kk < 2; ++kk)
#pragma unroll
            for (int mt = 0; mt < 2; ++mt) {
                bf16x8 pf = *(const bf16x8*)&PsR[(w * 32 + mt * 16 + lr) * 64 + (((kk * 8 + quad * 2) ^ pkey) * 4)];
                lacc[mt] = __builtin_amdgcn_mfma_f32_16x16x32_bf16(pf, ones, lacc[mt], 0, 0, 0);
#pragma unroll
                for (int ct = 0; ct < 4; ++ct)
                    o_acc[mt][ct] = __builtin_amdgcn_mfma_f32_16x16x32_bf16(pf, vr[kk * 4 + ct], o_acc[mt][ct], 0, 0, 0);
            }
        __builtin_amdgcn_s_setprio(0);
    };

    bf16x8 vrA[8], vrB[8];

    issue(0, Ka, Va);
    for (int kt = 0; kt < SEQ / 64; kt += 2) {
        __syncthreads();                      // publish Ka/Va(kt)
        issue(kt + 1, Kb, Vb);
        {
            f32x4 s[2][4];
            s_phase(Ka, s);                   // S(kt)
            if (kt) pv(PsB, vrB);             // PV(kt-1): regs + PsB (independent)
            exp_store(s, PsA);                // P(kt) -> PsA
            vload(Va, vrA);                   // V(kt) -> regs (before Va is re-DMA'd)
        }
        __syncthreads();                      // publish Kb/Vb(kt+1)
        if (kt + 2 < SEQ / 64) issue(kt + 2, Ka, Va);
        {
            f32x4 s[2][4];
            s_phase(Kb, s);                   // S(kt+1)
            pv(PsA, vrA);                     // PV(kt)
            exp_store(s, PsB);                // P(kt+1) -> PsB
            vload(Vb, vrB);                   // V(kt+1) -> regs
        }
    }
    pv(PsB, vrB);                             // drain: PV(last tile)

#pragma unroll
    for (int mt = 0; mt < 2; ++mt) {
        float inv[4];
#pragma unroll
        for (int r = 0; r < 4; ++r) inv[r] = 1.0f / lacc[mt][r];
#pragma unroll
        for (int ct = 0; ct < 4; ++ct)
#pragma unroll
            for (int r = 0; r < 4; ++r) {
                int qrow = qt * 128 + w * 32 + mt * 16 + quad * 4 + r;
                og[((size_t)(b * SEQ + qrow)) * DIMC + h * HD + ct * 16 + lr] =
                    f2bf(o_acc[mt][ct][r] * inv[r]);
            }
    }
}

// ---------------------------------------------------------------------------
// Fallback path (ws < 40 MB): fp32-staging GEMMs.
// ---------------------------------------------------------------------------
__global__ __launch_bounds__(256) void gemm_qkv_f32(
    const float* __restrict__ x,
    const float* __restrict__ Wq, const float* __restrict__ Wk, const float* __restrict__ Wv,
    unsigned short* __restrict__ qo, unsigned short* __restrict__ ko, unsigned short* __restrict__ vT)
{
    __shared__ unsigned short smem[2 * 128 * AST];
    unsigned short* As = smem;
    unsigned short* Bs = smem + 128 * AST;

    const int t  = threadIdx.x;
    const int n0 = blockIdx.x * 128, m0 = blockIdx.y * 128, z = blockIdx.z;
    const float* W = (z == 0) ? Wq : (z == 1) ? Wk : Wv;
    const int w = t >> 6, l = t & 63, quad = l >> 4, lr = l & 15;
    const int wr = w >> 1, wc = w & 1;

    f32x4 acc[4][4];
#pragma unroll
    for (int mt = 0; mt < 4; ++mt)
#pragma unroll
        for (int nt = 0; nt < 4; ++nt)
#pragma unroll
            for (int r = 0; r < 4; ++r) acc[mt][nt][r] = 0.f;

    for (int kt = 0; kt < DIMC; kt += 64) {
        __syncthreads();
#pragma unroll
        for (int i = 0; i < 8; ++i) {
            int flat = t + i * 256;
            int row = flat >> 4, seg = flat & 15;
            float4 a = *(const float4*)(x + (size_t)(m0 + row) * DIMC + kt + seg * 4);
            ushort4 pa; pa.x = f2bf(a.x); pa.y = f2bf(a.y); pa.z = f2bf(a.z); pa.w = f2bf(a.w);
            *(ushort4*)&As[row * AST + seg * 4] = pa;
            float4 b = *(const float4*)(W + (size_t)(n0 + row) * DIMC + kt + seg * 4);
            ushort4 pb; pb.x = f2bf(b.x); pb.y = f2bf(b.y); pb.z = f2bf(b.z); pb.w = f2bf(b.w);
            *(ushort4*)&Bs[row * AST + seg * 4] = pb;
        }
        __syncthreads();
#pragma unroll
        for (int kk = 0; kk < 2; ++kk) {
            bf16x8 af[4], bfr[4];
#pragma unroll
            for (int mt = 0; mt < 4; ++mt)
                af[mt] = *(const bf16x8*)&As[(wr * 64 + mt * 16 + lr) * AST + kk * 32 + quad * 8];
#pragma unroll
            for (int nt = 0; nt < 4; ++nt)
                bfr[nt] = *(const bf16x8*)&Bs[(wc * 64 + nt * 16 + lr) * AST + kk * 32 + quad * 8];
#pragma unroll
            for (int mt = 0; mt < 4; ++mt)
#pragma unroll
                for (int nt = 0; nt < 4; ++nt)
                    acc[mt][nt] = __builtin_amdgcn_mfma_f32_16x16x32_bf16(af[mt], bfr[nt], acc[mt][nt], 0, 0, 0);
        }
    }

    if (z == 2) {
        __syncthreads();
#pragma unroll
        for (int mt = 0; mt < 4; ++mt)
#pragma unroll
            for (int nt = 0; nt < 4; ++nt) {
                int lcol  = wc * 64 + nt * 16 + lr;
                int lrow0 = wr * 64 + mt * 16 + quad * 4;
                ushort4 p;
                p.x = f2bf(acc[mt][nt][0]); p.y = f2bf(acc[mt][nt][1]);
                p.z = f2bf(acc[mt][nt][2]); p.w = f2bf(acc[mt][nt][3]);
                *(ushort4*)&smem[lcol * TST + lrow0] = p;
            }
        __syncthreads();
        int lc = t >> 1, half = t & 1;
        int cg = n0 + lc, hh = cg >> 6, dd = cg & 63;
        int bb = m0 >> 11, nn0 = m0 & (SEQ - 1);
        size_t dst = ((size_t)((bb * NHEADS + hh) * HD + dd)) * SEQ + nn0 + half * 64;
        const unsigned short* srcp = &smem[lc * TST + half * 64];
#pragma unroll
        for (int i = 0; i < 8; ++i)
            *(uint4*)&vT[dst + i * 8] = *(const uint4*)&srcp[i * 8];
    } else {
        unsigned short* Out = (z == 0) ? qo : ko;
        const float sc = (z == 0) ? QSCALE2 : 1.0f;
#pragma unroll
        for (int mt = 0; mt < 4; ++mt)
#pragma unroll
            for (int nt = 0; nt < 4; ++nt)
#pragma unroll
                for (int r = 0; r < 4; ++r) {
                    int row = m0 + wr * 64 + mt * 16 + quad * 4 + r;
                    int col = n0 + wc * 64 + nt * 16 + lr;
                    Out[(size_t)row * DIMC + col] = f2bf(acc[mt][nt][r] * sc);
                }
    }
}

__global__ __launch_bounds__(256) void gemm_out_f32(
    const unsigned short* __restrict__ A, const float* __restrict__ Wp,
    const float* __restrict__ bias, float* __restrict__ out)
{
    __shared__ unsigned short As[128 * AST];
    __shared__ unsigned short Bs[128 * AST];

    const int t  = threadIdx.x;
    const int n0 = blockIdx.x * 128, m0 = blockIdx.y * 128;
    const int w = t >> 6, l = t & 63, quad = l >> 4, lr = l & 15;
    const int wr = w >> 1, wc = w & 1;

    f32x4 acc[4][4];
#pragma unroll
    for (int mt = 0; mt < 4; ++mt)
#pragma unroll
        for (int nt = 0; nt < 4; ++nt)
#pragma unroll
            for (int r = 0; r < 4; ++r) acc[mt][nt][r] = 0.f;

    for (int kt = 0; kt < DIMC; kt += 64) {
        __syncthreads();
#pragma unroll
        for (int i = 0; i < 8; ++i) {
            int flat = t + i * 256;
            int row = flat >> 4, seg = flat & 15;
            ushort4 a = *(const ushort4*)(A + (size_t)(m0 + row) * DIMC + kt + seg * 4);
            *(ushort4*)&As[row * AST + seg * 4] = a;
            float4 b = *(const float4*)(Wp + (size_t)(n0 + row) * DIMC + kt + seg * 4);
            ushort4 pb; pb.x = f2bf(b.x); pb.y = f2bf(b.y); pb.z = f2bf(b.z); pb.w = f2bf(b.w);
            *(ushort4*)&Bs[row * AST + seg * 4] = pb;
        }
        __syncthreads();
#pragma unroll
        for (int kk = 0; kk < 2; ++kk) {
            bf16x8 af[4], bfr[4];
#pragma unroll
            for (int mt = 0; mt < 4; ++mt)
                af[mt] = *(const bf16x8*)&As[(wr * 64 + mt * 16 + lr) * AST + kk * 32 + quad * 8];
#pragma unroll
            for (int nt = 0; nt < 4; ++nt)
                bfr[nt] = *(const bf16x8*)&Bs[(wc * 64 + nt * 16 + lr) * AST + kk * 32 + quad * 8];
#pragma unroll
            for (int mt = 0; mt < 4; ++mt)
#pragma unroll
                for (int nt = 0; nt < 4; ++nt)
                    acc[mt][nt] = __builtin_amdgcn_mfma_f32_16x16x32_bf16(af[mt], bfr[nt], acc[mt][nt], 0, 0, 0);
        }
    }

#pragma unroll
    for (int mt = 0; mt < 4; ++mt)
#pragma unroll
        for (int nt = 0; nt < 4; ++nt)
#pragma unroll
            for (int r = 0; r < 4; ++r) {
                int row = m0 + wr * 64 + mt * 16 + quad * 4 + r;
                int col = n0 + wc * 64 + nt * 16 + lr;
                out[(size_t)row * DIMC + col] = acc[mt][nt][r] + bias[col];
            }
}

// ---------------------------------------------------------------------------
extern "C" void kernel_launch(void* const* d_in, const int* in_sizes, int n_in,
                              void* d_out, int out_size, void* d_ws, size_t ws_size,
                              hipStream_t stream)
{
    const float* x  = (const float*)d_in[0];
    const float* Wq = (const float*)d_in[1];
    const float* Wk = (const float*)d_in[2];
    const float* Wv = (const float*)d_in[3];
    const float* Wp = (const float*)d_in[4];
    const float* bp = (const float*)d_in[5];
    float* out = (float*)d_out;

    const size_t SZ  = (size_t)MROWS * DIMC;   // 4M elems
    const size_t WSZ = (size_t)DIMC * DIMC;    // 1M elems
    const size_t need = (4 * SZ + 4 * WSZ) * sizeof(unsigned short);  // 40 MB

    if (ws_size >= need) {
        unsigned short* q  = (unsigned short*)d_ws;
        unsigned short* k  = q + SZ;
        unsigned short* vt = k + SZ;
        unsigned short* o  = vt + SZ;
        unsigned short* Wb = o + SZ;
        unsigned short* xb = (unsigned short*)d_out;   // scratch: dead before gemm_out writes

        cast_all<<<dim3(1024, 8), 256, 0, stream>>>(x, Wq, Wk, Wv, Wp, xb, Wb);
        gemm_qkv_fast<<<dim3(8, 32, 3), 256, 0, stream>>>(xb, Wb, q, k, vt);
        attn_kernel<<<dim3(512), 256, 0, stream>>>(q, k, vt, o);
        gemm_out_fast<<<dim3(16, 32), 256, 0, stream>>>(o, Wb + 3 * WSZ, bp, out);
    } else {
        unsigned short* q  = (unsigned short*)d_ws;
        unsigned short* k  = q + SZ;
        unsigned short* vt = k + SZ;
        unsigned short* o  = vt + SZ;

        gemm_qkv_f32<<<dim3(DIMC / 128, MROWS / 128, 3), 256, 0, stream>>>(x, Wq, Wk, Wv, q, k, vt);
        attn_kernel<<<dim3(512), 256, 0, stream>>>(q, k, vt, o);
        gemm_out_f32<<<dim3(DIMC / 128, MROWS / 128), 256, 0, stream>>>(o, Wp, bp, out);
    }
}

// Round 11
// 170.602 us; speedup vs baseline: 1.1564x; 1.0082x over previous
//
#include <hip/hip_runtime.h>
#include <cstdint>

#define DIMC   1024
#define NHEADS 16
#define HD     64
#define BATCH  2
#define SEQ    2048
#define MROWS  (BATCH*SEQ)   // 4096
// Q pre-scale: (1/sqrt(64)) * log2(e)  -> softmax computed in base 2 (exact)
#define QSCALE2 0.18033688f

typedef __bf16 bf16x8 __attribute__((ext_vector_type(8)));
typedef float  f32x4  __attribute__((ext_vector_type(4)));

#define AST 88    // fallback LDS row stride (bf16 elems)
#define TST 136   // transpose-epilogue LDS stride

__device__ __forceinline__ unsigned short f2bf(float f) {
    union { float f; unsigned int u; } v; v.f = f;
    unsigned int u = v.u;
    u += 0x7fffu + ((u >> 16) & 1u);   // round-to-nearest-even
    return (unsigned short)(u >> 16);
}

// pack two floats to bf16x2 (round-nearest, ties away): 2 adds + 1 v_perm
__device__ __forceinline__ unsigned int pk2bf(float a, float b) {
    union { float f; unsigned int u; } ua, ub;
    ua.f = a; ub.f = b;
    return __builtin_amdgcn_perm(ub.u + 0x8000u, ua.u + 0x8000u, 0x07060302u);
}

__device__ __forceinline__ void gload_lds16(const void* g, void* l) {
    __builtin_amdgcn_global_load_lds(
        (const __attribute__((address_space(1))) unsigned int*)g,
        (__attribute__((address_space(3))) unsigned int*)l, 16, 0, 0);
}

// T4 counted-vmcnt barrier: wait only the OLDEST 4 outstanding VMEM ops
// (the current tile's DMA), leaving the next tile's 4 in flight across the
// raw s_barrier.  "memory" clobber pins all LDS/global ops; sched_barrier
// pins the scheduler (guide rule 18).
#define WAITBAR4() do { asm volatile("s_waitcnt vmcnt(4)" ::: "memory"); \
                        __builtin_amdgcn_s_barrier();                    \
                        __builtin_amdgcn_sched_barrier(0); } while (0)
#define WAITBAR0() do { asm volatile("s_waitcnt vmcnt(0)" ::: "memory"); \
                        __builtin_amdgcn_s_barrier();                    \
                        __builtin_amdgcn_sched_barrier(0); } while (0)

// ---------------------------------------------------------------------------
// Pre-cast fp32 -> bf16: x (4M elems) and Wq|Wk|Wv|Wp (1M each) into xb / Wb.
// ---------------------------------------------------------------------------
__global__ __launch_bounds__(256) void cast_all(
    const float* __restrict__ x,
    const float* __restrict__ Wq, const float* __restrict__ Wk,
    const float* __restrict__ Wv, const float* __restrict__ Wp,
    unsigned short* __restrict__ xb, unsigned short* __restrict__ Wb)
{
    const size_t M1 = (size_t)DIMC * DIMC;   // 1M elems
    int y = blockIdx.y;
    const float* src;
    unsigned short* dst;
    if (y < 4)      { src = x  + (size_t)y * M1; dst = xb + (size_t)y * M1; }
    else if (y == 4){ src = Wq; dst = Wb; }
    else if (y == 5){ src = Wk; dst = Wb + M1; }
    else if (y == 6){ src = Wv; dst = Wb + 2 * M1; }
    else            { src = Wp; dst = Wb + 3 * M1; }
    size_t idx = ((size_t)blockIdx.x * 256 + threadIdx.x) * 4;
    float4 v = *(const float4*)(src + idx);
    ushort4 p; p.x = f2bf(v.x); p.y = f2bf(v.y); p.z = f2bf(v.z); p.w = f2bf(v.w);
    *(ushort4*)(dst + idx) = p;
}

// ---------------------------------------------------------------------------
// v20 qkv GEMM (unchanged from R10): 128x128 tile, BK=32, 32 KB dbuf,
// pair-row-interleaved LDS layout, 3 blocks/CU, 768 co-resident blocks.
// ---------------------------------------------------------------------------
__device__ __forceinline__ void gemm_issue32(
    const unsigned short* __restrict__ A, const unsigned short* __restrict__ B,
    unsigned short* As, unsigned short* Bs, int m0, int n0, int kt)
{
    const int t = threadIdx.x;
    const int rr = t >> 2, cg = t & 3;     // rr 0..63, physical chunk 0..3
#pragma unroll
    for (int i = 0; i < 2; ++i) {
        int r  = i * 64 + rr;              // logical row 0..127
        int sc = cg ^ ((r >> 1) & 3);      // source k-chunk (swizzled)
        int dst = (r >> 1) * 64 + (r & 1) * 32 + cg * 8;
        gload_lds16(A + (size_t)(m0 + r) * DIMC + kt + sc * 8, As + dst);
        gload_lds16(B + (size_t)(n0 + r) * DIMC + kt + sc * 8, Bs + dst);
    }
}

__device__ __forceinline__ void gemm_compute32(
    const unsigned short* As, const unsigned short* Bs, f32x4 acc[4][4])
{
    const int t = threadIdx.x;
    const int w = t >> 6, lane = t & 63, quad = lane >> 4, lr = lane & 15;
    const int wr = w >> 1, wc = w & 1;
    bf16x8 af[4], bfr[4];
#pragma unroll
    for (int mt = 0; mt < 4; ++mt) {
        int row = wr * 64 + mt * 16 + lr;
        af[mt] = *(const bf16x8*)&As[(row >> 1) * 64 + (row & 1) * 32
                                     + ((quad ^ ((row >> 1) & 3)) * 8)];
    }
#pragma unroll
    for (int nt = 0; nt < 4; ++nt) {
        int row = wc * 64 + nt * 16 + lr;
        bfr[nt] = *(const bf16x8*)&Bs[(row >> 1) * 64 + (row & 1) * 32
                                      + ((quad ^ ((row >> 1) & 3)) * 8)];
    }
#pragma unroll
    for (int mt = 0; mt < 4; ++mt)
#pragma unroll
        for (int nt = 0; nt < 4; ++nt)
            acc[mt][nt] = __builtin_amdgcn_mfma_f32_16x16x32_bf16(af[mt], bfr[nt], acc[mt][nt], 0, 0, 0);
}

__device__ __forceinline__ void gemm_k_loop_db32(
    const unsigned short* __restrict__ A, const unsigned short* __restrict__ B,
    unsigned short* smem, int m0, int n0, f32x4 acc[4][4])
{
    unsigned short* As0 = smem;            // 8 KB each (64 lines x 128 B)
    unsigned short* Bs0 = smem + 4096;
    unsigned short* As1 = smem + 8192;
    unsigned short* Bs1 = smem + 12288;

    gemm_issue32(A, B, As0, Bs0, m0, n0, 0);
    for (int kt = 0; kt < DIMC; kt += 64) {
        __syncthreads();                   // publish buf0(kt)
        gemm_issue32(A, B, As1, Bs1, m0, n0, kt + 32);
        gemm_compute32(As0, Bs0, acc);
        __syncthreads();                   // publish buf1(kt+32)
        if (kt + 64 < DIMC) gemm_issue32(A, B, As0, Bs0, m0, n0, kt + 64);
        gemm_compute32(As1, Bs1, acc);
    }
}

// vT transpose epilogue (128-col tile, R8-verified): stage C-tile transposed
// in LDS, then coalesced 16B global stores to vT[b][h][d][n].
__device__ __forceinline__ void vt_epilogue(
    unsigned short* Ts, f32x4 acc[4][4], int m0, int n0,
    unsigned short* __restrict__ vT)
{
    const int t = threadIdx.x;
    const int w = t >> 6, lane = t & 63, quad = lane >> 4, lr = lane & 15;
    const int wr = w >> 1, wc = w & 1;

    __syncthreads();
#pragma unroll
    for (int mt = 0; mt < 4; ++mt)
#pragma unroll
        for (int nt = 0; nt < 4; ++nt) {
            int lcol  = wc * 64 + nt * 16 + lr;
            int lrow0 = wr * 64 + mt * 16 + quad * 4;
            ushort4 p;
            p.x = f2bf(acc[mt][nt][0]); p.y = f2bf(acc[mt][nt][1]);
            p.z = f2bf(acc[mt][nt][2]); p.w = f2bf(acc[mt][nt][3]);
            *(ushort4*)&Ts[lcol * TST + lrow0] = p;
        }
    __syncthreads();

    int lc = t >> 1, half = t & 1;
    int cg = n0 + lc, hh = cg >> 6, dd = cg & 63;
    int bb = m0 >> 11, nn0 = m0 & (SEQ - 1);
    size_t dst = ((size_t)((bb * NHEADS + hh) * HD + dd)) * SEQ + nn0 + half * 64;
    const unsigned short* srcp = &Ts[lc * TST + half * 64];
#pragma unroll
    for (int i = 0; i < 8; ++i)
        *(uint4*)&vT[dst + i * 8] = *(const uint4*)&srcp[i * 8];
}

// ---------------------------------------------------------------------------
// Fast QKV projection (v20, unchanged): grid (8,32,3) = 768 blocks.
// ---------------------------------------------------------------------------
__global__ __launch_bounds__(256, 3) void gemm_qkv_fast(
    const unsigned short* __restrict__ xb, const unsigned short* __restrict__ Wb,
    unsigned short* __restrict__ qo, unsigned short* __restrict__ ko,
    unsigned short* __restrict__ vT)
{
    __shared__ unsigned short smem[17408];   // 34 KB: 32 KB dbuf / 34 KB Ts

    const int t  = threadIdx.x;
    const int lin = blockIdx.y * 8 + blockIdx.x;      // 0..255
    const int T   = (lin & 7) * 32 + (lin >> 3);      // bijective XCD chunking
    const int n0 = (T & 7) * 128, m0 = (T >> 3) * 128, z = blockIdx.z;
    const unsigned short* B = Wb + (size_t)z * DIMC * DIMC;
    const int w = t >> 6, lane = t & 63, quad = lane >> 4, lr = lane & 15;
    const int wr = w >> 1, wc = w & 1;

    f32x4 acc[4][4];
#pragma unroll
    for (int mt = 0; mt < 4; ++mt)
#pragma unroll
        for (int nt = 0; nt < 4; ++nt)
#pragma unroll
            for (int r = 0; r < 4; ++r) acc[mt][nt][r] = 0.f;

    gemm_k_loop_db32(xb, B, smem, m0, n0, acc);

    if (z == 2) {
        vt_epilogue(smem, acc, m0, n0, vT);
    } else {
        unsigned short* Out = (z == 0) ? qo : ko;
        const float sc = (z == 0) ? QSCALE2 : 1.0f;
#pragma unroll
        for (int mt = 0; mt < 4; ++mt)
#pragma unroll
            for (int nt = 0; nt < 4; ++nt)
#pragma unroll
                for (int r = 0; r < 4; ++r) {
                    int row = m0 + wr * 64 + mt * 16 + quad * 4 + r;
                    int col = n0 + wc * 64 + nt * 16 + lr;
                    Out[(size_t)row * DIMC + col] = f2bf(acc[mt][nt][r] * sc);
                }
    }
}

// ---------------------------------------------------------------------------
// Fast output projection (R9/R10 verified 128x64 geometry, unchanged).
// ---------------------------------------------------------------------------
__device__ __forceinline__ void gemm_issue_out(
    const unsigned short* __restrict__ A, const unsigned short* __restrict__ B,
    unsigned short* As, unsigned short* Bs, int m0, int n0, int kt)
{
    const int t = threadIdx.x;
    const int w = t >> 6, lane = t & 63;
    const int srow = lane >> 3, scol = lane & 7;
#pragma unroll
    for (int i = 0; i < 4; ++i) {
        int r  = i * 32 + w * 8 + srow;        // 0..127 (A rows)
        int cg = scol ^ (r & 7);
        gload_lds16(A + (size_t)(m0 + r) * DIMC + kt + cg * 8, As + r * 64 + scol * 8);
    }
#pragma unroll
    for (int i = 0; i < 2; ++i) {
        int r  = i * 32 + w * 8 + srow;        // 0..63 (B rows)
        int cg = scol ^ (r & 7);
        gload_lds16(B + (size_t)(n0 + r) * DIMC + kt + cg * 8, Bs + r * 64 + scol * 8);
    }
}

__device__ __forceinline__ void gemm_compute_out(
    const unsigned short* As, const unsigned short* Bs, f32x4 acc[4][2])
{
    const int t = threadIdx.x;
    const int w = t >> 6, lane = t & 63, quad = lane >> 4, lr = lane & 15;
    const int wr = w >> 1, wc = w & 1;
#pragma unroll
    for (int kk = 0; kk < 2; ++kk) {
        bf16x8 af[4], bfr[2];
#pragma unroll
        for (int mt = 0; mt < 4; ++mt) {
            int row = wr * 64 + mt * 16 + lr;
            int cb  = kk * 4 + quad;
            af[mt] = *(const bf16x8*)&As[row * 64 + (cb ^ (row & 7)) * 8];
        }
#pragma unroll
        for (int nt = 0; nt < 2; ++nt) {
            int row = wc * 32 + nt * 16 + lr;
            int cb  = kk * 4 + quad;
            bfr[nt] = *(const bf16x8*)&Bs[row * 64 + (cb ^ (row & 7)) * 8];
        }
#pragma unroll
        for (int mt = 0; mt < 4; ++mt)
#pragma unroll
            for (int nt = 0; nt < 2; ++nt)
                acc[mt][nt] = __builtin_amdgcn_mfma_f32_16x16x32_bf16(af[mt], bfr[nt], acc[mt][nt], 0, 0, 0);
    }
}

__global__ __launch_bounds__(256, 3) void gemm_out_fast(
    const unsigned short* __restrict__ O, const unsigned short* __restrict__ Wpb,
    const float* __restrict__ bias, float* __restrict__ out)
{
    __shared__ unsigned short smem[24576];   // 48 KB

    const int t  = threadIdx.x;
    const int lin = blockIdx.y * 16 + blockIdx.x;
    const int T   = (lin & 7) * 64 + (lin >> 3);
    const int n0 = (T & 15) * 64, m0 = (T >> 4) * 128;
    const int w = t >> 6, lane = t & 63, quad = lane >> 4, lr = lane & 15;
    const int wr = w >> 1, wc = w & 1;

    f32x4 acc[4][2];
#pragma unroll
    for (int mt = 0; mt < 4; ++mt)
#pragma unroll
        for (int nt = 0; nt < 2; ++nt)
#pragma unroll
            for (int r = 0; r < 4; ++r) acc[mt][nt][r] = 0.f;

    unsigned short* As0 = smem;              // 16 KB (128 x 64)
    unsigned short* Bs0 = smem + 8192;       //  8 KB ( 64 x 64)
    unsigned short* As1 = smem + 12288;
    unsigned short* Bs1 = smem + 20480;

    gemm_issue_out(O, Wpb, As0, Bs0, m0, n0, 0);
    for (int kt = 0; kt < DIMC; kt += 128) {
        __syncthreads();
        gemm_issue_out(O, Wpb, As1, Bs1, m0, n0, kt + 64);
        gemm_compute_out(As0, Bs0, acc);
        __syncthreads();
        if (kt + 128 < DIMC) gemm_issue_out(O, Wpb, As0, Bs0, m0, n0, kt + 128);
        gemm_compute_out(As1, Bs1, acc);
    }

#pragma unroll
    for (int mt = 0; mt < 4; ++mt)
#pragma unroll
        for (int nt = 0; nt < 2; ++nt)
#pragma unroll
            for (int r = 0; r < 4; ++r) {
                int row = m0 + wr * 64 + mt * 16 + quad * 4 + r;
                int col = n0 + wc * 32 + nt * 16 + lr;
                out[(size_t)row * DIMC + col] = acc[mt][nt][r] + bias[col];
            }
}

// ---------------------------------------------------------------------------
// Flash attention v21 = v18 + T3/T4 counted-vmcnt deep prefetch.
//   R10 analysis: all pipes <40% at 50 us; the residual stall is the
//   __syncthreads vmcnt(0) drain killing DMA overlap (prefetch distance
//   capped at 1 compute phase).  v21: 3-deep K/V buffers (tile t -> buf t%3,
//   compile-time names via 3-unrolled loop), raw s_barrier + s_waitcnt
//   vmcnt(4) (wait only the current tile's 4 loads; next tile's 4 stay in
//   flight) -> each DMA gets TWO compute phases to land.
//   To fit 64 KB static LDS: Ps single-buffered + single vr set — correct
//   because pv(t-1) reads Ps BEFORE exp_store(t) overwrites (same-wave DS
//   ops are in-order; compiler alias-constrained), and pv precedes vload.
//   LDS = 6x8 KB K/V + 16 KB Ps = 64 KB; 2 blocks/CU.  Fragment maps,
//   swizzles, S^T trick, setprio: byte-identical to v18.
// ---------------------------------------------------------------------------
__global__ __launch_bounds__(256, 2) void attn_kernel(
    const unsigned short* __restrict__ qg, const unsigned short* __restrict__ kg,
    const unsigned short* __restrict__ vT, unsigned short* __restrict__ og)
{
    __shared__ unsigned short K0s[64 * 64];
    __shared__ unsigned short K1s[64 * 64];
    __shared__ unsigned short K2s[64 * 64];
    __shared__ unsigned short V0s[64 * 64];
    __shared__ unsigned short V1s[64 * 64];
    __shared__ unsigned short V2s[64 * 64];
    __shared__ unsigned short Ps[128 * 64];   // wave w owns rows w*32..w*32+31

    const int t  = threadIdx.x;
    const int w = t >> 6, l = t & 63, quad = l >> 4, lr = l & 15;
    const int srow = t >> 3, scol = t & 7;    // staging coords (256 threads: srow 0..31)
    const int pkey = (lr & 7) << 1;           // Ps swizzle key (even -> keeps pairs)

    // XCD-aware mapping: bid&7 = XCD; each XCD owns 4 full (b,h) pairs.
    const int bid  = blockIdx.x;              // 0..511
    const int slot = bid >> 3;                // 0..63
    const int bh   = (bid & 7) * 4 + (slot >> 4);
    const int qt   = slot & 15;               // 128-row Q tile index
    const int b    = bh >> 4, h = bh & 15;

    const unsigned short* khead = kg + ((size_t)(b * SEQ)) * DIMC + h * HD;
    const unsigned short* vhead = vT + (size_t)((b * NHEADS + h) * HD) * SEQ;

    // Q A-fragments (pre-scaled by QSCALE2): 2 m-tiles x 2 k-steps per wave
    bf16x8 qf[2][2];
#pragma unroll
    for (int mt = 0; mt < 2; ++mt) {
        const size_t qoff = ((size_t)(b * SEQ + qt * 128 + w * 32 + mt * 16 + lr)) * DIMC + h * HD;
        qf[mt][0] = *(const bf16x8*)(qg + qoff + 0  + quad * 8);
        qf[mt][1] = *(const bf16x8*)(qg + qoff + 32 + quad * 8);
    }

    bf16x8 ones;
#pragma unroll
    for (int j = 0; j < 8; ++j) ones[j] = (__bf16)1.0f;
    const f32x4 fzero = { 0.f, 0.f, 0.f, 0.f };

    f32x4 o_acc[2][4], lacc[2];
#pragma unroll
    for (int mt = 0; mt < 2; ++mt) {
        lacc[mt] = fzero;
#pragma unroll
        for (int ct = 0; ct < 4; ++ct) o_acc[mt][ct] = fzero;
    }

    auto issue = [&](int kt, unsigned short* Kd, unsigned short* Vd) {
#pragma unroll
        for (int i = 0; i < 2; ++i) {
            int r  = i * 32 + srow;            // 0..63
            int cg = scol ^ (r & 7);
            gload_lds16(khead + (size_t)(kt * 64 + r) * DIMC + cg * 8, Kd + r * 64 + scol * 8);
            gload_lds16(vhead + (size_t)r * SEQ + kt * 64 + cg * 8,   Vd + r * 64 + scol * 8);
        }
    };

    // S^T = K·Q^T : row = kv, col = m; chain seeded with fzero
    auto s_phase = [&](const unsigned short* Kc, f32x4 (&s)[2][4]) {
        __builtin_amdgcn_s_setprio(1);        // T5: keep matrix pipe fed
#pragma unroll
        for (int nt = 0; nt < 4; ++nt) {
            int row = nt * 16 + lr;
            bf16x8 kf = *(const bf16x8*)&Kc[row * 64 + ((quad ^ (row & 7)) * 8)];
#pragma unroll
            for (int mt = 0; mt < 2; ++mt)
                s[mt][nt] = __builtin_amdgcn_mfma_f32_16x16x32_bf16(kf, qf[mt][0], fzero, 0, 0, 0);
        }
#pragma unroll
        for (int nt = 0; nt < 4; ++nt) {
            int row = nt * 16 + lr;
            bf16x8 kf = *(const bf16x8*)&Kc[row * 64 + (((4 + quad) ^ (row & 7)) * 8)];
#pragma unroll
            for (int mt = 0; mt < 2; ++mt)
                s[mt][nt] = __builtin_amdgcn_mfma_f32_16x16x32_bf16(kf, qf[mt][1], s[mt][nt], 0, 0, 0);
        }
        __builtin_amdgcn_s_setprio(0);
    };

    // p = 2^s (raw v_exp), packed pair-wise, 8B swizzled stores: Ps[m][kv]
    auto exp_store = [&](const f32x4 (&s)[2][4]) {
#pragma unroll
        for (int mt = 0; mt < 2; ++mt)
#pragma unroll
            for (int nt = 0; nt < 4; ++nt) {
                uint2 pp;
                pp.x = pk2bf(__builtin_amdgcn_exp2f(s[mt][nt][0]),
                             __builtin_amdgcn_exp2f(s[mt][nt][1]));
                pp.y = pk2bf(__builtin_amdgcn_exp2f(s[mt][nt][2]),
                             __builtin_amdgcn_exp2f(s[mt][nt][3]));
                *(uint2*)&Ps[(w * 32 + mt * 16 + lr) * 64 + (((nt * 4 + quad) ^ pkey) * 4)] = pp;
            }
    };

    // stage V(t) fragments to registers (used by pv in the NEXT sub-phase)
    bf16x8 vr[8];
    auto vload = [&](const unsigned short* Vc) {
#pragma unroll
        for (int kk = 0; kk < 2; ++kk)
#pragma unroll
            for (int ct = 0; ct < 4; ++ct) {
                int row = ct * 16 + lr;
                vr[kk * 4 + ct] = *(const bf16x8*)&Vc[row * 64 + (((kk * 4 + quad) ^ (row & 7)) * 8)];
            }
    };

    // O += P*V ; l += P*1   (P = previous tile, from wave-private Ps rows)
    auto pv = [&]() {
        __builtin_amdgcn_s_setprio(1);        // T5
#pragma unroll
        for (int kk = 0; kk < 2; ++kk)
#pragma unroll
            for (int mt = 0; mt < 2; ++mt) {
                bf16x8 pf = *(const bf16x8*)&Ps[(w * 32 + mt * 16 + lr) * 64 + (((kk * 8 + quad * 2) ^ pkey) * 4)];
                lacc[mt] = __builtin_amdgcn_mfma_f32_16x16x32_bf16(pf, ones, lacc[mt], 0, 0, 0);
#pragma unroll
                for (int ct = 0; ct < 4; ++ct)
                    o_acc[mt][ct] = __builtin_amdgcn_mfma_f32_16x16x32_bf16(pf, vr[kk * 4 + ct], o_acc[mt][ct], 0, 0, 0);
            }
        __builtin_amdgcn_s_setprio(0);
    };

    // sub-phase for tile t: S(t) || PV(t-1), then P(t)->Ps, V(t)->vr.
    // pv BEFORE exp_store (write-after-read on Ps, same-wave in-order DS)
    // and BEFORE vload (register anti-dependency).
    auto subphase = [&](const unsigned short* Kc, const unsigned short* Vc, bool first) {
        f32x4 s[2][4];
        s_phase(Kc, s);
        if (!first) pv();
        exp_store(s);
        vload(Vc);
    };

    // Prologue: 2 tiles in flight (8 loads/lane).
    issue(0, K0s, V0s);
    issue(1, K1s, V1s);

    // Tiles 0..29 in blocks of 3 (buffer names compile-time); issues reach 31.
    for (int base = 0; base < 30; base += 3) {
        WAITBAR4(); issue(base + 2, K2s, V2s); subphase(K0s, V0s, base == 0);
        WAITBAR4(); issue(base + 3, K0s, V0s); subphase(K1s, V1s, false);
        WAITBAR4(); issue(base + 4, K1s, V1s); subphase(K2s, V2s, false);
    }
    // Tail: tile 30 (buf0; {30,31} outstanding) and 31 (buf1; {31} left).
    WAITBAR4(); subphase(K0s, V0s, false);
    WAITBAR0(); subphase(K1s, V1s, false);
    pv();                                     // drain: PV(tile 31)

#pragma unroll
    for (int mt = 0; mt < 2; ++mt) {
        float inv[4];
#pragma unroll
        for (int r = 0; r < 4; ++r) inv[r] = 1.0f / lacc[mt][r];
#pragma unroll
        for (int ct = 0; ct < 4; ++ct)
#pragma unroll
            for (int r = 0; r < 4; ++r) {
                int qrow = qt * 128 + w * 32 + mt * 16 + quad * 4 + r;
                og[((size_t)(b * SEQ + qrow)) * DIMC + h * HD + ct * 16 + lr] =
                    f2bf(o_acc[mt][ct][r] * inv[r]);
            }
    }
}

// ---------------------------------------------------------------------------
// Fallback path (ws < 40 MB): fp32-staging GEMMs.
// ---------------------------------------------------------------------------
__global__ __launch_bounds__(256) void gemm_qkv_f32(
    const float* __restrict__ x,
    const float* __restrict__ Wq, const float* __restrict__ Wk, const float* __restrict__ Wv,
    unsigned short* __restrict__ qo, unsigned short* __restrict__ ko, unsigned short* __restrict__ vT)
{
    __shared__ unsigned short smem[2 * 128 * AST];
    unsigned short* As = smem;
    unsigned short* Bs = smem + 128 * AST;

    const int t  = threadIdx.x;
    const int n0 = blockIdx.x * 128, m0 = blockIdx.y * 128, z = blockIdx.z;
    const float* W = (z == 0) ? Wq : (z == 1) ? Wk : Wv;
    const int w = t >> 6, l = t & 63, quad = l >> 4, lr = l & 15;
    const int wr = w >> 1, wc = w & 1;

    f32x4 acc[4][4];
#pragma unroll
    for (int mt = 0; mt < 4; ++mt)
#pragma unroll
        for (int nt = 0; nt < 4; ++nt)
#pragma unroll
            for (int r = 0; r < 4; ++r) acc[mt][nt][r] = 0.f;

    for (int kt = 0; kt < DIMC; kt += 64) {
        __syncthreads();
#pragma unroll
        for (int i = 0; i < 8; ++i) {
            int flat = t + i * 256;
            int row = flat >> 4, seg = flat & 15;
            float4 a = *(const float4*)(x + (size_t)(m0 + row) * DIMC + kt + seg * 4);
            ushort4 pa; pa.x = f2bf(a.x); pa.y = f2bf(a.y); pa.z = f2bf(a.z); pa.w = f2bf(a.w);
            *(ushort4*)&As[row * AST + seg * 4] = pa;
            float4 b = *(const float4*)(W + (size_t)(n0 + row) * DIMC + kt + seg * 4);
            ushort4 pb; pb.x = f2bf(b.x); pb.y = f2bf(b.y); pb.z = f2bf(b.z); pb.w = f2bf(b.w);
            *(ushort4*)&Bs[row * AST + seg * 4] = pb;
        }
        __syncthreads();
#pragma unroll
        for (int kk = 0; kk < 2; ++kk) {
            bf16x8 af[4], bfr[4];
#pragma unroll
            for (int mt = 0; mt < 4; ++mt)
                af[mt] = *(const bf16x8*)&As[(wr * 64 + mt * 16 + lr) * AST + kk * 32 + quad * 8];
#pragma unroll
            for (int nt = 0; nt < 4; ++nt)
                bfr[nt] = *(const bf16x8*)&Bs[(wc * 64 + nt * 16 + lr) * AST + kk * 32 + quad * 8];
#pragma unroll
            for (int mt = 0; mt < 4; ++mt)
#pragma unroll
                for (int nt = 0; nt < 4; ++nt)
                    acc[mt][nt] = __builtin_amdgcn_mfma_f32_16x16x32_bf16(af[mt], bfr[nt], acc[mt][nt], 0, 0, 0);
        }
    }

    if (z == 2) {
        __syncthreads();
#pragma unroll
        for (int mt = 0; mt < 4; ++mt)
#pragma unroll
            for (int nt = 0; nt < 4; ++nt) {
                int lcol  = wc * 64 + nt * 16 + lr;
                int lrow0 = wr * 64 + mt * 16 + quad * 4;
                ushort4 p;
                p.x = f2bf(acc[mt][nt][0]); p.y = f2bf(acc[mt][nt][1]);
                p.z = f2bf(acc[mt][nt][2]); p.w = f2bf(acc[mt][nt][3]);
                *(ushort4*)&smem[lcol * TST + lrow0] = p;
            }
        __syncthreads();
        int lc = t >> 1, half = t & 1;
        int cg = n0 + lc, hh = cg >> 6, dd = cg & 63;
        int bb = m0 >> 11, nn0 = m0 & (SEQ - 1);
        size_t dst = ((size_t)((bb * NHEADS + hh) * HD + dd)) * SEQ + nn0 + half * 64;
        const unsigned short* srcp = &smem[lc * TST + half * 64];
#pragma unroll
        for (int i = 0; i < 8; ++i)
            *(uint4*)&vT[dst + i * 8] = *(const uint4*)&srcp[i * 8];
    } else {
        unsigned short* Out = (z == 0) ? qo : ko;
        const float sc = (z == 0) ? QSCALE2 : 1.0f;
#pragma unroll
        for (int mt = 0; mt < 4; ++mt)
#pragma unroll
            for (int nt = 0; nt < 4; ++nt)
#pragma unroll
                for (int r = 0; r < 4; ++r) {
                    int row = m0 + wr * 64 + mt * 16 + quad * 4 + r;
                    int col = n0 + wc * 64 + nt * 16 + lr;
                    Out[(size_t)row * DIMC + col] = f2bf(acc[mt][nt][r] * sc);
                }
    }
}

__global__ __launch_bounds__(256) void gemm_out_f32(
    const unsigned short* __restrict__ A, const float* __restrict__ Wp,
    const float* __restrict__ bias, float* __restrict__ out)
{
    __shared__ unsigned short As[128 * AST];
    __shared__ unsigned short Bs[128 * AST];

    const int t  = threadIdx.x;
    const int n0 = blockIdx.x * 128, m0 = blockIdx.y * 128;
    const int w = t >> 6, l = t & 63, quad = l >> 4, lr = l & 15;
    const int wr = w >> 1, wc = w & 1;

    f32x4 acc[4][4];
#pragma unroll
    for (int mt = 0; mt < 4; ++mt)
#pragma unroll
        for (int nt = 0; nt < 4; ++nt)
#pragma unroll
            for (int r = 0; r < 4; ++r) acc[mt][nt][r] = 0.f;

    for (int kt = 0; kt < DIMC; kt += 64) {
        __syncthreads();
#pragma unroll
        for (int i = 0; i < 8; ++i) {
            int flat = t + i * 256;
            int row = flat >> 4, seg = flat & 15;
            ushort4 a = *(const ushort4*)(A + (size_t)(m0 + row) * DIMC + kt + seg * 4);
            *(ushort4*)&As[row * AST + seg * 4] = a;
            float4 b = *(const float4*)(Wp + (size_t)(n0 + row) * DIMC + kt + seg * 4);
            ushort4 pb; pb.x = f2bf(b.x); pb.y = f2bf(b.y); pb.z = f2bf(b.z); pb.w = f2bf(b.w);
            *(ushort4*)&Bs[row * AST + seg * 4] = pb;
        }
        __syncthreads();
#pragma unroll
        for (int kk = 0; kk < 2; ++kk) {
            bf16x8 af[4], bfr[4];
#pragma unroll
            for (int mt = 0; mt < 4; ++mt)
                af[mt] = *(const bf16x8*)&As[(wr * 64 + mt * 16 + lr) * AST + kk * 32 + quad * 8];
#pragma unroll
            for (int nt = 0; nt < 4; ++nt)
                bfr[nt] = *(const bf16x8*)&Bs[(wc * 64 + nt * 16 + lr) * AST + kk * 32 + quad * 8];
#pragma unroll
            for (int mt = 0; mt < 4; ++mt)
#pragma unroll
                for (int nt = 0; nt < 4; ++nt)
                    acc[mt][nt] = __builtin_amdgcn_mfma_f32_16x16x32_bf16(af[mt], bfr[nt], acc[mt][nt], 0, 0, 0);
        }
    }

#pragma unroll
    for (int mt = 0; mt < 4; ++mt)
#pragma unroll
        for (int nt = 0; nt < 4; ++nt)
#pragma unroll
            for (int r = 0; r < 4; ++r) {
                int row = m0 + wr * 64 + mt * 16 + quad * 4 + r;
                int col = n0 + wc * 64 + nt * 16 + lr;
                out[(size_t)row * DIMC + col] = acc[mt][nt][r] + bias[col];
            }
}

// ---------------------------------------------------------------------------
extern "C" void kernel_launch(void* const* d_in, const int* in_sizes, int n_in,
                              void* d_out, int out_size, void* d_ws, size_t ws_size,
                              hipStream_t stream)
{
    const float* x  = (const float*)d_in[0];
    const float* Wq = (const float*)d_in[1];
    const float* Wk = (const float*)d_in[2];
    const float* Wv = (const float*)d_in[3];
    const float* Wp = (const float*)d_in[4];
    const float* bp = (const float*)d_in[5];
    float* out = (float*)d_out;

    const size_t SZ  = (size_t)MROWS * DIMC;   // 4M elems
    const size_t WSZ = (size_t)DIMC * DIMC;    // 1M elems
    const size_t need = (4 * SZ + 4 * WSZ) * sizeof(unsigned short);  // 40 MB

    if (ws_size >= need) {
        unsigned short* q  = (unsigned short*)d_ws;
        unsigned short* k  = q + SZ;
        unsigned short* vt = k + SZ;
        unsigned short* o  = vt + SZ;
        unsigned short* Wb = o + SZ;
        unsigned short* xb = (unsigned short*)d_out;   // scratch: dead before gemm_out writes

        cast_all<<<dim3(1024, 8), 256, 0, stream>>>(x, Wq, Wk, Wv, Wp, xb, Wb);
        gemm_qkv_fast<<<dim3(8, 32, 3), 256, 0, stream>>>(xb, Wb, q, k, vt);
        attn_kernel<<<dim3(512), 256, 0, stream>>>(q, k, vt, o);
        gemm_out_fast<<<dim3(16, 32), 256, 0, stream>>>(o, Wb + 3 * WSZ, bp, out);
    } else {
        unsigned short* q  = (unsigned short*)d_ws;
        unsigned short* k  = q + SZ;
        unsigned short* vt = k + SZ;
        unsigned short* o  = vt + SZ;

        gemm_qkv_f32<<<dim3(DIMC / 128, MROWS / 128, 3), 256, 0, stream>>>(x, Wq, Wk, Wv, q, k, vt);
        attn_kernel<<<dim3(512), 256, 0, stream>>>(q, k, vt, o);
        gemm_out_f32<<<dim3(DIMC / 128, MROWS / 128), 256, 0, stream>>>(o, Wp, bp, out);
    }
}

// Round 13
// 170.415 us; speedup vs baseline: 1.1577x; 1.0011x over previous
//
#include <hip/hip_runtime.h>
#include <cstdint>

#define DIMC   1024
#define NHEADS 16
#define HD     64
#define BATCH  2
#define SEQ    2048
#define MROWS  (BATCH*SEQ)   // 4096
// Q pre-scale: (1/sqrt(64)) * log2(e)  -> softmax computed in base 2 (exact)
#define QSCALE2 0.18033688f

typedef __bf16 bf16x8 __attribute__((ext_vector_type(8)));
typedef float  f32x4  __attribute__((ext_vector_type(4)));

#define AST 88    // fallback LDS row stride (bf16 elems)
#define TST 136   // transpose-epilogue LDS stride

__device__ __forceinline__ unsigned short f2bf(float f) {
    union { float f; unsigned int u; } v; v.f = f;
    unsigned int u = v.u;
    u += 0x7fffu + ((u >> 16) & 1u);   // round-to-nearest-even
    return (unsigned short)(u >> 16);
}

// pack two floats to bf16x2 (round-nearest, ties away): 2 adds + 1 v_perm
__device__ __forceinline__ unsigned int pk2bf(float a, float b) {
    union { float f; unsigned int u; } ua, ub;
    ua.f = a; ub.f = b;
    return __builtin_amdgcn_perm(ub.u + 0x8000u, ua.u + 0x8000u, 0x07060302u);
}

__device__ __forceinline__ void gload_lds16(const void* g, void* l) {
    __builtin_amdgcn_global_load_lds(
        (const __attribute__((address_space(1))) unsigned int*)g,
        (__attribute__((address_space(3))) unsigned int*)l, 16, 0, 0);
}

// T4 counted-vmcnt barrier: wait only the OLDEST 4 outstanding VMEM ops
// (one issue-group), leaving the newest group in flight across the raw
// s_barrier.  "memory" clobber pins LDS/global ops; sched_barrier pins the
// scheduler (guide rule 18).  Proven in-session on attn (R11, -6%).
#define WAITBAR4() do { asm volatile("s_waitcnt vmcnt(4)" ::: "memory"); \
                        __builtin_amdgcn_s_barrier();                    \
                        __builtin_amdgcn_sched_barrier(0); } while (0)
#define WAITBAR0() do { asm volatile("s_waitcnt vmcnt(0)" ::: "memory"); \
                        __builtin_amdgcn_s_barrier();                    \
                        __builtin_amdgcn_sched_barrier(0); } while (0)

// ---------------------------------------------------------------------------
// Pre-cast fp32 -> bf16: x (4M elems) and Wq|Wk|Wv|Wp (1M each) into xb / Wb.
// ---------------------------------------------------------------------------
__global__ __launch_bounds__(256) void cast_all(
    const float* __restrict__ x,
    const float* __restrict__ Wq, const float* __restrict__ Wk,
    const float* __restrict__ Wv, const float* __restrict__ Wp,
    unsigned short* __restrict__ xb, unsigned short* __restrict__ Wb)
{
    const size_t M1 = (size_t)DIMC * DIMC;   // 1M elems
    int y = blockIdx.y;
    const float* src;
    unsigned short* dst;
    if (y < 4)      { src = x  + (size_t)y * M1; dst = xb + (size_t)y * M1; }
    else if (y == 4){ src = Wq; dst = Wb; }
    else if (y == 5){ src = Wk; dst = Wb + M1; }
    else if (y == 6){ src = Wv; dst = Wb + 2 * M1; }
    else            { src = Wp; dst = Wb + 3 * M1; }
    size_t idx = ((size_t)blockIdx.x * 256 + threadIdx.x) * 4;
    float4 v = *(const float4*)(src + idx);
    ushort4 p; p.x = f2bf(v.x); p.y = f2bf(v.y); p.z = f2bf(v.z); p.w = f2bf(v.w);
    *(ushort4*)(dst + idx) = p;
}

// ---------------------------------------------------------------------------
// qkv GEMM building blocks (R10/R11-verified): 128x128 tile, BK=32,
// pair-row-interleaved LDS layout (logical row r at (r>>1)*64 + (r&1)*32,
// chunk key (r>>1)&3; DMA dest = wave-uniform base + lane*16).
// ---------------------------------------------------------------------------
__device__ __forceinline__ void gemm_issue32(
    const unsigned short* __restrict__ A, const unsigned short* __restrict__ B,
    unsigned short* As, unsigned short* Bs, int m0, int n0, int kt)
{
    const int t = threadIdx.x;
    const int rr = t >> 2, cg = t & 3;     // rr 0..63, physical chunk 0..3
#pragma unroll
    for (int i = 0; i < 2; ++i) {
        int r  = i * 64 + rr;              // logical row 0..127
        int sc = cg ^ ((r >> 1) & 3);      // source k-chunk (swizzled)
        int dst = (r >> 1) * 64 + (r & 1) * 32 + cg * 8;
        gload_lds16(A + (size_t)(m0 + r) * DIMC + kt + sc * 8, As + dst);
        gload_lds16(B + (size_t)(n0 + r) * DIMC + kt + sc * 8, Bs + dst);
    }
}

__device__ __forceinline__ void gemm_compute32(
    const unsigned short* As, const unsigned short* Bs, f32x4 acc[4][4])
{
    const int t = threadIdx.x;
    const int w = t >> 6, lane = t & 63, quad = lane >> 4, lr = lane & 15;
    const int wr = w >> 1, wc = w & 1;
    bf16x8 af[4], bfr[4];
#pragma unroll
    for (int mt = 0; mt < 4; ++mt) {
        int row = wr * 64 + mt * 16 + lr;
        af[mt] = *(const bf16x8*)&As[(row >> 1) * 64 + (row & 1) * 32
                                     + ((quad ^ ((row >> 1) & 3)) * 8)];
    }
#pragma unroll
    for (int nt = 0; nt < 4; ++nt) {
        int row = wc * 64 + nt * 16 + lr;
        bfr[nt] = *(const bf16x8*)&Bs[(row >> 1) * 64 + (row & 1) * 32
                                      + ((quad ^ ((row >> 1) & 3)) * 8)];
    }
#pragma unroll
    for (int mt = 0; mt < 4; ++mt)
#pragma unroll
        for (int nt = 0; nt < 4; ++nt)
            acc[mt][nt] = __builtin_amdgcn_mfma_f32_16x16x32_bf16(af[mt], bfr[nt], acc[mt][nt], 0, 0, 0);
}

// vT transpose epilogue (128-col tile, R8-verified): stage C-tile transposed
// in LDS, then coalesced 16B global stores to vT[b][h][d][n].
__device__ __forceinline__ void vt_epilogue(
    unsigned short* Ts, f32x4 acc[4][4], int m0, int n0,
    unsigned short* __restrict__ vT)
{
    const int t = threadIdx.x;
    const int w = t >> 6, lane = t & 63, quad = lane >> 4, lr = lane & 15;
    const int wr = w >> 1, wc = w & 1;

    __syncthreads();
#pragma unroll
    for (int mt = 0; mt < 4; ++mt)
#pragma unroll
        for (int nt = 0; nt < 4; ++nt) {
            int lcol  = wc * 64 + nt * 16 + lr;
            int lrow0 = wr * 64 + mt * 16 + quad * 4;
            ushort4 p;
            p.x = f2bf(acc[mt][nt][0]); p.y = f2bf(acc[mt][nt][1]);
            p.z = f2bf(acc[mt][nt][2]); p.w = f2bf(acc[mt][nt][3]);
            *(ushort4*)&Ts[lcol * TST + lrow0] = p;
        }
    __syncthreads();

    int lc = t >> 1, half = t & 1;
    int cg = n0 + lc, hh = cg >> 6, dd = cg & 63;
    int bb = m0 >> 11, nn0 = m0 & (SEQ - 1);
    size_t dst = ((size_t)((bb * NHEADS + hh) * HD + dd)) * SEQ + nn0 + half * 64;
    const unsigned short* srcp = &Ts[lc * TST + half * 64];
#pragma unroll
    for (int i = 0; i < 8; ++i)
        *(uint4*)&vT[dst + i * 8] = *(const uint4*)&srcp[i * 8];
}

// ---------------------------------------------------------------------------
// Fast QKV projection v23: R11 geometry + T3/T4 counted-vmcnt deep prefetch
// (port of the attn-proven rotation).  3-deep As/Bs buffers (step s -> buf
// s%3, compile-time names), vmcnt(4) leaves the newest issue-group of 4 in
// flight across each raw s_barrier -> each DMA gets TWO compute phases to
// land.  Enumerated: outstanding invariant {s, s+1} at each block head;
// every buffer write is barrier-separated from its previous readers; tail
// drains via vmcnt(4)->vmcnt(0) before the Ts-reuse epilogue.
// LDS = 3 x (8+8) KB = 48 KB -> 3 blocks/CU; grid (8,32,3) = 768 blocks
// co-resident.  R12's fused variant is abandoned (race-signature failure).
// ---------------------------------------------------------------------------
__global__ __launch_bounds__(256, 3) void gemm_qkv_fast(
    const unsigned short* __restrict__ xb, const unsigned short* __restrict__ Wb,
    unsigned short* __restrict__ qo, unsigned short* __restrict__ ko,
    unsigned short* __restrict__ vT)
{
    __shared__ unsigned short smem[24576];   // 48 KB: 3 x (As 8 KB + Bs 8 KB)
    unsigned short* As0 = smem;
    unsigned short* Bs0 = smem + 4096;
    unsigned short* As1 = smem + 8192;
    unsigned short* Bs1 = smem + 12288;
    unsigned short* As2 = smem + 16384;
    unsigned short* Bs2 = smem + 20480;

    const int t  = threadIdx.x;
    const int lin = blockIdx.y * 8 + blockIdx.x;      // 0..255
    const int T   = (lin & 7) * 32 + (lin >> 3);      // bijective XCD chunking
    const int n0 = (T & 7) * 128, m0 = (T >> 3) * 128, z = blockIdx.z;
    const unsigned short* B = Wb + (size_t)z * DIMC * DIMC;
    const int w = t >> 6, lane = t & 63, quad = lane >> 4, lr = lane & 15;
    const int wr = w >> 1, wc = w & 1;

    f32x4 acc[4][4];
#pragma unroll
    for (int mt = 0; mt < 4; ++mt)
#pragma unroll
        for (int nt = 0; nt < 4; ++nt)
#pragma unroll
            for (int r = 0; r < 4; ++r) acc[mt][nt][r] = 0.f;

    // step s covers k-chunk [s*32, s*32+32); 32 steps total.
    // Prologue: 2 steps in flight (8 loads/lane).
    gemm_issue32(xb, B, As0, Bs0, m0, n0, 0);
    gemm_issue32(xb, B, As1, Bs1, m0, n0, 32);

    // Steps 0..29 in blocks of 3 (buffer names compile-time); issues reach 31.
    for (int base = 0; base < 30; base += 3) {
        WAITBAR4(); gemm_issue32(xb, B, As2, Bs2, m0, n0, (base + 2) * 32);
        gemm_compute32(As0, Bs0, acc);
        WAITBAR4(); gemm_issue32(xb, B, As0, Bs0, m0, n0, (base + 3) * 32);
        gemm_compute32(As1, Bs1, acc);
        WAITBAR4(); gemm_issue32(xb, B, As1, Bs1, m0, n0, (base + 4) * 32);
        gemm_compute32(As2, Bs2, acc);
    }
    // Tail: step 30 (buf0; {30,31} outstanding) and 31 (buf1; {31} left).
    WAITBAR4(); gemm_compute32(As0, Bs0, acc);
    WAITBAR0(); gemm_compute32(As1, Bs1, acc);

    if (z == 2) {
        vt_epilogue(smem, acc, m0, n0, vT);
    } else {
        unsigned short* Out = (z == 0) ? qo : ko;
        const float sc = (z == 0) ? QSCALE2 : 1.0f;
#pragma unroll
        for (int mt = 0; mt < 4; ++mt)
#pragma unroll
            for (int nt = 0; nt < 4; ++nt)
#pragma unroll
                for (int r = 0; r < 4; ++r) {
                    int row = m0 + wr * 64 + mt * 16 + quad * 4 + r;
                    int col = n0 + wc * 64 + nt * 16 + lr;
                    Out[(size_t)row * DIMC + col] = f2bf(acc[mt][nt][r] * sc);
                }
    }
}

// ---------------------------------------------------------------------------
// Fast output projection (R9/R10/R11 verified 128x64 geometry, unchanged:
// 3-deep doesn't fit its 24 KB/stage tile in 64 KB static LDS).
// ---------------------------------------------------------------------------
__device__ __forceinline__ void gemm_issue_out(
    const unsigned short* __restrict__ A, const unsigned short* __restrict__ B,
    unsigned short* As, unsigned short* Bs, int m0, int n0, int kt)
{
    const int t = threadIdx.x;
    const int w = t >> 6, lane = t & 63;
    const int srow = lane >> 3, scol = lane & 7;
#pragma unroll
    for (int i = 0; i < 4; ++i) {
        int r  = i * 32 + w * 8 + srow;        // 0..127 (A rows)
        int cg = scol ^ (r & 7);
        gload_lds16(A + (size_t)(m0 + r) * DIMC + kt + cg * 8, As + r * 64 + scol * 8);
    }
#pragma unroll
    for (int i = 0; i < 2; ++i) {
        int r  = i * 32 + w * 8 + srow;        // 0..63 (B rows)
        int cg = scol ^ (r & 7);
        gload_lds16(B + (size_t)(n0 + r) * DIMC + kt + cg * 8, Bs + r * 64 + scol * 8);
    }
}

__device__ __forceinline__ void gemm_compute_out(
    const unsigned short* As, const unsigned short* Bs, f32x4 acc[4][2])
{
    const int t = threadIdx.x;
    const int w = t >> 6, lane = t & 63, quad = lane >> 4, lr = lane & 15;
    const int wr = w >> 1, wc = w & 1;
#pragma unroll
    for (int kk = 0; kk < 2; ++kk) {
        bf16x8 af[4], bfr[2];
#pragma unroll
        for (int mt = 0; mt < 4; ++mt) {
            int row = wr * 64 + mt * 16 + lr;
            int cb  = kk * 4 + quad;
            af[mt] = *(const bf16x8*)&As[row * 64 + (cb ^ (row & 7)) * 8];
        }
#pragma unroll
        for (int nt = 0; nt < 2; ++nt) {
            int row = wc * 32 + nt * 16 + lr;
            int cb  = kk * 4 + quad;
            bfr[nt] = *(const bf16x8*)&Bs[row * 64 + (cb ^ (row & 7)) * 8];
        }
#pragma unroll
        for (int mt = 0; mt < 4; ++mt)
#pragma unroll
            for (int nt = 0; nt < 2; ++nt)
                acc[mt][nt] = __builtin_amdgcn_mfma_f32_16x16x32_bf16(af[mt], bfr[nt], acc[mt][nt], 0, 0, 0);
    }
}

__global__ __launch_bounds__(256, 3) void gemm_out_fast(
    const unsigned short* __restrict__ O, const unsigned short* __restrict__ Wpb,
    const float* __restrict__ bias, float* __restrict__ out)
{
    __shared__ unsigned short smem[24576];   // 48 KB

    const int t  = threadIdx.x;
    const int lin = blockIdx.y * 16 + blockIdx.x;
    const int T   = (lin & 7) * 64 + (lin >> 3);
    const int n0 = (T & 15) * 64, m0 = (T >> 4) * 128;
    const int w = t >> 6, lane = t & 63, quad = lane >> 4, lr = lane & 15;
    const int wr = w >> 1, wc = w & 1;

    f32x4 acc[4][2];
#pragma unroll
    for (int mt = 0; mt < 4; ++mt)
#pragma unroll
        for (int nt = 0; nt < 2; ++nt)
#pragma unroll
            for (int r = 0; r < 4; ++r) acc[mt][nt][r] = 0.f;

    unsigned short* As0 = smem;              // 16 KB (128 x 64)
    unsigned short* Bs0 = smem + 8192;       //  8 KB ( 64 x 64)
    unsigned short* As1 = smem + 12288;
    unsigned short* Bs1 = smem + 20480;

    gemm_issue_out(O, Wpb, As0, Bs0, m0, n0, 0);
    for (int kt = 0; kt < DIMC; kt += 128) {
        __syncthreads();
        gemm_issue_out(O, Wpb, As1, Bs1, m0, n0, kt + 64);
        gemm_compute_out(As0, Bs0, acc);
        __syncthreads();
        if (kt + 128 < DIMC) gemm_issue_out(O, Wpb, As0, Bs0, m0, n0, kt + 128);
        gemm_compute_out(As1, Bs1, acc);
    }

#pragma unroll
    for (int mt = 0; mt < 4; ++mt)
#pragma unroll
        for (int nt = 0; nt < 2; ++nt)
#pragma unroll
            for (int r = 0; r < 4; ++r) {
                int row = m0 + wr * 64 + mt * 16 + quad * 4 + r;
                int col = n0 + wc * 32 + nt * 16 + lr;
                out[(size_t)row * DIMC + col] = acc[mt][nt][r] + bias[col];
            }
}

// ---------------------------------------------------------------------------
// Flash attention v21 (UNCHANGED from R11, 46.9 us proven): v18 + T3/T4
// counted-vmcnt deep prefetch; 3-deep K/V buffers, raw s_barrier + vmcnt(4);
// Ps single-buffered, single vr set; T5 setprio; 2 blocks/CU.
// ---------------------------------------------------------------------------
__global__ __launch_bounds__(256, 2) void attn_kernel(
    const unsigned short* __restrict__ qg, const unsigned short* __restrict__ kg,
    const unsigned short* __restrict__ vT, unsigned short* __restrict__ og)
{
    __shared__ unsigned short K0s[64 * 64];
    __shared__ unsigned short K1s[64 * 64];
    __shared__ unsigned short K2s[64 * 64];
    __shared__ unsigned short V0s[64 * 64];
    __shared__ unsigned short V1s[64 * 64];
    __shared__ unsigned short V2s[64 * 64];
    __shared__ unsigned short Ps[128 * 64];   // wave w owns rows w*32..w*32+31

    const int t  = threadIdx.x;
    const int w = t >> 6, l = t & 63, quad = l >> 4, lr = l & 15;
    const int srow = t >> 3, scol = t & 7;    // staging coords (256 threads: srow 0..31)
    const int pkey = (lr & 7) << 1;           // Ps swizzle key (even -> keeps pairs)

    // XCD-aware mapping: bid&7 = XCD; each XCD owns 4 full (b,h) pairs.
    const int bid  = blockIdx.x;              // 0..511
    const int slot = bid >> 3;                // 0..63
    const int bh   = (bid & 7) * 4 + (slot >> 4);
    const int qt   = slot & 15;               // 128-row Q tile index
    const int b    = bh >> 4, h = bh & 15;

    const unsigned short* khead = kg + ((size_t)(b * SEQ)) * DIMC + h * HD;
    const unsigned short* vhead = vT + (size_t)((b * NHEADS + h) * HD) * SEQ;

    // Q A-fragments (pre-scaled by QSCALE2): 2 m-tiles x 2 k-steps per wave
    bf16x8 qf[2][2];
#pragma unroll
    for (int mt = 0; mt < 2; ++mt) {
        const size_t qoff = ((size_t)(b * SEQ + qt * 128 + w * 32 + mt * 16 + lr)) * DIMC + h * HD;
        qf[mt][0] = *(const bf16x8*)(qg + qoff + 0  + quad * 8);
        qf[mt][1] = *(const bf16x8*)(qg + qoff + 32 + quad * 8);
    }

    bf16x8 ones;
#pragma unroll
    for (int j = 0; j < 8; ++j) ones[j] = (__bf16)1.0f;
    const f32x4 fzero = { 0.f, 0.f, 0.f, 0.f };

    f32x4 o_acc[2][4], lacc[2];
#pragma unroll
    for (int mt = 0; mt < 2; ++mt) {
        lacc[mt] = fzero;
#pragma unroll
        for (int ct = 0; ct < 4; ++ct) o_acc[mt][ct] = fzero;
    }

    auto issue = [&](int kt, unsigned short* Kd, unsigned short* Vd) {
#pragma unroll
        for (int i = 0; i < 2; ++i) {
            int r  = i * 32 + srow;            // 0..63
            int cg = scol ^ (r & 7);
            gload_lds16(khead + (size_t)(kt * 64 + r) * DIMC + cg * 8, Kd + r * 64 + scol * 8);
            gload_lds16(vhead + (size_t)r * SEQ + kt * 64 + cg * 8,   Vd + r * 64 + scol * 8);
        }
    };

    // S^T = K·Q^T : row = kv, col = m; chain seeded with fzero
    auto s_phase = [&](const unsigned short* Kc, f32x4 (&s)[2][4]) {
        __builtin_amdgcn_s_setprio(1);        // T5: keep matrix pipe fed
#pragma unroll
        for (int nt = 0; nt < 4; ++nt) {
            int row = nt * 16 + lr;
            bf16x8 kf = *(const bf16x8*)&Kc[row * 64 + ((quad ^ (row & 7)) * 8)];
#pragma unroll
            for (int mt = 0; mt < 2; ++mt)
                s[mt][nt] = __builtin_amdgcn_mfma_f32_16x16x32_bf16(kf, qf[mt][0], fzero, 0, 0, 0);
        }
#pragma unroll
        for (int nt = 0; nt < 4; ++nt) {
            int row = nt * 16 + lr;
            bf16x8 kf = *(const bf16x8*)&Kc[row * 64 + (((4 + quad) ^ (row & 7)) * 8)];
#pragma unroll
            for (int mt = 0; mt < 2; ++mt)
                s[mt][nt] = __builtin_amdgcn_mfma_f32_16x16x32_bf16(kf, qf[mt][1], s[mt][nt], 0, 0, 0);
        }
        __builtin_amdgcn_s_setprio(0);
    };

    // p = 2^s (raw v_exp), packed pair-wise, 8B swizzled stores: Ps[m][kv]
    auto exp_store = [&](const f32x4 (&s)[2][4]) {
#pragma unroll
        for (int mt = 0; mt < 2; ++mt)
#pragma unroll
            for (int nt = 0; nt < 4; ++nt) {
                uint2 pp;
                pp.x = pk2bf(__builtin_amdgcn_exp2f(s[mt][nt][0]),
                             __builtin_amdgcn_exp2f(s[mt][nt][1]));
                pp.y = pk2bf(__builtin_amdgcn_exp2f(s[mt][nt][2]),
                             __builtin_amdgcn_exp2f(s[mt][nt][3]));
                *(uint2*)&Ps[(w * 32 + mt * 16 + lr) * 64 + (((nt * 4 + quad) ^ pkey) * 4)] = pp;
            }
    };

    // stage V(t) fragments to registers (used by pv in the NEXT sub-phase)
    bf16x8 vr[8];
    auto vload = [&](const unsigned short* Vc) {
#pragma unroll
        for (int kk = 0; kk < 2; ++kk)
#pragma unroll
            for (int ct = 0; ct < 4; ++ct) {
                int row = ct * 16 + lr;
                vr[kk * 4 + ct] = *(const bf16x8*)&Vc[row * 64 + (((kk * 4 + quad) ^ (row & 7)) * 8)];
            }
    };

    // O += P*V ; l += P*1   (P = previous tile, from wave-private Ps rows)
    auto pv = [&]() {
        __builtin_amdgcn_s_setprio(1);        // T5
#pragma unroll
        for (int kk = 0; kk < 2; ++kk)
#pragma unroll
            for (int mt = 0; mt < 2; ++mt) {
                bf16x8 pf = *(const bf16x8*)&Ps[(w * 32 + mt * 16 + lr) * 64 + (((kk * 8 + quad * 2) ^ pkey) * 4)];
                lacc[mt] = __builtin_amdgcn_mfma_f32_16x16x32_bf16(pf, ones, lacc[mt], 0, 0, 0);
#pragma unroll
                for (int ct = 0; ct < 4; ++ct)
                    o_acc[mt][ct] = __builtin_amdgcn_mfma_f32_16x16x32_bf16(pf, vr[kk * 4 + ct], o_acc[mt][ct], 0, 0, 0);
            }
        __builtin_amdgcn_s_setprio(0);
    };

    // sub-phase for tile t: S(t) || PV(t-1), then P(t)->Ps, V(t)->vr.
    auto subphase = [&](const unsigned short* Kc, const unsigned short* Vc, bool first) {
        f32x4 s[2][4];
        s_phase(Kc, s);
        if (!first) pv();
        exp_store(s);
        vload(Vc);
    };

    // Prologue: 2 tiles in flight (8 loads/lane).
    issue(0, K0s, V0s);
    issue(1, K1s, V1s);

    // Tiles 0..29 in blocks of 3 (buffer names compile-time); issues reach 31.
    for (int base = 0; base < 30; base += 3) {
        WAITBAR4(); issue(base + 2, K2s, V2s); subphase(K0s, V0s, base == 0);
        WAITBAR4(); issue(base + 3, K0s, V0s); subphase(K1s, V1s, false);
        WAITBAR4(); issue(base + 4, K1s, V1s); subphase(K2s, V2s, false);
    }
    // Tail: tile 30 (buf0; {30,31} outstanding) and 31 (buf1; {31} left).
    WAITBAR4(); subphase(K0s, V0s, false);
    WAITBAR0(); subphase(K1s, V1s, false);
    pv();                                     // drain: PV(tile 31)

#pragma unroll
    for (int mt = 0; mt < 2; ++mt) {
        float inv[4];
#pragma unroll
        for (int r = 0; r < 4; ++r) inv[r] = 1.0f / lacc[mt][r];
#pragma unroll
        for (int ct = 0; ct < 4; ++ct)
#pragma unroll
            for (int r = 0; r < 4; ++r) {
                int qrow = qt * 128 + w * 32 + mt * 16 + quad * 4 + r;
                og[((size_t)(b * SEQ + qrow)) * DIMC + h * HD + ct * 16 + lr] =
                    f2bf(o_acc[mt][ct][r] * inv[r]);
            }
    }
}

// ---------------------------------------------------------------------------
// Fallback path (ws < 40 MB): fp32-staging GEMMs.
// ---------------------------------------------------------------------------
__global__ __launch_bounds__(256) void gemm_qkv_f32(
    const float* __restrict__ x,
    const float* __restrict__ Wq, const float* __restrict__ Wk, const float* __restrict__ Wv,
    unsigned short* __restrict__ qo, unsigned short* __restrict__ ko, unsigned short* __restrict__ vT)
{
    __shared__ unsigned short smem[2 * 128 * AST];
    unsigned short* As = smem;
    unsigned short* Bs = smem + 128 * AST;

    const int t  = threadIdx.x;
    const int n0 = blockIdx.x * 128, m0 = blockIdx.y * 128, z = blockIdx.z;
    const float* W = (z == 0) ? Wq : (z == 1) ? Wk : Wv;
    const int w = t >> 6, l = t & 63, quad = l >> 4, lr = l & 15;
    const int wr = w >> 1, wc = w & 1;

    f32x4 acc[4][4];
#pragma unroll
    for (int mt = 0; mt < 4; ++mt)
#pragma unroll
        for (int nt = 0; nt < 4; ++nt)
#pragma unroll
            for (int r = 0; r < 4; ++r) acc[mt][nt][r] = 0.f;

    for (int kt = 0; kt < DIMC; kt += 64) {
        __syncthreads();
#pragma unroll
        for (int i = 0; i < 8; ++i) {
            int flat = t + i * 256;
            int row = flat >> 4, seg = flat & 15;
            float4 a = *(const float4*)(x + (size_t)(m0 + row) * DIMC + kt + seg * 4);
            ushort4 pa; pa.x = f2bf(a.x); pa.y = f2bf(a.y); pa.z = f2bf(a.z); pa.w = f2bf(a.w);
            *(ushort4*)&As[row * AST + seg * 4] = pa;
            float4 b = *(const float4*)(W + (size_t)(n0 + row) * DIMC + kt + seg * 4);
            ushort4 pb; pb.x = f2bf(b.x); pb.y = f2bf(b.y); pb.z = f2bf(b.z); pb.w = f2bf(b.w);
            *(ushort4*)&Bs[row * AST + seg * 4] = pb;
        }
        __syncthreads();
#pragma unroll
        for (int kk = 0; kk < 2; ++kk) {
            bf16x8 af[4], bfr[4];
#pragma unroll
            for (int mt = 0; mt < 4; ++mt)
                af[mt] = *(const bf16x8*)&As[(wr * 64 + mt * 16 + lr) * AST + kk * 32 + quad * 8];
#pragma unroll
            for (int nt = 0; nt < 4; ++nt)
                bfr[nt] = *(const bf16x8*)&Bs[(wc * 64 + nt * 16 + lr) * AST + kk * 32 + quad * 8];
#pragma unroll
            for (int mt = 0; mt < 4; ++mt)
#pragma unroll
                for (int nt = 0; nt < 4; ++nt)
                    acc[mt][nt] = __builtin_amdgcn_mfma_f32_16x16x32_bf16(af[mt], bfr[nt], acc[mt][nt], 0, 0, 0);
        }
    }

    if (z == 2) {
        __syncthreads();
#pragma unroll
        for (int mt = 0; mt < 4; ++mt)
#pragma unroll
            for (int nt = 0; nt < 4; ++nt) {
                int lcol  = wc * 64 + nt * 16 + lr;
                int lrow0 = wr * 64 + mt * 16 + quad * 4;
                ushort4 p;
                p.x = f2bf(acc[mt][nt][0]); p.y = f2bf(acc[mt][nt][1]);
                p.z = f2bf(acc[mt][nt][2]); p.w = f2bf(acc[mt][nt][3]);
                *(ushort4*)&smem[lcol * TST + lrow0] = p;
            }
        __syncthreads();
        int lc = t >> 1, half = t & 1;
        int cg = n0 + lc, hh = cg >> 6, dd = cg & 63;
        int bb = m0 >> 11, nn0 = m0 & (SEQ - 1);
        size_t dst = ((size_t)((bb * NHEADS + hh) * HD + dd)) * SEQ + nn0 + half * 64;
        const unsigned short* srcp = &smem[lc * TST + half * 64];
#pragma unroll
        for (int i = 0; i < 8; ++i)
            *(uint4*)&vT[dst + i * 8] = *(const uint4*)&srcp[i * 8];
    } else {
        unsigned short* Out = (z == 0) ? qo : ko;
        const float sc = (z == 0) ? QSCALE2 : 1.0f;
#pragma unroll
        for (int mt = 0; mt < 4; ++mt)
#pragma unroll
            for (int nt = 0; nt < 4; ++nt)
#pragma unroll
                for (int r = 0; r < 4; ++r) {
                    int row = m0 + wr * 64 + mt * 16 + quad * 4 + r;
                    int col = n0 + wc * 64 + nt * 16 + lr;
                    Out[(size_t)row * DIMC + col] = f2bf(acc[mt][nt][r] * sc);
                }
    }
}

__global__ __launch_bounds__(256) void gemm_out_f32(
    const unsigned short* __restrict__ A, const float* __restrict__ Wp,
    const float* __restrict__ bias, float* __restrict__ out)
{
    __shared__ unsigned short As[128 * AST];
    __shared__ unsigned short Bs[128 * AST];

    const int t  = threadIdx.x;
    const int n0 = blockIdx.x * 128, m0 = blockIdx.y * 128;
    const int w = t >> 6, l = t & 63, quad = l >> 4, lr = l & 15;
    const int wr = w >> 1, wc = w & 1;

    f32x4 acc[4][4];
#pragma unroll
    for (int mt = 0; mt < 4; ++mt)
#pragma unroll
        for (int nt = 0; nt < 4; ++nt)
#pragma unroll
            for (int r = 0; r < 4; ++r) acc[mt][nt][r] = 0.f;

    for (int kt = 0; kt < DIMC; kt += 64) {
        __syncthreads();
#pragma unroll
        for (int i = 0; i < 8; ++i) {
            int flat = t + i * 256;
            int row = flat >> 4, seg = flat & 15;
            ushort4 a = *(const ushort4*)(A + (size_t)(m0 + row) * DIMC + kt + seg * 4);
            *(ushort4*)&As[row * AST + seg * 4] = a;
            float4 b = *(const float4*)(Wp + (size_t)(n0 + row) * DIMC + kt + seg * 4);
            ushort4 pb; pb.x = f2bf(b.x); pb.y = f2bf(b.y); pb.z = f2bf(b.z); pb.w = f2bf(b.w);
            *(ushort4*)&Bs[row * AST + seg * 4] = pb;
        }
        __syncthreads();
#pragma unroll
        for (int kk = 0; kk < 2; ++kk) {
            bf16x8 af[4], bfr[4];
#pragma unroll
            for (int mt = 0; mt < 4; ++mt)
                af[mt] = *(const bf16x8*)&As[(wr * 64 + mt * 16 + lr) * AST + kk * 32 + quad * 8];
#pragma unroll
            for (int nt = 0; nt < 4; ++nt)
                bfr[nt] = *(const bf16x8*)&Bs[(wc * 64 + nt * 16 + lr) * AST + kk * 32 + quad * 8];
#pragma unroll
            for (int mt = 0; mt < 4; ++mt)
#pragma unroll
                for (int nt = 0; nt < 4; ++nt)
                    acc[mt][nt] = __builtin_amdgcn_mfma_f32_16x16x32_bf16(af[mt], bfr[nt], acc[mt][nt], 0, 0, 0);
        }
    }

#pragma unroll
    for (int mt = 0; mt < 4; ++mt)
#pragma unroll
        for (int nt = 0; nt < 4; ++nt)
#pragma unroll
            for (int r = 0; r < 4; ++r) {
                int row = m0 + wr * 64 + mt * 16 + quad * 4 + r;
                int col = n0 + wc * 64 + nt * 16 + lr;
                out[(size_t)row * DIMC + col] = acc[mt][nt][r] + bias[col];
            }
}

// ---------------------------------------------------------------------------
extern "C" void kernel_launch(void* const* d_in, const int* in_sizes, int n_in,
                              void* d_out, int out_size, void* d_ws, size_t ws_size,
                              hipStream_t stream)
{
    const float* x  = (const float*)d_in[0];
    const float* Wq = (const float*)d_in[1];
    const float* Wk = (const float*)d_in[2];
    const float* Wv = (const float*)d_in[3];
    const float* Wp = (const float*)d_in[4];
    const float* bp = (const float*)d_in[5];
    float* out = (float*)d_out;

    const size_t SZ  = (size_t)MROWS * DIMC;   // 4M elems
    const size_t WSZ = (size_t)DIMC * DIMC;    // 1M elems
    const size_t need = (4 * SZ + 4 * WSZ) * sizeof(unsigned short);  // 40 MB

    if (ws_size >= need) {
        unsigned short* q  = (unsigned short*)d_ws;
        unsigned short* k  = q + SZ;
        unsigned short* vt = k + SZ;
        unsigned short* o  = vt + SZ;
        unsigned short* Wb = o + SZ;
        unsigned short* xb = (unsigned short*)d_out;   // scratch: dead before gemm_out writes

        cast_all<<<dim3(1024, 8), 256, 0, stream>>>(x, Wq, Wk, Wv, Wp, xb, Wb);
        gemm_qkv_fast<<<dim3(8, 32, 3), 256, 0, stream>>>(xb, Wb, q, k, vt);
        attn_kernel<<<dim3(512), 256, 0, stream>>>(q, k, vt, o);
        gemm_out_fast<<<dim3(16, 32), 256, 0, stream>>>(o, Wb + 3 * WSZ, bp, out);
    } else {
        unsigned short* q  = (unsigned short*)d_ws;
        unsigned short* k  = q + SZ;
        unsigned short* vt = k + SZ;
        unsigned short* o  = vt + SZ;

        gemm_qkv_f32<<<dim3(DIMC / 128, MROWS / 128, 3), 256, 0, stream>>>(x, Wq, Wk, Wv, q, k, vt);
        attn_kernel<<<dim3(512), 256, 0, stream>>>(q, k, vt, o);
        gemm_out_f32<<<dim3(DIMC / 128, MROWS / 128), 256, 0, stream>>>(o, Wp, bp, out);
    }
}